// Round 2
// baseline (535.536 us; speedup 1.0000x reference)
//
#include <hip/hip_runtime.h>
#include <cstdint>
#include <cstddef>

// ---------- types ----------
typedef __attribute__((ext_vector_type(8))) short short8;   // 8 x bf16 (4 VGPR)
typedef __attribute__((ext_vector_type(4))) float f32x4;

__device__ __forceinline__ unsigned short f2bf(float x) {
    unsigned u = __float_as_uint(x);
    u += 0x7FFFu + ((u >> 16) & 1u);        // RNE
    return (unsigned short)(u >> 16);
}
__device__ __forceinline__ float bf2f(unsigned short h) {
    return __uint_as_float(((unsigned)h) << 16);
}

// async global->LDS, 16B per lane; LDS dest = uniform base + lane*16
__device__ __forceinline__ void gload_lds16(const void* g, void* l) {
    __builtin_amdgcn_global_load_lds(
        (const __attribute__((address_space(1))) unsigned int*)g,
        (__attribute__((address_space(3))) unsigned int*)l, 16, 0, 0);
}

// ---------- kernel 1a: f32 -> bf16 hidden (exact grid) ----------
__global__ void convert_hidden(const float* __restrict__ in, unsigned short* __restrict__ out) {
    int i = blockIdx.x * 256 + threadIdx.x;           // 262144 float4 total
    float4 v = *(const float4*)(in + (size_t)i * 4);
    unsigned long long p = (unsigned long long)f2bf(v.x)
                         | ((unsigned long long)f2bf(v.y) << 16)
                         | ((unsigned long long)f2bf(v.z) << 32)
                         | ((unsigned long long)f2bf(v.w) << 48);
    *(unsigned long long*)(out + (size_t)i * 4) = p;
}

// ---------- kernel 1b: generic f32 -> bf16 (n4 float4 chunks) ----------
__global__ void convert_w(const float* __restrict__ in, unsigned short* __restrict__ out, int n4) {
    int i = blockIdx.x * 256 + threadIdx.x;
    if (i >= n4) return;
    float4 v = *(const float4*)(in + (size_t)i * 4);
    unsigned long long p = (unsigned long long)f2bf(v.x)
                         | ((unsigned long long)f2bf(v.y) << 16)
                         | ((unsigned long long)f2bf(v.z) << 32)
                         | ((unsigned long long)f2bf(v.w) << 48);
    *(unsigned long long*)(out + (size_t)i * 4) = p;
}

// ---------- kernel 2: proj_i = hidden @ P_i^T  (bf16 out, proj3 zero-padded to 64) ----------
__global__ __launch_bounds__(384)
void proj_kernel(const float* __restrict__ hidden,
                 const float* __restrict__ P1, const float* __restrict__ P2,
                 const float* __restrict__ P3,
                 unsigned short* __restrict__ proj1, unsigned short* __restrict__ proj2,
                 unsigned short* __restrict__ proj3) {
    __shared__ __align__(16) float h[8][1024];
    const int t0 = blockIdx.x * 8;
    const int tid = threadIdx.x;
    for (int f = tid; f < 2048; f += 384) {
        int tok = f >> 8, pos = (f & 255) * 4;
        *(float4*)&h[tok][pos] = *(const float4*)(hidden + (size_t)(t0 + tok) * 1024 + pos);
    }
    __syncthreads();
    const int n = tid;
    const float* Prow;
    unsigned short* outp;
    int stride;
    if (n < 256)      { Prow = P1 + (size_t)n * 1024;        outp = proj1 + n;        stride = 256; }
    else if (n < 320) { Prow = P2 + (size_t)(n - 256) * 1024; outp = proj2 + (n - 256); stride = 64; }
    else if (n < 336) { Prow = P3 + (size_t)(n - 320) * 1024; outp = proj3 + (n - 320); stride = 64; }
    else {  // zero-pad proj3 columns 16..63
        int idx = n - 320;
        for (int tok = 0; tok < 8; ++tok) proj3[(size_t)(t0 + tok) * 64 + idx] = 0;
        return;
    }
    float acc[8] = {0.f,0.f,0.f,0.f,0.f,0.f,0.f,0.f};
    for (int k = 0; k < 1024; k += 4) {
        float4 p = *(const float4*)(Prow + k);
#pragma unroll
        for (int tok = 0; tok < 8; ++tok)
            acc[tok] += p.x * h[tok][k] + p.y * h[tok][k+1] + p.z * h[tok][k+2] + p.w * h[tok][k+3];
    }
    for (int tok = 0; tok < 8; ++tok)
        outp[(size_t)(t0 + tok) * stride] = f2bf(acc[tok]);
}

// ---------- kernel 3: tiled bf16 MFMA GEMM with fused per-row (max, sumexp) partials ----------
// Partials layout: pM[nt * 1024 + token]  (contiguous per block -> full-line writes)
template<bool BF16B>
__global__ __launch_bounds__(256)
void gemm_lse(const unsigned short* __restrict__ A, int KP, int K, int KTILES,
              const unsigned short* __restrict__ B16,
              const float* __restrict__ B1f, int Nsplit,
              const float* __restrict__ B2, int N,
              const float* __restrict__ bias1, const float* __restrict__ bias2,
              float* __restrict__ pM, float* __restrict__ pS) {
    __shared__ __align__(16) char lds[32768];
    char* As = lds;
    char* Bs = lds + 16384;
    const int tid  = threadIdx.x;
    const int lane = tid & 63;
    const int wid  = tid >> 6;
    const int wm = wid >> 1, wn = wid & 1;          // 2x2 waves, each 64x64
    const int nt = blockIdx.x, mt = blockIdx.y;
    const int n0 = nt * 128, m0 = mt * 128;
    const bool clean = BF16B && (n0 + 128 <= Nsplit);

    f32x4 acc[4][4];
    const f32x4 zero = {0.f, 0.f, 0.f, 0.f};
#pragma unroll
    for (int i = 0; i < 4; ++i)
#pragma unroll
        for (int j = 0; j < 4; ++j) acc[i][j] = zero;

    for (int kt = 0; kt < KTILES; ++kt) {
        // ---- stage A tile [128][64] bf16 via global_load_lds (inverse-swizzled source) ----
#pragma unroll
        for (int j = 0; j < 4; ++j) {
            int lds_off = wid * 4096 + j * 1024;
            int o = lds_off + lane * 16;
            int r = o >> 7;                             // tile row 0..127
            int b = (o & 127) ^ ((r & 7) << 4);         // source byte within row
            gload_lds16(A + (size_t)(m0 + r) * KP + kt * 64 + (b >> 1), As + lds_off);
        }
        if (clean) {
            // ---- stage B tile from pre-converted bf16 weights ----
#pragma unroll
            for (int j = 0; j < 4; ++j) {
                int lds_off = wid * 4096 + j * 1024;
                int o = lds_off + lane * 16;
                int r = o >> 7;
                int b = (o & 127) ^ ((r & 7) << 4);
                gload_lds16(B16 + (size_t)(n0 + r) * K + kt * 64 + (b >> 1), Bs + lds_off);
            }
        } else {
            // ---- stage B tile from f32 (guarded, convert) ----
#pragma unroll
            for (int it = 0; it < 4; ++it) {
                int c = tid + it * 256;
                int row = c >> 3, kc = (c & 7) << 3;
                int n = n0 + row;
                int kg = kt * 64 + kc;
                float v[8] = {0.f,0.f,0.f,0.f,0.f,0.f,0.f,0.f};
                const float* rp = nullptr;
                if (n < Nsplit)      rp = B1f + (size_t)n * K;
                else if (n < N)      rp = B2 + (size_t)(n - Nsplit) * K;
                if (rp != nullptr) {
                    float4 u0 = *(const float4*)(rp + kg);
                    float4 u1 = *(const float4*)(rp + kg + 4);
                    v[0]=u0.x; v[1]=u0.y; v[2]=u0.z; v[3]=u0.w;
                    v[4]=u1.x; v[5]=u1.y; v[6]=u1.z; v[7]=u1.w;
                }
                unsigned short hh[8];
#pragma unroll
                for (int j = 0; j < 8; ++j) hh[j] = f2bf(v[j]);
                int off = (row * 128 + kc * 2) ^ ((row & 7) << 4);
                *(int4*)(Bs + off) = *(const int4*)hh;
            }
        }
        __syncthreads();
        // ---- compute: 2 k-slices x 4x4 fragments ----
#pragma unroll
        for (int kk = 0; kk < 2; ++kk) {
            const int kbyte = (kk * 32 + ((lane >> 4) << 3)) * 2;
            short8 a[4], b[4];
#pragma unroll
            for (int mi = 0; mi < 4; ++mi) {
                int row = wm * 64 + mi * 16 + (lane & 15);
                int off = (row * 128 + kbyte) ^ ((row & 7) << 4);
                a[mi] = *(const short8*)(As + off);
            }
#pragma unroll
            for (int ni = 0; ni < 4; ++ni) {
                int row = wn * 64 + ni * 16 + (lane & 15);
                int off = (row * 128 + kbyte) ^ ((row & 7) << 4);
                b[ni] = *(const short8*)(Bs + off);
            }
#pragma unroll
            for (int mi = 0; mi < 4; ++mi)
#pragma unroll
                for (int ni = 0; ni < 4; ++ni)
                    acc[mi][ni] = __builtin_amdgcn_mfma_f32_16x16x32_bf16(a[mi], b[ni], acc[mi][ni], 0, 0, 0);
        }
        __syncthreads();
    }

    // ---- epilogue: bias + per-row max & sumexp over this 128-col tile ----
    const int cl = lane & 15;
    float bv[4];
    bool  val[4];
#pragma unroll
    for (int ni = 0; ni < 4; ++ni) {
        int col = n0 + wn * 64 + ni * 16 + cl;
        val[ni] = (col < N);
        float b = 0.f;
        if (val[ni]) b = (col < Nsplit) ? bias1[col] : bias2[col - Nsplit];
        bv[ni] = b;
    }
    float rm[4][4], rs[4][4];
#pragma unroll
    for (int mi = 0; mi < 4; ++mi) {
#pragma unroll
        for (int r = 0; r < 4; ++r) {
            float mx = -INFINITY;
#pragma unroll
            for (int ni = 0; ni < 4; ++ni)
                if (val[ni]) mx = fmaxf(mx, acc[mi][ni][r] + bv[ni]);
#pragma unroll
            for (int msk = 1; msk < 16; msk <<= 1)
                mx = fmaxf(mx, __shfl_xor(mx, msk, 64));
            float sm = 0.f;
#pragma unroll
            for (int ni = 0; ni < 4; ++ni)
                if (val[ni]) sm += __expf(acc[mi][ni][r] + bv[ni] - mx);
#pragma unroll
            for (int msk = 1; msk < 16; msk <<= 1)
                sm += __shfl_xor(sm, msk, 64);
            rm[mi][r] = mx; rs[mi][r] = sm;
        }
    }
    float* red = (float*)lds;   // [2][128][2] (tile reads drained past last barrier)
    if (cl == 0) {
#pragma unroll
        for (int mi = 0; mi < 4; ++mi)
#pragma unroll
            for (int r = 0; r < 4; ++r) {
                int row = wm * 64 + mi * 16 + ((lane >> 4) << 2) + r;
                red[(wn * 128 + row) * 2 + 0] = rm[mi][r];
                red[(wn * 128 + row) * 2 + 1] = rs[mi][r];
            }
    }
    __syncthreads();
    if (tid < 128) {
        float m0v = red[(0 * 128 + tid) * 2 + 0];
        float s0v = red[(0 * 128 + tid) * 2 + 1];
        float m1v = red[(1 * 128 + tid) * 2 + 0];
        float s1v = red[(1 * 128 + tid) * 2 + 1];
        float M = fmaxf(m0v, m1v);
        float S = 0.f;
        if (s0v > 0.f) S += s0v * __expf(m0v - M);
        if (s1v > 0.f) S += s1v * __expf(m1v - M);
        size_t idx = (size_t)nt * 1024 + m0 + tid;     // tile-major: contiguous per block
        pM[idx] = M;
        pS[idx] = S;
    }
}

// ---------- kernel 3b: resident-B tail GEMM (K padded to 64), loops all 8 m-tiles ----------
// B [N][Kv] f32 staged+converted ONCE per block; partials pM[nt*1024 + token].
__global__ __launch_bounds__(256)
void tail_lse(const unsigned short* __restrict__ A,            // [1024][64] bf16
              const float* __restrict__ B, int Kv,             // [N][Kv] f32 (Kv<=64)
              int N, const float* __restrict__ bias,
              float* __restrict__ pM, float* __restrict__ pS) {
    __shared__ __align__(16) char Bs[16384];
    __shared__ __align__(16) char As[16384];
    __shared__ float red[2 * 128 * 2];
    const int tid  = threadIdx.x;
    const int lane = tid & 63;
    const int wid  = tid >> 6;
    const int wm = wid >> 1, wn = wid & 1;
    const int nt = blockIdx.x, n0 = nt * 128;

    // ---- stage B [128][64] once (f32 -> bf16, zero-pad k>=Kv, guard n>=N) ----
#pragma unroll
    for (int it = 0; it < 4; ++it) {
        int c = tid + it * 256;
        int row = c >> 3, kc = (c & 7) << 3;
        int n = n0 + row;
        float v[8] = {0.f,0.f,0.f,0.f,0.f,0.f,0.f,0.f};
        if (n < N && kc < Kv) {
            const float* rp = B + (size_t)n * Kv;
            float4 u0 = *(const float4*)(rp + kc);
            float4 u1 = *(const float4*)(rp + kc + 4);
            v[0]=u0.x; v[1]=u0.y; v[2]=u0.z; v[3]=u0.w;
            v[4]=u1.x; v[5]=u1.y; v[6]=u1.z; v[7]=u1.w;
        }
        unsigned short hh[8];
#pragma unroll
        for (int j = 0; j < 8; ++j) hh[j] = f2bf(v[j]);
        int off = (row * 128 + kc * 2) ^ ((row & 7) << 4);
        *(int4*)(Bs + off) = *(const int4*)hh;
    }
    __syncthreads();
    // ---- lift B fragments to registers (held across all m-tiles) ----
    short8 bfrag[2][4];
#pragma unroll
    for (int kk = 0; kk < 2; ++kk)
#pragma unroll
        for (int ni = 0; ni < 4; ++ni) {
            int row = wn * 64 + ni * 16 + (lane & 15);
            int kbyte = (kk * 32 + ((lane >> 4) << 3)) * 2;
            int off = (row * 128 + kbyte) ^ ((row & 7) << 4);
            bfrag[kk][ni] = *(const short8*)(Bs + off);
        }
    const int cl = lane & 15;
    float bv[4];
    bool  val[4];
#pragma unroll
    for (int ni = 0; ni < 4; ++ni) {
        int col = n0 + wn * 64 + ni * 16 + cl;
        val[ni] = (col < N);
        bv[ni] = val[ni] ? bias[col] : 0.f;
    }

    for (int mt = 0; mt < 8; ++mt) {
        __syncthreads();   // protect As & red from previous iteration
        // ---- stage A tile [128][64] via global_load_lds ----
#pragma unroll
        for (int j = 0; j < 4; ++j) {
            int lds_off = wid * 4096 + j * 1024;
            int o = lds_off + lane * 16;
            int r = o >> 7;
            int b = (o & 127) ^ ((r & 7) << 4);
            gload_lds16(A + (size_t)(mt * 128 + r) * 64 + (b >> 1), As + lds_off);
        }
        __syncthreads();
        f32x4 acc[4][4];
        const f32x4 zero = {0.f, 0.f, 0.f, 0.f};
#pragma unroll
        for (int i = 0; i < 4; ++i)
#pragma unroll
            for (int j = 0; j < 4; ++j) acc[i][j] = zero;
#pragma unroll
        for (int kk = 0; kk < 2; ++kk) {
            const int kbyte = (kk * 32 + ((lane >> 4) << 3)) * 2;
            short8 a[4];
#pragma unroll
            for (int mi = 0; mi < 4; ++mi) {
                int row = wm * 64 + mi * 16 + (lane & 15);
                int off = (row * 128 + kbyte) ^ ((row & 7) << 4);
                a[mi] = *(const short8*)(As + off);
            }
#pragma unroll
            for (int mi = 0; mi < 4; ++mi)
#pragma unroll
                for (int ni = 0; ni < 4; ++ni)
                    acc[mi][ni] = __builtin_amdgcn_mfma_f32_16x16x32_bf16(a[mi], bfrag[kk][ni], acc[mi][ni], 0, 0, 0);
        }
        // ---- per-mt epilogue ----
        float rm[4][4], rs[4][4];
#pragma unroll
        for (int mi = 0; mi < 4; ++mi) {
#pragma unroll
            for (int r = 0; r < 4; ++r) {
                float mx = -INFINITY;
#pragma unroll
                for (int ni = 0; ni < 4; ++ni)
                    if (val[ni]) mx = fmaxf(mx, acc[mi][ni][r] + bv[ni]);
#pragma unroll
                for (int msk = 1; msk < 16; msk <<= 1)
                    mx = fmaxf(mx, __shfl_xor(mx, msk, 64));
                float sm = 0.f;
#pragma unroll
                for (int ni = 0; ni < 4; ++ni)
                    if (val[ni]) sm += __expf(acc[mi][ni][r] + bv[ni] - mx);
#pragma unroll
                for (int msk = 1; msk < 16; msk <<= 1)
                    sm += __shfl_xor(sm, msk, 64);
                rm[mi][r] = mx; rs[mi][r] = sm;
            }
        }
        if (cl == 0) {
#pragma unroll
            for (int mi = 0; mi < 4; ++mi)
#pragma unroll
                for (int r = 0; r < 4; ++r) {
                    int row = wm * 64 + mi * 16 + ((lane >> 4) << 2) + r;
                    red[(wn * 128 + row) * 2 + 0] = rm[mi][r];
                    red[(wn * 128 + row) * 2 + 1] = rs[mi][r];
                }
        }
        __syncthreads();
        if (tid < 128) {
            float m0v = red[(0 * 128 + tid) * 2 + 0];
            float s0v = red[(0 * 128 + tid) * 2 + 1];
            float m1v = red[(1 * 128 + tid) * 2 + 0];
            float s1v = red[(1 * 128 + tid) * 2 + 1];
            float M = fmaxf(m0v, m1v);
            float S = 0.f;
            if (s0v > 0.f) S += s0v * __expf(m0v - M);
            if (s1v > 0.f) S += s1v * __expf(m1v - M);
            size_t idx = (size_t)nt * 1024 + mt * 128 + tid;
            pM[idx] = M;
            pS[idx] = S;
        }
    }
}

// ---------- kernel 4: fused per-cluster LSE reduce (tile-major partials) ----------
__global__ __launch_bounds__(256)
void reduce_all(const float* __restrict__ pMh, const float* __restrict__ pSh, int nth,
                const float* __restrict__ pM1, const float* __restrict__ pS1, int nt1,
                const float* __restrict__ pM2, const float* __restrict__ pS2, int nt2,
                const float* __restrict__ pM3, const float* __restrict__ pS3, int nt3,
                float* __restrict__ lse) {
    const int c = blockIdx.y;
    const float* PM = (c == 0) ? pMh : (c == 1) ? pM1 : (c == 2) ? pM2 : pM3;
    const float* PS = (c == 0) ? pSh : (c == 1) ? pS1 : (c == 2) ? pS2 : pS3;
    const int nt = (c == 0) ? nth : (c == 1) ? nt1 : (c == 2) ? nt2 : nt3;
    const int lane = threadIdx.x & 63;
    const int seg  = threadIdx.x >> 6;
    const int t = blockIdx.x * 64 + lane;
    float m = -INFINITY, s = 0.f;
    for (int i = seg; i < nt; i += 4) {
        float mi = PM[(size_t)i * 1024 + t];
        float si = PS[(size_t)i * 1024 + t];
        if (mi > m) { s = s * __expf(m - mi) + si; m = mi; }
        else if (si > 0.f) { s += si * __expf(mi - m); }
    }
    __shared__ float rm[4][64], rs[4][64];
    rm[seg][lane] = m; rs[seg][lane] = s;
    __syncthreads();
    if (seg == 0) {
#pragma unroll
        for (int q = 1; q < 4; ++q) {
            float om = rm[q][lane], os = rs[q][lane];
            if (om > m) { s = s * __expf(m - om) + os; m = om; }
            else if (os > 0.f) { s += os * __expf(om - m); }
        }
        lse[c * 1024 + t] = m + logf(s);
    }
}

// ---------- kernel 5: gather needed logits + assemble output ----------
__global__ void finalize(const float* __restrict__ hidden, const int* __restrict__ target,
                         const float* __restrict__ W_head, const float* __restrict__ b_head,
                         const float* __restrict__ W_clu, const float* __restrict__ b_clu,
                         const float* __restrict__ W1, const float* __restrict__ b1,
                         const float* __restrict__ W2, const float* __restrict__ b2,
                         const float* __restrict__ W3, const float* __restrict__ b3,
                         const unsigned short* __restrict__ proj1,
                         const unsigned short* __restrict__ proj2,
                         const unsigned short* __restrict__ proj3,
                         const float* __restrict__ lse,   // [4][1024]
                         float* __restrict__ out) {
    const int t = blockIdx.x;
    const int lane = threadIdx.x;
    const int tgt = target[t];
    const int cid = (tgt >= 20000) + (tgt >= 40000) + (tgt >= 200000);
    const int j = (cid == 0) ? tgt : (20003 - cid);
    const float* wr = (j < 20000) ? (W_head + (size_t)j * 1024)
                                  : (W_clu + (size_t)(j - 20000) * 1024);
    float acc = 0.f;
#pragma unroll
    for (int i = 0; i < 4; ++i) {
        int k4 = lane + i * 64;
        float4 h = *(const float4*)(hidden + (size_t)t * 1024 + k4 * 4);
        float4 w = *(const float4*)(wr + k4 * 4);
        acc += h.x * w.x + h.y * w.y + h.z * w.z + h.w * w.w;
    }
#pragma unroll
    for (int msk = 1; msk < 64; msk <<= 1) acc += __shfl_xor(acc, msk, 64);
    float bj = (j < 20000) ? b_head[j] : b_clu[j - 20000];
    float res = (acc + bj) - lse[t];
    if (cid > 0) {
        const int starts[4] = {0, 20000, 40000, 200000};
        const int dims[4]   = {0, 256, 64, 16};
        const float* Wt = (cid == 1) ? W1 : (cid == 2) ? W2 : W3;
        const float* bt = (cid == 1) ? b1 : (cid == 2) ? b2 : b3;
        const unsigned short* pr = (cid == 1) ? proj1 + (size_t)t * 256
                                 : (cid == 2) ? proj2 + (size_t)t * 64
                                              : proj3 + (size_t)t * 64;
        int ti = tgt - starts[cid];
        int d  = dims[cid];
        const float* wt = Wt + (size_t)ti * d;
        float a2 = 0.f;
        for (int k = lane; k < d; k += 64) a2 += bf2f(pr[k]) * wt[k];
#pragma unroll
        for (int msk = 1; msk < 64; msk <<= 1) a2 += __shfl_xor(a2, msk, 64);
        res += (a2 + bt[ti]) - lse[cid * 1024 + t];
    }
    if (lane == 0) out[t] = -res;
}

// ---------- launch ----------
extern "C" void kernel_launch(void* const* d_in, const int* in_sizes, int n_in,
                              void* d_out, int out_size, void* d_ws, size_t ws_size,
                              hipStream_t stream) {
    const float* hidden = (const float*)d_in[0];
    const int*   target = (const int*)d_in[1];
    const float* W_head = (const float*)d_in[2];
    const float* b_head = (const float*)d_in[3];
    const float* W_clu  = (const float*)d_in[4];
    const float* b_clu  = (const float*)d_in[5];
    const float* P1 = (const float*)d_in[6];
    const float* W1 = (const float*)d_in[7];
    const float* b1 = (const float*)d_in[8];
    const float* P2 = (const float*)d_in[9];
    const float* W2 = (const float*)d_in[10];
    const float* b2 = (const float*)d_in[11];
    const float* P3 = (const float*)d_in[12];
    const float* W3 = (const float*)d_in[13];
    const float* b3 = (const float*)d_in[14];
    float* out = (float*)d_out;

    char* ws = (char*)d_ws;
    size_t off = 0;
    auto alloc = [&](size_t bytes) -> char* {
        char* p = ws + off;
        off += (bytes + 255) & ~(size_t)255;
        return p;
    };
    const int NT_H = 157;   // ceil(20003/128)
    const int NT_1 = 157;   // ceil(20000/128)
    const int NT_2 = 1250;  // 160000/128
    const int NT_3 = 530;   // ceil(67735/128)

    unsigned short* hbf   = (unsigned short*)alloc((size_t)1024 * 1024 * 2);
    unsigned short* proj1 = (unsigned short*)alloc((size_t)1024 * 256 * 2);
    unsigned short* proj2 = (unsigned short*)alloc((size_t)1024 * 64 * 2);
    unsigned short* proj3 = (unsigned short*)alloc((size_t)1024 * 64 * 2);
    float* pMh = (float*)alloc((size_t)1024 * NT_H * 4);
    float* pSh = (float*)alloc((size_t)1024 * NT_H * 4);
    float* pM1 = (float*)alloc((size_t)1024 * NT_1 * 4);
    float* pS1 = (float*)alloc((size_t)1024 * NT_1 * 4);
    float* pM2 = (float*)alloc((size_t)1024 * NT_2 * 4);
    float* pS2 = (float*)alloc((size_t)1024 * NT_2 * 4);
    float* pM3 = (float*)alloc((size_t)1024 * NT_3 * 4);
    float* pS3 = (float*)alloc((size_t)1024 * NT_3 * 4);
    float* lse = (float*)alloc((size_t)4 * 1024 * 4);
    // optional bf16 weight mirrors (last, so fallback stays in-bounds)
    unsigned short* Whb = (unsigned short*)alloc((size_t)20000 * 1024 * 2);
    unsigned short* W1b = (unsigned short*)alloc((size_t)20000 * 256 * 2);
    const bool pre = (off <= ws_size);

    convert_hidden<<<1024, 256, 0, stream>>>(hidden, hbf);
    proj_kernel<<<128, 384, 0, stream>>>(hidden, P1, P2, P3, proj1, proj2, proj3);
    if (pre) {
        convert_w<<<(5120000 + 255) / 256, 256, 0, stream>>>(W_head, Whb, 5120000);
        convert_w<<<(1280000 + 255) / 256, 256, 0, stream>>>(W1, W1b, 1280000);
        gemm_lse<true><<<dim3(NT_H, 8), 256, 0, stream>>>(hbf, 1024, 1024, 16,
                                                          Whb, W_head, 20000, W_clu, 20003,
                                                          b_head, b_clu, pMh, pSh);
        gemm_lse<true><<<dim3(NT_1, 8), 256, 0, stream>>>(proj1, 256, 256, 4,
                                                          W1b, W1, 20000, nullptr, 20000,
                                                          b1, nullptr, pM1, pS1);
    } else {
        gemm_lse<false><<<dim3(NT_H, 8), 256, 0, stream>>>(hbf, 1024, 1024, 16,
                                                           nullptr, W_head, 20000, W_clu, 20003,
                                                           b_head, b_clu, pMh, pSh);
        gemm_lse<false><<<dim3(NT_1, 8), 256, 0, stream>>>(proj1, 256, 256, 4,
                                                           nullptr, W1, 20000, nullptr, 20000,
                                                           b1, nullptr, pM1, pS1);
    }
    tail_lse<<<NT_2, 256, 0, stream>>>(proj2, W2, 64, 160000, b2, pM2, pS2);
    tail_lse<<<NT_3, 256, 0, stream>>>(proj3, W3, 16, 67735, b3, pM3, pS3);

    reduce_all<<<dim3(16, 4), 256, 0, stream>>>(pMh, pSh, NT_H,
                                                pM1, pS1, NT_1,
                                                pM2, pS2, NT_2,
                                                pM3, pS3, NT_3, lse);

    finalize<<<1024, 64, 0, stream>>>(hidden, target,
                                      W_head, b_head, W_clu, b_clu,
                                      W1, b1, W2, b2, W3, b3,
                                      proj1, proj2, proj3, lse, out);
}

// Round 3
// 416.941 us; speedup vs baseline: 1.2844x; 1.2844x over previous
//
#include <hip/hip_runtime.h>
#include <cstdint>
#include <cstddef>

// ---------- types ----------
typedef __attribute__((ext_vector_type(8))) short short8;   // 8 x bf16 (4 VGPR)
typedef __attribute__((ext_vector_type(4))) float f32x4;

__device__ __forceinline__ unsigned short f2bf(float x) {
    unsigned u = __float_as_uint(x);
    u += 0x7FFFu + ((u >> 16) & 1u);        // RNE
    return (unsigned short)(u >> 16);
}
__device__ __forceinline__ float bf2f(unsigned short h) {
    return __uint_as_float(((unsigned)h) << 16);
}

// async global->LDS, 16B per lane; LDS dest = uniform base + lane*16
__device__ __forceinline__ void gload_lds16(const void* g, void* l) {
    __builtin_amdgcn_global_load_lds(
        (const __attribute__((address_space(1))) unsigned int*)g,
        (__attribute__((address_space(3))) unsigned int*)l, 16, 0, 0);
}

// ---------- kernel 1a: f32 -> bf16 hidden (exact grid) ----------
__global__ void convert_hidden(const float* __restrict__ in, unsigned short* __restrict__ out) {
    int i = blockIdx.x * 256 + threadIdx.x;           // 262144 float4 total
    float4 v = *(const float4*)(in + (size_t)i * 4);
    unsigned long long p = (unsigned long long)f2bf(v.x)
                         | ((unsigned long long)f2bf(v.y) << 16)
                         | ((unsigned long long)f2bf(v.z) << 32)
                         | ((unsigned long long)f2bf(v.w) << 48);
    *(unsigned long long*)(out + (size_t)i * 4) = p;
}

// ---------- kernel 1b: generic f32 -> bf16 (n4 float4 chunks) ----------
__global__ void convert_w(const float* __restrict__ in, unsigned short* __restrict__ out, int n4) {
    int i = blockIdx.x * 256 + threadIdx.x;
    if (i >= n4) return;
    float4 v = *(const float4*)(in + (size_t)i * 4);
    unsigned long long p = (unsigned long long)f2bf(v.x)
                         | ((unsigned long long)f2bf(v.y) << 16)
                         | ((unsigned long long)f2bf(v.z) << 32)
                         | ((unsigned long long)f2bf(v.w) << 48);
    *(unsigned long long*)(out + (size_t)i * 4) = p;
}

// ---------- kernel 2: proj_i = hidden @ P_i^T  (bf16 out, proj3 zero-padded to 64) ----------
__global__ __launch_bounds__(384)
void proj_kernel(const float* __restrict__ hidden,
                 const float* __restrict__ P1, const float* __restrict__ P2,
                 const float* __restrict__ P3,
                 unsigned short* __restrict__ proj1, unsigned short* __restrict__ proj2,
                 unsigned short* __restrict__ proj3) {
    __shared__ __align__(16) float h[8][1024];
    const int t0 = blockIdx.x * 8;
    const int tid = threadIdx.x;
    for (int f = tid; f < 2048; f += 384) {
        int tok = f >> 8, pos = (f & 255) * 4;
        *(float4*)&h[tok][pos] = *(const float4*)(hidden + (size_t)(t0 + tok) * 1024 + pos);
    }
    __syncthreads();
    const int n = tid;
    const float* Prow;
    unsigned short* outp;
    int stride;
    if (n < 256)      { Prow = P1 + (size_t)n * 1024;        outp = proj1 + n;        stride = 256; }
    else if (n < 320) { Prow = P2 + (size_t)(n - 256) * 1024; outp = proj2 + (n - 256); stride = 64; }
    else if (n < 336) { Prow = P3 + (size_t)(n - 320) * 1024; outp = proj3 + (n - 320); stride = 64; }
    else {  // zero-pad proj3 columns 16..63
        int idx = n - 320;
        for (int tok = 0; tok < 8; ++tok) proj3[(size_t)(t0 + tok) * 64 + idx] = 0;
        return;
    }
    float acc[8] = {0.f,0.f,0.f,0.f,0.f,0.f,0.f,0.f};
    for (int k = 0; k < 1024; k += 4) {
        float4 p = *(const float4*)(Prow + k);
#pragma unroll
        for (int tok = 0; tok < 8; ++tok)
            acc[tok] += p.x * h[tok][k] + p.y * h[tok][k+1] + p.z * h[tok][k+2] + p.w * h[tok][k+3];
    }
    for (int tok = 0; tok < 8; ++tok)
        outp[(size_t)(t0 + tok) * stride] = f2bf(acc[tok]);
}

// ---------- kernel 3: swapped-operand GEMM + fused LSE partials ----------
// C[v][t] = sum_k W[v][k] * H[t][k] + bias[v]
// MFMA: A-operand = W rows (vocab), B-operand = H rows (tokens).
// C/D layout: row (lane>>4)*4+reg = vocab, col lane&15 = token -> softmax axis
// (vocab) is lane-local within a 64-row strip; only 2 shuffles per token.
// Grid: (tt=8 token tiles of 128, nt = vocab tiles of 128); tt is the fast
// axis so blocks sharing a W tile are dispatch-adjacent (L2/L3 locality).
// Partials: pM[nt*1024 + token] (contiguous 512B per block write).
template<bool BF16B>
__global__ __launch_bounds__(256)
void gemm_lse_t(const unsigned short* __restrict__ Wb,  // bf16 [Nsplit][K]  (BF16B)
                const float* __restrict__ Wfa,          // f32 [Nsplit][Kv]  (!BF16B)
                const float* __restrict__ Wfb,          // f32 [N-Nsplit][K] extra rows (may be null)
                int Nsplit, int N, int K, int Kv, int KTILES,
                const float* __restrict__ bias1, const float* __restrict__ bias2,
                const unsigned short* __restrict__ H,   // bf16 [1024][K]
                float* __restrict__ pM, float* __restrict__ pS) {
    __shared__ __align__(16) char Ws[16384];
    __shared__ __align__(16) char Hs[16384];
    __shared__ float bias_s[128];
    __shared__ float red[2][128][2];
    const int tid  = threadIdx.x;
    const int lane = tid & 63;
    const int wid  = tid >> 6;
    const int wm = wid >> 1, wn = wid & 1;          // wm: vocab strip, wn: token strip
    const int tt = blockIdx.x, nt = blockIdx.y;
    const int t0 = tt * 128, n0 = nt * 128;
    const bool clean = BF16B && (n0 + 128 <= Nsplit);

    // stage bias (+ -inf for invalid rows; makes epilogue branch-free)
    if (tid < 128) {
        int v = n0 + tid;
        float b;
        if (v < Nsplit)      b = bias1[v];
        else if (v < N)      b = bias2[v - Nsplit];
        else                 b = -INFINITY;
        bias_s[tid] = b;
    }

    f32x4 acc[4][4];
    const f32x4 zero = {0.f, 0.f, 0.f, 0.f};
#pragma unroll
    for (int i = 0; i < 4; ++i)
#pragma unroll
        for (int j = 0; j < 4; ++j) acc[i][j] = zero;

    for (int kt = 0; kt < KTILES; ++kt) {
        // ---- stage W tile [128][64] ----
        if (clean) {
#pragma unroll
            for (int j = 0; j < 4; ++j) {
                int lds_off = wid * 4096 + j * 1024;
                int o = lds_off + lane * 16;
                int r = o >> 7;                          // tile row
                int b = (o & 127) ^ ((r & 7) << 4);      // inverse-swizzled source byte
                gload_lds16(Wb + (size_t)(n0 + r) * K + kt * 64 + (b >> 1), Ws + lds_off);
            }
        } else {
#pragma unroll
            for (int it = 0; it < 4; ++it) {
                int c = tid + it * 256;
                int row = c >> 3, kc = (c & 7) << 3;
                int v = n0 + row;
                int kg = kt * 64 + kc;
                unsigned short hh[8] = {0,0,0,0,0,0,0,0};
                if (v < Nsplit) {
                    if (BF16B) {
                        *(int4*)hh = *(const int4*)(Wb + (size_t)v * K + kg);
                    } else if (kg + 8 <= Kv) {
                        const float* p = Wfa + (size_t)v * Kv;
                        float4 u0 = *(const float4*)(p + kg);
                        float4 u1 = *(const float4*)(p + kg + 4);
                        hh[0]=f2bf(u0.x); hh[1]=f2bf(u0.y); hh[2]=f2bf(u0.z); hh[3]=f2bf(u0.w);
                        hh[4]=f2bf(u1.x); hh[5]=f2bf(u1.y); hh[6]=f2bf(u1.z); hh[7]=f2bf(u1.w);
                    }
                } else if (v < N && Wfb != nullptr) {
                    const float* p = Wfb + (size_t)(v - Nsplit) * K;
                    float4 u0 = *(const float4*)(p + kg);
                    float4 u1 = *(const float4*)(p + kg + 4);
                    hh[0]=f2bf(u0.x); hh[1]=f2bf(u0.y); hh[2]=f2bf(u0.z); hh[3]=f2bf(u0.w);
                    hh[4]=f2bf(u1.x); hh[5]=f2bf(u1.y); hh[6]=f2bf(u1.z); hh[7]=f2bf(u1.w);
                }
                int off = (row * 128 + kc * 2) ^ ((row & 7) << 4);
                *(int4*)(Ws + off) = *(const int4*)hh;
            }
        }
        // ---- stage H tile [128][64] (always bf16, always valid rows) ----
#pragma unroll
        for (int j = 0; j < 4; ++j) {
            int lds_off = wid * 4096 + j * 1024;
            int o = lds_off + lane * 16;
            int r = o >> 7;
            int b = (o & 127) ^ ((r & 7) << 4);
            gload_lds16(H + (size_t)(t0 + r) * K + kt * 64 + (b >> 1), Hs + lds_off);
        }
        __syncthreads();
        // ---- compute: 2 k-slices, a = W frags (vocab), b = H frags (tokens) ----
#pragma unroll
        for (int kk = 0; kk < 2; ++kk) {
            const int kbyte = (kk * 32 + ((lane >> 4) << 3)) * 2;
            short8 a[4], b[4];
#pragma unroll
            for (int mi = 0; mi < 4; ++mi) {
                int row = wm * 64 + mi * 16 + (lane & 15);
                int off = (row * 128 + kbyte) ^ ((row & 7) << 4);
                a[mi] = *(const short8*)(Ws + off);
            }
#pragma unroll
            for (int ni = 0; ni < 4; ++ni) {
                int row = wn * 64 + ni * 16 + (lane & 15);
                int off = (row * 128 + kbyte) ^ ((row & 7) << 4);
                b[ni] = *(const short8*)(Hs + off);
            }
#pragma unroll
            for (int mi = 0; mi < 4; ++mi)
#pragma unroll
                for (int ni = 0; ni < 4; ++ni)
                    acc[mi][ni] = __builtin_amdgcn_mfma_f32_16x16x32_bf16(a[mi], b[ni], acc[mi][ni], 0, 0, 0);
        }
        __syncthreads();
    }

    // ---- epilogue: lane-local vocab reduce ----
    float bvv[4][4];
#pragma unroll
    for (int mi = 0; mi < 4; ++mi)
#pragma unroll
        for (int r = 0; r < 4; ++r)
            bvv[mi][r] = bias_s[wm * 64 + mi * 16 + ((lane >> 4) << 2) + r];
#pragma unroll
    for (int mi = 0; mi < 4; ++mi)
#pragma unroll
        for (int ni = 0; ni < 4; ++ni)
#pragma unroll
            for (int r = 0; r < 4; ++r)
                acc[mi][ni][r] += bvv[mi][r];

#pragma unroll
    for (int ni = 0; ni < 4; ++ni) {
        float mx = -INFINITY;
#pragma unroll
        for (int mi = 0; mi < 4; ++mi)
#pragma unroll
            for (int r = 0; r < 4; ++r)
                mx = fmaxf(mx, acc[mi][ni][r]);
        mx = fmaxf(mx, __shfl_xor(mx, 16, 64));
        mx = fmaxf(mx, __shfl_xor(mx, 32, 64));
        float mxe = (mx == -INFINITY) ? 0.f : mx;   // all-invalid strip guard
        float sm = 0.f;
#pragma unroll
        for (int mi = 0; mi < 4; ++mi)
#pragma unroll
            for (int r = 0; r < 4; ++r)
                sm += __expf(acc[mi][ni][r] - mxe);
        sm += __shfl_xor(sm, 16, 64);
        sm += __shfl_xor(sm, 32, 64);
        if ((lane >> 4) == 0) {
            int tloc = wn * 64 + ni * 16 + lane;    // lane == lane&15 here
            red[wm][tloc][0] = mx;
            red[wm][tloc][1] = sm;
        }
    }
    __syncthreads();
    if (tid < 128) {
        float m0v = red[0][tid][0], s0v = red[0][tid][1];
        float m1v = red[1][tid][0], s1v = red[1][tid][1];
        float M = fmaxf(m0v, m1v);
        float S = 0.f;
        if (s0v > 0.f) S += s0v * __expf(m0v - M);
        if (s1v > 0.f) S += s1v * __expf(m1v - M);
        size_t idx = (size_t)nt * 1024 + t0 + tid;
        pM[idx] = M;
        pS[idx] = S;
    }
}

// ---------- kernel 4: fused per-cluster LSE reduce (tile-major partials) ----------
__global__ __launch_bounds__(256)
void reduce_all(const float* __restrict__ pMh, const float* __restrict__ pSh, int nth,
                const float* __restrict__ pM1, const float* __restrict__ pS1, int nt1,
                const float* __restrict__ pM2, const float* __restrict__ pS2, int nt2,
                const float* __restrict__ pM3, const float* __restrict__ pS3, int nt3,
                float* __restrict__ lse) {
    const int c = blockIdx.y;
    const float* PM = (c == 0) ? pMh : (c == 1) ? pM1 : (c == 2) ? pM2 : pM3;
    const float* PS = (c == 0) ? pSh : (c == 1) ? pS1 : (c == 2) ? pS2 : pS3;
    const int nt = (c == 0) ? nth : (c == 1) ? nt1 : (c == 2) ? nt2 : nt3;
    const int lane = threadIdx.x & 63;
    const int seg  = threadIdx.x >> 6;
    const int t = blockIdx.x * 64 + lane;
    float m = -INFINITY, s = 0.f;
    for (int i = seg; i < nt; i += 4) {
        float mi = PM[(size_t)i * 1024 + t];
        float si = PS[(size_t)i * 1024 + t];
        if (mi > m) { s = s * __expf(m - mi) + si; m = mi; }
        else if (si > 0.f) { s += si * __expf(mi - m); }
    }
    __shared__ float rm[4][64], rs[4][64];
    rm[seg][lane] = m; rs[seg][lane] = s;
    __syncthreads();
    if (seg == 0) {
#pragma unroll
        for (int q = 1; q < 4; ++q) {
            float om = rm[q][lane], os = rs[q][lane];
            if (om > m) { s = s * __expf(m - om) + os; m = om; }
            else if (os > 0.f) { s += os * __expf(om - m); }
        }
        lse[c * 1024 + t] = m + logf(s);
    }
}

// ---------- kernel 5: gather needed logits + assemble output ----------
__global__ void finalize(const float* __restrict__ hidden, const int* __restrict__ target,
                         const float* __restrict__ W_head, const float* __restrict__ b_head,
                         const float* __restrict__ W_clu, const float* __restrict__ b_clu,
                         const float* __restrict__ W1, const float* __restrict__ b1,
                         const float* __restrict__ W2, const float* __restrict__ b2,
                         const float* __restrict__ W3, const float* __restrict__ b3,
                         const unsigned short* __restrict__ proj1,
                         const unsigned short* __restrict__ proj2,
                         const unsigned short* __restrict__ proj3,
                         const float* __restrict__ lse,   // [4][1024]
                         float* __restrict__ out) {
    const int t = blockIdx.x;
    const int lane = threadIdx.x;
    const int tgt = target[t];
    const int cid = (tgt >= 20000) + (tgt >= 40000) + (tgt >= 200000);
    const int j = (cid == 0) ? tgt : (20003 - cid);
    const float* wr = (j < 20000) ? (W_head + (size_t)j * 1024)
                                  : (W_clu + (size_t)(j - 20000) * 1024);
    float acc = 0.f;
#pragma unroll
    for (int i = 0; i < 4; ++i) {
        int k4 = lane + i * 64;
        float4 h = *(const float4*)(hidden + (size_t)t * 1024 + k4 * 4);
        float4 w = *(const float4*)(wr + k4 * 4);
        acc += h.x * w.x + h.y * w.y + h.z * w.z + h.w * w.w;
    }
#pragma unroll
    for (int msk = 1; msk < 64; msk <<= 1) acc += __shfl_xor(acc, msk, 64);
    float bj = (j < 20000) ? b_head[j] : b_clu[j - 20000];
    float res = (acc + bj) - lse[t];
    if (cid > 0) {
        const int starts[4] = {0, 20000, 40000, 200000};
        const int dims[4]   = {0, 256, 64, 16};
        const float* Wt = (cid == 1) ? W1 : (cid == 2) ? W2 : W3;
        const float* bt = (cid == 1) ? b1 : (cid == 2) ? b2 : b3;
        const unsigned short* pr = (cid == 1) ? proj1 + (size_t)t * 256
                                 : (cid == 2) ? proj2 + (size_t)t * 64
                                              : proj3 + (size_t)t * 64;
        int ti = tgt - starts[cid];
        int d  = dims[cid];
        const float* wt = Wt + (size_t)ti * d;
        float a2 = 0.f;
        for (int k = lane; k < d; k += 64) a2 += bf2f(pr[k]) * wt[k];
#pragma unroll
        for (int msk = 1; msk < 64; msk <<= 1) a2 += __shfl_xor(a2, msk, 64);
        res += (a2 + bt[ti]) - lse[cid * 1024 + t];
    }
    if (lane == 0) out[t] = -res;
}

// ---------- launch ----------
extern "C" void kernel_launch(void* const* d_in, const int* in_sizes, int n_in,
                              void* d_out, int out_size, void* d_ws, size_t ws_size,
                              hipStream_t stream) {
    const float* hidden = (const float*)d_in[0];
    const int*   target = (const int*)d_in[1];
    const float* W_head = (const float*)d_in[2];
    const float* b_head = (const float*)d_in[3];
    const float* W_clu  = (const float*)d_in[4];
    const float* b_clu  = (const float*)d_in[5];
    const float* P1 = (const float*)d_in[6];
    const float* W1 = (const float*)d_in[7];
    const float* b1 = (const float*)d_in[8];
    const float* P2 = (const float*)d_in[9];
    const float* W2 = (const float*)d_in[10];
    const float* b2 = (const float*)d_in[11];
    const float* P3 = (const float*)d_in[12];
    const float* W3 = (const float*)d_in[13];
    const float* b3 = (const float*)d_in[14];
    float* out = (float*)d_out;

    char* ws = (char*)d_ws;
    size_t off = 0;
    auto alloc = [&](size_t bytes) -> char* {
        char* p = ws + off;
        off += (bytes + 255) & ~(size_t)255;
        return p;
    };
    const int NT_H = 157;   // ceil(20003/128)
    const int NT_1 = 157;   // ceil(20000/128)
    const int NT_2 = 1250;  // 160000/128
    const int NT_3 = 530;   // ceil(67735/128)

    unsigned short* hbf   = (unsigned short*)alloc((size_t)1024 * 1024 * 2);
    unsigned short* proj1 = (unsigned short*)alloc((size_t)1024 * 256 * 2);
    unsigned short* proj2 = (unsigned short*)alloc((size_t)1024 * 64 * 2);
    unsigned short* proj3 = (unsigned short*)alloc((size_t)1024 * 64 * 2);
    float* pMh = (float*)alloc((size_t)1024 * NT_H * 4);
    float* pSh = (float*)alloc((size_t)1024 * NT_H * 4);
    float* pM1 = (float*)alloc((size_t)1024 * NT_1 * 4);
    float* pS1 = (float*)alloc((size_t)1024 * NT_1 * 4);
    float* pM2 = (float*)alloc((size_t)1024 * NT_2 * 4);
    float* pS2 = (float*)alloc((size_t)1024 * NT_2 * 4);
    float* pM3 = (float*)alloc((size_t)1024 * NT_3 * 4);
    float* pS3 = (float*)alloc((size_t)1024 * NT_3 * 4);
    float* lse = (float*)alloc((size_t)4 * 1024 * 4);
    // optional bf16 weight mirrors (last, so fallback stays in-bounds)
    unsigned short* Whb = (unsigned short*)alloc((size_t)20000 * 1024 * 2);
    unsigned short* W1b = (unsigned short*)alloc((size_t)20000 * 256 * 2);
    const bool pre = (off <= ws_size);

    convert_hidden<<<1024, 256, 0, stream>>>(hidden, hbf);
    proj_kernel<<<128, 384, 0, stream>>>(hidden, P1, P2, P3, proj1, proj2, proj3);
    if (pre) {
        convert_w<<<(5120000 + 255) / 256, 256, 0, stream>>>(W_head, Whb, 5120000);
        convert_w<<<(1280000 + 255) / 256, 256, 0, stream>>>(W1, W1b, 1280000);
        gemm_lse_t<true><<<dim3(8, NT_H), 256, 0, stream>>>(
            Whb, nullptr, W_clu, 20000, 20003, 1024, 1024, 16,
            b_head, b_clu, hbf, pMh, pSh);
        gemm_lse_t<true><<<dim3(8, NT_1), 256, 0, stream>>>(
            W1b, nullptr, nullptr, 20000, 20000, 256, 256, 4,
            b1, nullptr, proj1, pM1, pS1);
    } else {
        gemm_lse_t<false><<<dim3(8, NT_H), 256, 0, stream>>>(
            nullptr, W_head, W_clu, 20000, 20003, 1024, 1024, 16,
            b_head, b_clu, hbf, pMh, pSh);
        gemm_lse_t<false><<<dim3(8, NT_1), 256, 0, stream>>>(
            nullptr, W1, nullptr, 20000, 20000, 256, 256, 4,
            b1, nullptr, proj1, pM1, pS1);
    }
    gemm_lse_t<false><<<dim3(8, NT_2), 256, 0, stream>>>(
        nullptr, W2, nullptr, 160000, 160000, 64, 64, 1,
        b2, nullptr, proj2, pM2, pS2);
    gemm_lse_t<false><<<dim3(8, NT_3), 256, 0, stream>>>(
        nullptr, W3, nullptr, 67735, 67735, 64, 16, 1,
        b3, nullptr, proj3, pM3, pS3);

    reduce_all<<<dim3(16, 4), 256, 0, stream>>>(pMh, pSh, NT_H,
                                                pM1, pS1, NT_1,
                                                pM2, pS2, NT_2,
                                                pM3, pS3, NT_3, lse);

    finalize<<<1024, 64, 0, stream>>>(hidden, target,
                                      W_head, b_head, W_clu, b_clu,
                                      W1, b1, W2, b2, W3, b3,
                                      proj1, proj2, proj3, lse, out);
}

// Round 4
// 306.454 us; speedup vs baseline: 1.7475x; 1.3605x over previous
//
#include <hip/hip_runtime.h>
#include <cstdint>
#include <cstddef>

// ---------- types ----------
typedef __attribute__((ext_vector_type(8))) short short8;   // 8 x bf16 (4 VGPR)
typedef __attribute__((ext_vector_type(4))) float f32x4;

__device__ __forceinline__ unsigned short f2bf(float x) {
    unsigned u = __float_as_uint(x);
    u += 0x7FFFu + ((u >> 16) & 1u);        // RNE
    return (unsigned short)(u >> 16);
}
__device__ __forceinline__ float bf2f(unsigned short h) {
    return __uint_as_float(((unsigned)h) << 16);
}

// async global->LDS, 16B per lane; LDS dest = uniform base + lane*16
__device__ __forceinline__ void gload_lds16(const void* g, void* l) {
    __builtin_amdgcn_global_load_lds(
        (const __attribute__((address_space(1))) unsigned int*)g,
        (__attribute__((address_space(3))) unsigned int*)l, 16, 0, 0);
}

// ---------- kernel 1a: f32 -> bf16 hidden (exact grid) ----------
__global__ void convert_hidden(const float* __restrict__ in, unsigned short* __restrict__ out) {
    int i = blockIdx.x * 256 + threadIdx.x;           // 262144 float4 total
    float4 v = *(const float4*)(in + (size_t)i * 4);
    unsigned long long p = (unsigned long long)f2bf(v.x)
                         | ((unsigned long long)f2bf(v.y) << 16)
                         | ((unsigned long long)f2bf(v.z) << 32)
                         | ((unsigned long long)f2bf(v.w) << 48);
    *(unsigned long long*)(out + (size_t)i * 4) = p;
}

// ---------- kernel 1b: generic f32 -> bf16 (n4 float4 chunks) ----------
__global__ void convert_w(const float* __restrict__ in, unsigned short* __restrict__ out, int n4) {
    int i = blockIdx.x * 256 + threadIdx.x;
    if (i >= n4) return;
    float4 v = *(const float4*)(in + (size_t)i * 4);
    unsigned long long p = (unsigned long long)f2bf(v.x)
                         | ((unsigned long long)f2bf(v.y) << 16)
                         | ((unsigned long long)f2bf(v.z) << 32)
                         | ((unsigned long long)f2bf(v.w) << 48);
    *(unsigned long long*)(out + (size_t)i * 4) = p;
}

// ---------- kernel 1c: f32 [N][16] -> bf16 [N][64] zero-padded ----------
// One thread per 8-bf16 output chunk (16B... actually 8 elems = 16 bytes? 8*2=16B).
// chunks per row = 8; chunk c<2 -> convert in[r][c*8..+7]; else zeros.
__global__ void convert_pad16to64(const float* __restrict__ in, unsigned short* __restrict__ out,
                                  int nrows) {
    int idx = blockIdx.x * 256 + threadIdx.x;
    int r = idx >> 3, c = idx & 7;
    if (r >= nrows) return;
    unsigned long long p0 = 0ull, p1 = 0ull;
    if (c < 2) {
        const float* rp = in + (size_t)r * 16 + c * 8;
        float4 u0 = *(const float4*)(rp);
        float4 u1 = *(const float4*)(rp + 4);
        p0 = (unsigned long long)f2bf(u0.x) | ((unsigned long long)f2bf(u0.y) << 16)
           | ((unsigned long long)f2bf(u0.z) << 32) | ((unsigned long long)f2bf(u0.w) << 48);
        p1 = (unsigned long long)f2bf(u1.x) | ((unsigned long long)f2bf(u1.y) << 16)
           | ((unsigned long long)f2bf(u1.z) << 32) | ((unsigned long long)f2bf(u1.w) << 48);
    }
    unsigned long long* op = (unsigned long long*)(out + (size_t)r * 64 + c * 8);
    op[0] = p0;
    op[1] = p1;
}

// ---------- kernel 2: proj_i = hidden @ P_i^T  (bf16 out, proj3 zero-padded to 64) ----------
__global__ __launch_bounds__(384)
void proj_kernel(const float* __restrict__ hidden,
                 const float* __restrict__ P1, const float* __restrict__ P2,
                 const float* __restrict__ P3,
                 unsigned short* __restrict__ proj1, unsigned short* __restrict__ proj2,
                 unsigned short* __restrict__ proj3) {
    __shared__ __align__(16) float h[8][1024];
    const int t0 = blockIdx.x * 8;
    const int tid = threadIdx.x;
    for (int f = tid; f < 2048; f += 384) {
        int tok = f >> 8, pos = (f & 255) * 4;
        *(float4*)&h[tok][pos] = *(const float4*)(hidden + (size_t)(t0 + tok) * 1024 + pos);
    }
    __syncthreads();
    const int n = tid;
    const float* Prow;
    unsigned short* outp;
    int stride;
    if (n < 256)      { Prow = P1 + (size_t)n * 1024;        outp = proj1 + n;        stride = 256; }
    else if (n < 320) { Prow = P2 + (size_t)(n - 256) * 1024; outp = proj2 + (n - 256); stride = 64; }
    else if (n < 336) { Prow = P3 + (size_t)(n - 320) * 1024; outp = proj3 + (n - 320); stride = 64; }
    else {  // zero-pad proj3 columns 16..63
        int idx = n - 320;
        for (int tok = 0; tok < 8; ++tok) proj3[(size_t)(t0 + tok) * 64 + idx] = 0;
        return;
    }
    float acc[8] = {0.f,0.f,0.f,0.f,0.f,0.f,0.f,0.f};
    for (int k = 0; k < 1024; k += 4) {
        float4 p = *(const float4*)(Prow + k);
#pragma unroll
        for (int tok = 0; tok < 8; ++tok)
            acc[tok] += p.x * h[tok][k] + p.y * h[tok][k+1] + p.z * h[tok][k+2] + p.w * h[tok][k+3];
    }
    for (int tok = 0; tok < 8; ++tok)
        outp[(size_t)(t0 + tok) * stride] = f2bf(acc[tok]);
}

// ---------- kernel 3: swapped-operand GEMM + fused LSE partials ----------
// C[v][t] = sum_k W[v][k] * H[t][k] + bias[v]
// C/D layout: row (lane>>4)*4+reg = vocab (lane-local softmax), col lane&15 = token.
// Partials: pM[nt*1024 + token] (contiguous 512B per block write).
template<bool BF16B>
__global__ __launch_bounds__(256)
void gemm_lse_t(const unsigned short* __restrict__ Wb,  // bf16 [Nsplit][K]  (BF16B)
                const float* __restrict__ Wfa,          // f32 [Nsplit][Kv]  (!BF16B)
                const float* __restrict__ Wfb,          // f32 [N-Nsplit][K] extra rows (may be null)
                int Nsplit, int N, int K, int Kv, int KTILES,
                const float* __restrict__ bias1, const float* __restrict__ bias2,
                const unsigned short* __restrict__ H,   // bf16 [1024][K]
                float* __restrict__ pM, float* __restrict__ pS) {
    __shared__ __align__(16) char Ws[16384];
    __shared__ __align__(16) char Hs[16384];
    __shared__ float bias_s[128];
    __shared__ float red[2][128][2];
    const int tid  = threadIdx.x;
    const int lane = tid & 63;
    const int wid  = tid >> 6;
    const int wm = wid >> 1, wn = wid & 1;          // wm: vocab strip, wn: token strip
    const int tt = blockIdx.x, nt = blockIdx.y;
    const int t0 = tt * 128, n0 = nt * 128;
    const bool clean = BF16B && (n0 + 128 <= Nsplit);

    // stage bias (+ -inf for invalid rows; makes epilogue branch-free)
    if (tid < 128) {
        int v = n0 + tid;
        float b;
        if (v < Nsplit)      b = bias1[v];
        else if (v < N)      b = bias2[v - Nsplit];
        else                 b = -INFINITY;
        bias_s[tid] = b;
    }

    f32x4 acc[4][4];
    const f32x4 zero = {0.f, 0.f, 0.f, 0.f};
#pragma unroll
    for (int i = 0; i < 4; ++i)
#pragma unroll
        for (int j = 0; j < 4; ++j) acc[i][j] = zero;

    for (int kt = 0; kt < KTILES; ++kt) {
        // ---- stage W tile [128][64] ----
        if (clean) {
#pragma unroll
            for (int j = 0; j < 4; ++j) {
                int lds_off = wid * 4096 + j * 1024;
                int o = lds_off + lane * 16;
                int r = o >> 7;                          // tile row
                int b = (o & 127) ^ ((r & 7) << 4);      // inverse-swizzled source byte
                gload_lds16(Wb + (size_t)(n0 + r) * K + kt * 64 + (b >> 1), Ws + lds_off);
            }
        } else {
#pragma unroll
            for (int it = 0; it < 4; ++it) {
                int c = tid + it * 256;
                int row = c >> 3, kc = (c & 7) << 3;
                int v = n0 + row;
                int kg = kt * 64 + kc;
                unsigned short hh[8] = {0,0,0,0,0,0,0,0};
                if (v < Nsplit) {
                    if (BF16B) {
                        *(int4*)hh = *(const int4*)(Wb + (size_t)v * K + kg);
                    } else if (kg + 8 <= Kv) {
                        const float* p = Wfa + (size_t)v * Kv;
                        float4 u0 = *(const float4*)(p + kg);
                        float4 u1 = *(const float4*)(p + kg + 4);
                        hh[0]=f2bf(u0.x); hh[1]=f2bf(u0.y); hh[2]=f2bf(u0.z); hh[3]=f2bf(u0.w);
                        hh[4]=f2bf(u1.x); hh[5]=f2bf(u1.y); hh[6]=f2bf(u1.z); hh[7]=f2bf(u1.w);
                    }
                } else if (v < N && Wfb != nullptr) {
                    const float* p = Wfb + (size_t)(v - Nsplit) * K;
                    float4 u0 = *(const float4*)(p + kg);
                    float4 u1 = *(const float4*)(p + kg + 4);
                    hh[0]=f2bf(u0.x); hh[1]=f2bf(u0.y); hh[2]=f2bf(u0.z); hh[3]=f2bf(u0.w);
                    hh[4]=f2bf(u1.x); hh[5]=f2bf(u1.y); hh[6]=f2bf(u1.z); hh[7]=f2bf(u1.w);
                }
                int off = (row * 128 + kc * 2) ^ ((row & 7) << 4);
                *(int4*)(Ws + off) = *(const int4*)hh;
            }
        }
        // ---- stage H tile [128][64] (always bf16, always valid rows) ----
#pragma unroll
        for (int j = 0; j < 4; ++j) {
            int lds_off = wid * 4096 + j * 1024;
            int o = lds_off + lane * 16;
            int r = o >> 7;
            int b = (o & 127) ^ ((r & 7) << 4);
            gload_lds16(H + (size_t)(t0 + r) * K + kt * 64 + (b >> 1), Hs + lds_off);
        }
        __syncthreads();
        // ---- compute: 2 k-slices, a = W frags (vocab), b = H frags (tokens) ----
#pragma unroll
        for (int kk = 0; kk < 2; ++kk) {
            const int kbyte = (kk * 32 + ((lane >> 4) << 3)) * 2;
            short8 a[4], b[4];
#pragma unroll
            for (int mi = 0; mi < 4; ++mi) {
                int row = wm * 64 + mi * 16 + (lane & 15);
                int off = (row * 128 + kbyte) ^ ((row & 7) << 4);
                a[mi] = *(const short8*)(Ws + off);
            }
#pragma unroll
            for (int ni = 0; ni < 4; ++ni) {
                int row = wn * 64 + ni * 16 + (lane & 15);
                int off = (row * 128 + kbyte) ^ ((row & 7) << 4);
                b[ni] = *(const short8*)(Hs + off);
            }
#pragma unroll
            for (int mi = 0; mi < 4; ++mi)
#pragma unroll
                for (int ni = 0; ni < 4; ++ni)
                    acc[mi][ni] = __builtin_amdgcn_mfma_f32_16x16x32_bf16(a[mi], b[ni], acc[mi][ni], 0, 0, 0);
        }
        __syncthreads();
    }

    // ---- epilogue: lane-local vocab reduce ----
    float bvv[4][4];
#pragma unroll
    for (int mi = 0; mi < 4; ++mi)
#pragma unroll
        for (int r = 0; r < 4; ++r)
            bvv[mi][r] = bias_s[wm * 64 + mi * 16 + ((lane >> 4) << 2) + r];
#pragma unroll
    for (int mi = 0; mi < 4; ++mi)
#pragma unroll
        for (int ni = 0; ni < 4; ++ni)
#pragma unroll
            for (int r = 0; r < 4; ++r)
                acc[mi][ni][r] += bvv[mi][r];

#pragma unroll
    for (int ni = 0; ni < 4; ++ni) {
        float mx = -INFINITY;
#pragma unroll
        for (int mi = 0; mi < 4; ++mi)
#pragma unroll
            for (int r = 0; r < 4; ++r)
                mx = fmaxf(mx, acc[mi][ni][r]);
        mx = fmaxf(mx, __shfl_xor(mx, 16, 64));
        mx = fmaxf(mx, __shfl_xor(mx, 32, 64));
        float mxe = (mx == -INFINITY) ? 0.f : mx;   // all-invalid strip guard
        float sm = 0.f;
#pragma unroll
        for (int mi = 0; mi < 4; ++mi)
#pragma unroll
            for (int r = 0; r < 4; ++r)
                sm += __expf(acc[mi][ni][r] - mxe);
        sm += __shfl_xor(sm, 16, 64);
        sm += __shfl_xor(sm, 32, 64);
        if ((lane >> 4) == 0) {
            int tloc = wn * 64 + ni * 16 + lane;    // lane == lane&15 here
            red[wm][tloc][0] = mx;
            red[wm][tloc][1] = sm;
        }
    }
    __syncthreads();
    if (tid < 128) {
        float m0v = red[0][tid][0], s0v = red[0][tid][1];
        float m1v = red[1][tid][0], s1v = red[1][tid][1];
        float M = fmaxf(m0v, m1v);
        float S = 0.f;
        if (s0v > 0.f) S += s0v * __expf(m0v - M);
        if (s1v > 0.f) S += s1v * __expf(m1v - M);
        size_t idx = (size_t)nt * 1024 + t0 + tid;
        pM[idx] = M;
        pS[idx] = S;
    }
}

// ---------- kernel 4a: stage-1 LSE reduce: tile segments -> [c][z][token] ----------
// grid (16 token-groups, 4 clusters, 16 segments), block 256 (4 waves).
__global__ __launch_bounds__(256)
void reduce_part(const float* __restrict__ pMh, const float* __restrict__ pSh, int nth,
                 const float* __restrict__ pM1, const float* __restrict__ pS1, int nt1,
                 const float* __restrict__ pM2, const float* __restrict__ pS2, int nt2,
                 const float* __restrict__ pM3, const float* __restrict__ pS3, int nt3,
                 float* __restrict__ pRm, float* __restrict__ pRs) {
    const int c = blockIdx.y, z = blockIdx.z;
    const float* PM = (c == 0) ? pMh : (c == 1) ? pM1 : (c == 2) ? pM2 : pM3;
    const float* PS = (c == 0) ? pSh : (c == 1) ? pS1 : (c == 2) ? pS2 : pS3;
    const int nt = (c == 0) ? nth : (c == 1) ? nt1 : (c == 2) ? nt2 : nt3;
    const int lane = threadIdx.x & 63;
    const int seg  = threadIdx.x >> 6;
    const int t = blockIdx.x * 64 + lane;
    float m = -INFINITY, s = 0.f;
    for (int i = z * 4 + seg; i < nt; i += 64) {
        float mi = PM[(size_t)i * 1024 + t];
        float si = PS[(size_t)i * 1024 + t];
        if (mi > m) { s = s * __expf(m - mi) + si; m = mi; }
        else if (si > 0.f) { s += si * __expf(mi - m); }
    }
    __shared__ float rm[4][64], rs[4][64];
    rm[seg][lane] = m; rs[seg][lane] = s;
    __syncthreads();
    if (seg == 0) {
#pragma unroll
        for (int q = 1; q < 4; ++q) {
            float om = rm[q][lane], os = rs[q][lane];
            if (om > m) { s = s * __expf(m - om) + os; m = om; }
            else if (os > 0.f) { s += os * __expf(om - m); }
        }
        size_t idx = ((size_t)c * 16 + z) * 1024 + t;
        pRm[idx] = m;
        pRs[idx] = s;
    }
}

// ---------- kernel 4b: stage-2 combine 16 segments -> lse[c][token] ----------
__global__ __launch_bounds__(256)
void reduce_final(const float* __restrict__ pRm, const float* __restrict__ pRs,
                  float* __restrict__ lse) {
    const int c = blockIdx.y;
    const int lane = threadIdx.x & 63;
    const int seg  = threadIdx.x >> 6;
    const int t = blockIdx.x * 64 + lane;
    float m = -INFINITY, s = 0.f;
#pragma unroll
    for (int z = 0; z < 4; ++z) {
        size_t idx = ((size_t)c * 16 + seg * 4 + z) * 1024 + t;
        float om = pRm[idx], os = pRs[idx];
        if (om > m) { s = s * __expf(m - om) + os; m = om; }
        else if (os > 0.f) { s += os * __expf(om - m); }
    }
    __shared__ float rm[4][64], rs[4][64];
    rm[seg][lane] = m; rs[seg][lane] = s;
    __syncthreads();
    if (seg == 0) {
#pragma unroll
        for (int q = 1; q < 4; ++q) {
            float om = rm[q][lane], os = rs[q][lane];
            if (om > m) { s = s * __expf(m - om) + os; m = om; }
            else if (os > 0.f) { s += os * __expf(om - m); }
        }
        lse[c * 1024 + t] = m + logf(s);
    }
}

// ---------- kernel 5: gather needed logits + assemble output ----------
__global__ void finalize(const float* __restrict__ hidden, const int* __restrict__ target,
                         const float* __restrict__ W_head, const float* __restrict__ b_head,
                         const float* __restrict__ W_clu, const float* __restrict__ b_clu,
                         const float* __restrict__ W1, const float* __restrict__ b1,
                         const float* __restrict__ W2, const float* __restrict__ b2,
                         const float* __restrict__ W3, const float* __restrict__ b3,
                         const unsigned short* __restrict__ proj1,
                         const unsigned short* __restrict__ proj2,
                         const unsigned short* __restrict__ proj3,
                         const float* __restrict__ lse,   // [4][1024]
                         float* __restrict__ out) {
    const int t = blockIdx.x;
    const int lane = threadIdx.x;
    const int tgt = target[t];
    const int cid = (tgt >= 20000) + (tgt >= 40000) + (tgt >= 200000);
    const int j = (cid == 0) ? tgt : (20003 - cid);
    const float* wr = (j < 20000) ? (W_head + (size_t)j * 1024)
                                  : (W_clu + (size_t)(j - 20000) * 1024);
    float acc = 0.f;
#pragma unroll
    for (int i = 0; i < 4; ++i) {
        int k4 = lane + i * 64;
        float4 h = *(const float4*)(hidden + (size_t)t * 1024 + k4 * 4);
        float4 w = *(const float4*)(wr + k4 * 4);
        acc += h.x * w.x + h.y * w.y + h.z * w.z + h.w * w.w;
    }
#pragma unroll
    for (int msk = 1; msk < 64; msk <<= 1) acc += __shfl_xor(acc, msk, 64);
    float bj = (j < 20000) ? b_head[j] : b_clu[j - 20000];
    float res = (acc + bj) - lse[t];
    if (cid > 0) {
        const int starts[4] = {0, 20000, 40000, 200000};
        const int dims[4]   = {0, 256, 64, 16};
        const float* Wt = (cid == 1) ? W1 : (cid == 2) ? W2 : W3;
        const float* bt = (cid == 1) ? b1 : (cid == 2) ? b2 : b3;
        const unsigned short* pr = (cid == 1) ? proj1 + (size_t)t * 256
                                 : (cid == 2) ? proj2 + (size_t)t * 64
                                              : proj3 + (size_t)t * 64;
        int ti = tgt - starts[cid];
        int d  = dims[cid];
        const float* wt = Wt + (size_t)ti * d;
        float a2 = 0.f;
        for (int k = lane; k < d; k += 64) a2 += bf2f(pr[k]) * wt[k];
#pragma unroll
        for (int msk = 1; msk < 64; msk <<= 1) a2 += __shfl_xor(a2, msk, 64);
        res += (a2 + bt[ti]) - lse[cid * 1024 + t];
    }
    if (lane == 0) out[t] = -res;
}

// ---------- launch ----------
extern "C" void kernel_launch(void* const* d_in, const int* in_sizes, int n_in,
                              void* d_out, int out_size, void* d_ws, size_t ws_size,
                              hipStream_t stream) {
    const float* hidden = (const float*)d_in[0];
    const int*   target = (const int*)d_in[1];
    const float* W_head = (const float*)d_in[2];
    const float* b_head = (const float*)d_in[3];
    const float* W_clu  = (const float*)d_in[4];
    const float* b_clu  = (const float*)d_in[5];
    const float* P1 = (const float*)d_in[6];
    const float* W1 = (const float*)d_in[7];
    const float* b1 = (const float*)d_in[8];
    const float* P2 = (const float*)d_in[9];
    const float* W2 = (const float*)d_in[10];
    const float* b2 = (const float*)d_in[11];
    const float* P3 = (const float*)d_in[12];
    const float* W3 = (const float*)d_in[13];
    const float* b3 = (const float*)d_in[14];
    float* out = (float*)d_out;

    char* ws = (char*)d_ws;
    size_t off = 0;
    auto alloc = [&](size_t bytes) -> char* {
        char* p = ws + off;
        off += (bytes + 255) & ~(size_t)255;
        return p;
    };
    const int NT_H = 157;   // ceil(20003/128)
    const int NT_1 = 157;   // ceil(20000/128)
    const int NT_2 = 1250;  // 160000/128
    const int NT_3 = 530;   // ceil(67735/128)

    unsigned short* hbf   = (unsigned short*)alloc((size_t)1024 * 1024 * 2);
    unsigned short* proj1 = (unsigned short*)alloc((size_t)1024 * 256 * 2);
    unsigned short* proj2 = (unsigned short*)alloc((size_t)1024 * 64 * 2);
    unsigned short* proj3 = (unsigned short*)alloc((size_t)1024 * 64 * 2);
    float* pMh = (float*)alloc((size_t)1024 * NT_H * 4);
    float* pSh = (float*)alloc((size_t)1024 * NT_H * 4);
    float* pM1 = (float*)alloc((size_t)1024 * NT_1 * 4);
    float* pS1 = (float*)alloc((size_t)1024 * NT_1 * 4);
    float* pM2 = (float*)alloc((size_t)1024 * NT_2 * 4);
    float* pS2 = (float*)alloc((size_t)1024 * NT_2 * 4);
    float* pM3 = (float*)alloc((size_t)1024 * NT_3 * 4);
    float* pS3 = (float*)alloc((size_t)1024 * NT_3 * 4);
    float* lse = (float*)alloc((size_t)4 * 1024 * 4);
    float* pRm = (float*)alloc((size_t)4 * 16 * 1024 * 4);
    float* pRs = (float*)alloc((size_t)4 * 16 * 1024 * 4);
    // optional bf16 weight mirrors (last, so fallback stays in-bounds)
    unsigned short* Whb = (unsigned short*)alloc((size_t)20000 * 1024 * 2);
    unsigned short* W1b = (unsigned short*)alloc((size_t)20000 * 256 * 2);
    unsigned short* W2b = (unsigned short*)alloc((size_t)160000 * 64 * 2);
    unsigned short* W3b = (unsigned short*)alloc((size_t)67735 * 64 * 2);
    const bool pre = (off <= ws_size);

    convert_hidden<<<1024, 256, 0, stream>>>(hidden, hbf);
    proj_kernel<<<128, 384, 0, stream>>>(hidden, P1, P2, P3, proj1, proj2, proj3);
    if (pre) {
        convert_w<<<(5120000 + 255) / 256, 256, 0, stream>>>(W_head, Whb, 5120000);
        convert_w<<<(1280000 + 255) / 256, 256, 0, stream>>>(W1, W1b, 1280000);
        convert_w<<<(2560000 + 255) / 256, 256, 0, stream>>>(W2, W2b, 2560000);
        convert_pad16to64<<<(67735 * 8 + 255) / 256, 256, 0, stream>>>(W3, W3b, 67735);
        gemm_lse_t<true><<<dim3(8, NT_H), 256, 0, stream>>>(
            Whb, nullptr, W_clu, 20000, 20003, 1024, 1024, 16,
            b_head, b_clu, hbf, pMh, pSh);
        gemm_lse_t<true><<<dim3(8, NT_1), 256, 0, stream>>>(
            W1b, nullptr, nullptr, 20000, 20000, 256, 256, 4,
            b1, nullptr, proj1, pM1, pS1);
        gemm_lse_t<true><<<dim3(8, NT_2), 256, 0, stream>>>(
            W2b, nullptr, nullptr, 160000, 160000, 64, 64, 1,
            b2, nullptr, proj2, pM2, pS2);
        gemm_lse_t<true><<<dim3(8, NT_3), 256, 0, stream>>>(
            W3b, nullptr, nullptr, 67735, 67735, 64, 64, 1,
            b3, nullptr, proj3, pM3, pS3);
    } else {
        gemm_lse_t<false><<<dim3(8, NT_H), 256, 0, stream>>>(
            nullptr, W_head, W_clu, 20000, 20003, 1024, 1024, 16,
            b_head, b_clu, hbf, pMh, pSh);
        gemm_lse_t<false><<<dim3(8, NT_1), 256, 0, stream>>>(
            nullptr, W1, nullptr, 20000, 20000, 256, 256, 4,
            b1, nullptr, proj1, pM1, pS1);
        gemm_lse_t<false><<<dim3(8, NT_2), 256, 0, stream>>>(
            nullptr, W2, nullptr, 160000, 160000, 64, 64, 1,
            b2, nullptr, proj2, pM2, pS2);
        gemm_lse_t<false><<<dim3(8, NT_3), 256, 0, stream>>>(
            nullptr, W3, nullptr, 67735, 67735, 64, 16, 1,
            b3, nullptr, proj3, pM3, pS3);
    }

    reduce_part<<<dim3(16, 4, 16), 256, 0, stream>>>(pMh, pSh, NT_H,
                                                     pM1, pS1, NT_1,
                                                     pM2, pS2, NT_2,
                                                     pM3, pS3, NT_3, pRm, pRs);
    reduce_final<<<dim3(16, 4), 256, 0, stream>>>(pRm, pRs, lse);

    finalize<<<1024, 64, 0, stream>>>(hidden, target,
                                      W_head, b_head, W_clu, b_clu,
                                      W1, b1, W2, b2, W3, b3,
                                      proj1, proj2, proj3, lse, out);
}

// Round 5
// 258.969 us; speedup vs baseline: 2.0680x; 1.1834x over previous
//
#include <hip/hip_runtime.h>
#include <cstdint>
#include <cstddef>

// ---------- types ----------
typedef __attribute__((ext_vector_type(8))) short short8;   // 8 x bf16 (4 VGPR)
typedef __attribute__((ext_vector_type(4))) float f32x4;

__device__ __forceinline__ unsigned short f2bf(float x) {
    unsigned u = __float_as_uint(x);
    u += 0x7FFFu + ((u >> 16) & 1u);        // RNE
    return (unsigned short)(u >> 16);
}
__device__ __forceinline__ float bf2f(unsigned short h) {
    return __uint_as_float(((unsigned)h) << 16);
}

// async global->LDS, 16B per lane; LDS dest = uniform base + lane*16
__device__ __forceinline__ void gload_lds16(const void* g, void* l) {
    __builtin_amdgcn_global_load_lds(
        (const __attribute__((address_space(1))) unsigned int*)g,
        (__attribute__((address_space(3))) unsigned int*)l, 16, 0, 0);
}

// ---------- kernel 1a: f32 -> bf16 hidden (exact grid) ----------
__global__ void convert_hidden(const float* __restrict__ in, unsigned short* __restrict__ out) {
    int i = blockIdx.x * 256 + threadIdx.x;           // 262144 float4 total
    float4 v = *(const float4*)(in + (size_t)i * 4);
    unsigned long long p = (unsigned long long)f2bf(v.x)
                         | ((unsigned long long)f2bf(v.y) << 16)
                         | ((unsigned long long)f2bf(v.z) << 32)
                         | ((unsigned long long)f2bf(v.w) << 48);
    *(unsigned long long*)(out + (size_t)i * 4) = p;
}

// ---------- kernel 1b: generic f32 -> bf16 (n4 float4 chunks) ----------
__global__ void convert_w(const float* __restrict__ in, unsigned short* __restrict__ out, int n4) {
    int i = blockIdx.x * 256 + threadIdx.x;
    if (i >= n4) return;
    float4 v = *(const float4*)(in + (size_t)i * 4);
    unsigned long long p = (unsigned long long)f2bf(v.x)
                         | ((unsigned long long)f2bf(v.y) << 16)
                         | ((unsigned long long)f2bf(v.z) << 32)
                         | ((unsigned long long)f2bf(v.w) << 48);
    *(unsigned long long*)(out + (size_t)i * 4) = p;
}

// ---------- kernel 1c: f32 [N][16] -> bf16 [N][64] zero-padded ----------
__global__ void convert_pad16to64(const float* __restrict__ in, unsigned short* __restrict__ out,
                                  int nrows) {
    int idx = blockIdx.x * 256 + threadIdx.x;
    int r = idx >> 3, c = idx & 7;
    if (r >= nrows) return;
    unsigned long long p0 = 0ull, p1 = 0ull;
    if (c < 2) {
        const float* rp = in + (size_t)r * 16 + c * 8;
        float4 u0 = *(const float4*)(rp);
        float4 u1 = *(const float4*)(rp + 4);
        p0 = (unsigned long long)f2bf(u0.x) | ((unsigned long long)f2bf(u0.y) << 16)
           | ((unsigned long long)f2bf(u0.z) << 32) | ((unsigned long long)f2bf(u0.w) << 48);
        p1 = (unsigned long long)f2bf(u1.x) | ((unsigned long long)f2bf(u1.y) << 16)
           | ((unsigned long long)f2bf(u1.z) << 32) | ((unsigned long long)f2bf(u1.w) << 48);
    }
    unsigned long long* op = (unsigned long long*)(out + (size_t)r * 64 + c * 8);
    op[0] = p0;
    op[1] = p1;
}

// ---------- kernel 2: MFMA projection: proj[t][d] = sum_k hbf[t][k] * Pb[d][k] ----------
// Pb: bf16 [384][1024] = [P1(256); P2(64); P3(16); zeros(48)].
// Zero-padded P rows make proj3 cols 16..63 zero automatically.
// Grid (8 token tiles, 3 d tiles), block 256 (2x2 waves).
__global__ __launch_bounds__(256)
void proj_mfma(const unsigned short* __restrict__ Hb,   // [1024][1024]
               const unsigned short* __restrict__ Pb,   // [384][1024]
               unsigned short* __restrict__ proj1,      // [1024][256]
               unsigned short* __restrict__ proj2,      // [1024][64]
               unsigned short* __restrict__ proj3) {    // [1024][64]
    __shared__ __align__(16) char As[16384];   // token rows
    __shared__ __align__(16) char Bs[16384];   // P rows
    const int tid  = threadIdx.x;
    const int lane = tid & 63;
    const int wid  = tid >> 6;
    const int wm = wid >> 1, wn = wid & 1;
    const int tt = blockIdx.x, dt = blockIdx.y;
    const int t0 = tt * 128, d0 = dt * 128;

    f32x4 acc[4][4];
    const f32x4 zero = {0.f, 0.f, 0.f, 0.f};
#pragma unroll
    for (int i = 0; i < 4; ++i)
#pragma unroll
        for (int j = 0; j < 4; ++j) acc[i][j] = zero;

    for (int kt = 0; kt < 16; ++kt) {
#pragma unroll
        for (int j = 0; j < 4; ++j) {
            int lds_off = wid * 4096 + j * 1024;
            int o = lds_off + lane * 16;
            int r = o >> 7;
            int b = (o & 127) ^ ((r & 7) << 4);
            gload_lds16(Hb + (size_t)(t0 + r) * 1024 + kt * 64 + (b >> 1), As + lds_off);
        }
#pragma unroll
        for (int j = 0; j < 4; ++j) {
            int lds_off = wid * 4096 + j * 1024;
            int o = lds_off + lane * 16;
            int r = o >> 7;
            int b = (o & 127) ^ ((r & 7) << 4);
            gload_lds16(Pb + (size_t)(d0 + r) * 1024 + kt * 64 + (b >> 1), Bs + lds_off);
        }
        __syncthreads();
#pragma unroll
        for (int kk = 0; kk < 2; ++kk) {
            const int kbyte = (kk * 32 + ((lane >> 4) << 3)) * 2;
            short8 a[4], b[4];
#pragma unroll
            for (int mi = 0; mi < 4; ++mi) {
                int row = wm * 64 + mi * 16 + (lane & 15);
                int off = (row * 128 + kbyte) ^ ((row & 7) << 4);
                a[mi] = *(const short8*)(As + off);
            }
#pragma unroll
            for (int ni = 0; ni < 4; ++ni) {
                int row = wn * 64 + ni * 16 + (lane & 15);
                int off = (row * 128 + kbyte) ^ ((row & 7) << 4);
                b[ni] = *(const short8*)(Bs + off);
            }
#pragma unroll
            for (int mi = 0; mi < 4; ++mi)
#pragma unroll
                for (int ni = 0; ni < 4; ++ni)
                    acc[mi][ni] = __builtin_amdgcn_mfma_f32_16x16x32_bf16(a[mi], b[ni], acc[mi][ni], 0, 0, 0);
        }
        __syncthreads();
    }

    // epilogue: C row = token (A-operand rows), C col = d (B-operand rows)
#pragma unroll
    for (int ni = 0; ni < 4; ++ni) {
        int dg = d0 + wn * 64 + ni * 16 + (lane & 15);
        unsigned short* bp;
        int stride;
        if (dg < 256)      { bp = proj1 + dg;         stride = 256; }
        else if (dg < 320) { bp = proj2 + (dg - 256); stride = 64;  }
        else               { bp = proj3 + (dg - 320); stride = 64;  }
#pragma unroll
        for (int mi = 0; mi < 4; ++mi)
#pragma unroll
            for (int r = 0; r < 4; ++r) {
                int tok = t0 + wm * 64 + mi * 16 + ((lane >> 4) << 2) + r;
                bp[(size_t)tok * stride] = f2bf(acc[mi][ni][r]);
            }
    }
}

// ---------- kernel 3: swapped-operand GEMM + fused LSE partials ----------
// C[v][t] = sum_k W[v][k] * H[t][k] + bias[v]
// C/D layout: row (lane>>4)*4+reg = vocab (lane-local softmax), col lane&15 = token.
// Partials: pM[nt*1024 + token] (contiguous 512B per block write).
template<bool BF16B>
__global__ __launch_bounds__(256)
void gemm_lse_t(const unsigned short* __restrict__ Wb,  // bf16 [Nsplit][K]  (BF16B)
                const float* __restrict__ Wfa,          // f32 [Nsplit][Kv]  (!BF16B)
                const float* __restrict__ Wfb,          // f32 [N-Nsplit][K] extra rows (may be null)
                int Nsplit, int N, int K, int Kv, int KTILES,
                const float* __restrict__ bias1, const float* __restrict__ bias2,
                const unsigned short* __restrict__ H,   // bf16 [1024][K]
                float* __restrict__ pM, float* __restrict__ pS) {
    __shared__ __align__(16) char Ws[16384];
    __shared__ __align__(16) char Hs[16384];
    __shared__ float bias_s[128];
    __shared__ float red[2][128][2];
    const int tid  = threadIdx.x;
    const int lane = tid & 63;
    const int wid  = tid >> 6;
    const int wm = wid >> 1, wn = wid & 1;          // wm: vocab strip, wn: token strip
    const int tt = blockIdx.x, nt = blockIdx.y;
    const int t0 = tt * 128, n0 = nt * 128;
    const bool clean = BF16B && (n0 + 128 <= Nsplit);

    // stage bias (+ -inf for invalid rows; makes epilogue branch-free)
    if (tid < 128) {
        int v = n0 + tid;
        float b;
        if (v < Nsplit)      b = bias1[v];
        else if (v < N)      b = bias2[v - Nsplit];
        else                 b = -INFINITY;
        bias_s[tid] = b;
    }

    f32x4 acc[4][4];
    const f32x4 zero = {0.f, 0.f, 0.f, 0.f};
#pragma unroll
    for (int i = 0; i < 4; ++i)
#pragma unroll
        for (int j = 0; j < 4; ++j) acc[i][j] = zero;

    for (int kt = 0; kt < KTILES; ++kt) {
        // ---- stage W tile [128][64] ----
        if (clean) {
#pragma unroll
            for (int j = 0; j < 4; ++j) {
                int lds_off = wid * 4096 + j * 1024;
                int o = lds_off + lane * 16;
                int r = o >> 7;                          // tile row
                int b = (o & 127) ^ ((r & 7) << 4);      // inverse-swizzled source byte
                gload_lds16(Wb + (size_t)(n0 + r) * K + kt * 64 + (b >> 1), Ws + lds_off);
            }
        } else {
#pragma unroll
            for (int it = 0; it < 4; ++it) {
                int c = tid + it * 256;
                int row = c >> 3, kc = (c & 7) << 3;
                int v = n0 + row;
                int kg = kt * 64 + kc;
                unsigned short hh[8] = {0,0,0,0,0,0,0,0};
                if (v < Nsplit) {
                    if (BF16B) {
                        *(int4*)hh = *(const int4*)(Wb + (size_t)v * K + kg);
                    } else if (kg + 8 <= Kv) {
                        const float* p = Wfa + (size_t)v * Kv;
                        float4 u0 = *(const float4*)(p + kg);
                        float4 u1 = *(const float4*)(p + kg + 4);
                        hh[0]=f2bf(u0.x); hh[1]=f2bf(u0.y); hh[2]=f2bf(u0.z); hh[3]=f2bf(u0.w);
                        hh[4]=f2bf(u1.x); hh[5]=f2bf(u1.y); hh[6]=f2bf(u1.z); hh[7]=f2bf(u1.w);
                    }
                } else if (v < N && Wfb != nullptr) {
                    const float* p = Wfb + (size_t)(v - Nsplit) * K;
                    float4 u0 = *(const float4*)(p + kg);
                    float4 u1 = *(const float4*)(p + kg + 4);
                    hh[0]=f2bf(u0.x); hh[1]=f2bf(u0.y); hh[2]=f2bf(u0.z); hh[3]=f2bf(u0.w);
                    hh[4]=f2bf(u1.x); hh[5]=f2bf(u1.y); hh[6]=f2bf(u1.z); hh[7]=f2bf(u1.w);
                }
                int off = (row * 128 + kc * 2) ^ ((row & 7) << 4);
                *(int4*)(Ws + off) = *(const int4*)hh;
            }
        }
        // ---- stage H tile [128][64] (always bf16, always valid rows) ----
#pragma unroll
        for (int j = 0; j < 4; ++j) {
            int lds_off = wid * 4096 + j * 1024;
            int o = lds_off + lane * 16;
            int r = o >> 7;
            int b = (o & 127) ^ ((r & 7) << 4);
            gload_lds16(H + (size_t)(t0 + r) * K + kt * 64 + (b >> 1), Hs + lds_off);
        }
        __syncthreads();
        // ---- compute: 2 k-slices, a = W frags (vocab), b = H frags (tokens) ----
#pragma unroll
        for (int kk = 0; kk < 2; ++kk) {
            const int kbyte = (kk * 32 + ((lane >> 4) << 3)) * 2;
            short8 a[4], b[4];
#pragma unroll
            for (int mi = 0; mi < 4; ++mi) {
                int row = wm * 64 + mi * 16 + (lane & 15);
                int off = (row * 128 + kbyte) ^ ((row & 7) << 4);
                a[mi] = *(const short8*)(Ws + off);
            }
#pragma unroll
            for (int ni = 0; ni < 4; ++ni) {
                int row = wn * 64 + ni * 16 + (lane & 15);
                int off = (row * 128 + kbyte) ^ ((row & 7) << 4);
                b[ni] = *(const short8*)(Hs + off);
            }
#pragma unroll
            for (int mi = 0; mi < 4; ++mi)
#pragma unroll
                for (int ni = 0; ni < 4; ++ni)
                    acc[mi][ni] = __builtin_amdgcn_mfma_f32_16x16x32_bf16(a[mi], b[ni], acc[mi][ni], 0, 0, 0);
        }
        __syncthreads();
    }

    // ---- epilogue: lane-local vocab reduce ----
    float bvv[4][4];
#pragma unroll
    for (int mi = 0; mi < 4; ++mi)
#pragma unroll
        for (int r = 0; r < 4; ++r)
            bvv[mi][r] = bias_s[wm * 64 + mi * 16 + ((lane >> 4) << 2) + r];
#pragma unroll
    for (int mi = 0; mi < 4; ++mi)
#pragma unroll
        for (int ni = 0; ni < 4; ++ni)
#pragma unroll
            for (int r = 0; r < 4; ++r)
                acc[mi][ni][r] += bvv[mi][r];

#pragma unroll
    for (int ni = 0; ni < 4; ++ni) {
        float mx = -INFINITY;
#pragma unroll
        for (int mi = 0; mi < 4; ++mi)
#pragma unroll
            for (int r = 0; r < 4; ++r)
                mx = fmaxf(mx, acc[mi][ni][r]);
        mx = fmaxf(mx, __shfl_xor(mx, 16, 64));
        mx = fmaxf(mx, __shfl_xor(mx, 32, 64));
        float mxe = (mx == -INFINITY) ? 0.f : mx;   // all-invalid strip guard
        float sm = 0.f;
#pragma unroll
        for (int mi = 0; mi < 4; ++mi)
#pragma unroll
            for (int r = 0; r < 4; ++r)
                sm += __expf(acc[mi][ni][r] - mxe);
        sm += __shfl_xor(sm, 16, 64);
        sm += __shfl_xor(sm, 32, 64);
        if ((lane >> 4) == 0) {
            int tloc = wn * 64 + ni * 16 + lane;    // lane == lane&15 here
            red[wm][tloc][0] = mx;
            red[wm][tloc][1] = sm;
        }
    }
    __syncthreads();
    if (tid < 128) {
        float m0v = red[0][tid][0], s0v = red[0][tid][1];
        float m1v = red[1][tid][0], s1v = red[1][tid][1];
        float M = fmaxf(m0v, m1v);
        float S = 0.f;
        if (s0v > 0.f) S += s0v * __expf(m0v - M);
        if (s1v > 0.f) S += s1v * __expf(m1v - M);
        size_t idx = (size_t)nt * 1024 + t0 + tid;
        pM[idx] = M;
        pS[idx] = S;
    }
}

// ---------- kernel 4a: stage-1 LSE reduce: tile segments -> [c][z][token] ----------
__global__ __launch_bounds__(256)
void reduce_part(const float* __restrict__ pMh, const float* __restrict__ pSh, int nth,
                 const float* __restrict__ pM1, const float* __restrict__ pS1, int nt1,
                 const float* __restrict__ pM2, const float* __restrict__ pS2, int nt2,
                 const float* __restrict__ pM3, const float* __restrict__ pS3, int nt3,
                 float* __restrict__ pRm, float* __restrict__ pRs) {
    const int c = blockIdx.y, z = blockIdx.z;
    const float* PM = (c == 0) ? pMh : (c == 1) ? pM1 : (c == 2) ? pM2 : pM3;
    const float* PS = (c == 0) ? pSh : (c == 1) ? pS1 : (c == 2) ? pS2 : pS3;
    const int nt = (c == 0) ? nth : (c == 1) ? nt1 : (c == 2) ? nt2 : nt3;
    const int lane = threadIdx.x & 63;
    const int seg  = threadIdx.x >> 6;
    const int t = blockIdx.x * 64 + lane;
    float m = -INFINITY, s = 0.f;
    for (int i = z * 4 + seg; i < nt; i += 64) {
        float mi = PM[(size_t)i * 1024 + t];
        float si = PS[(size_t)i * 1024 + t];
        if (mi > m) { s = s * __expf(m - mi) + si; m = mi; }
        else if (si > 0.f) { s += si * __expf(mi - m); }
    }
    __shared__ float rm[4][64], rs[4][64];
    rm[seg][lane] = m; rs[seg][lane] = s;
    __syncthreads();
    if (seg == 0) {
#pragma unroll
        for (int q = 1; q < 4; ++q) {
            float om = rm[q][lane], os = rs[q][lane];
            if (om > m) { s = s * __expf(m - om) + os; m = om; }
            else if (os > 0.f) { s += os * __expf(om - m); }
        }
        size_t idx = ((size_t)c * 16 + z) * 1024 + t;
        pRm[idx] = m;
        pRs[idx] = s;
    }
}

// ---------- kernel 4b: stage-2 combine 16 segments -> lse[c][token] ----------
__global__ __launch_bounds__(256)
void reduce_final(const float* __restrict__ pRm, const float* __restrict__ pRs,
                  float* __restrict__ lse) {
    const int c = blockIdx.y;
    const int lane = threadIdx.x & 63;
    const int seg  = threadIdx.x >> 6;
    const int t = blockIdx.x * 64 + lane;
    float m = -INFINITY, s = 0.f;
#pragma unroll
    for (int z = 0; z < 4; ++z) {
        size_t idx = ((size_t)c * 16 + seg * 4 + z) * 1024 + t;
        float om = pRm[idx], os = pRs[idx];
        if (om > m) { s = s * __expf(m - om) + os; m = om; }
        else if (os > 0.f) { s += os * __expf(om - m); }
    }
    __shared__ float rm[4][64], rs[4][64];
    rm[seg][lane] = m; rs[seg][lane] = s;
    __syncthreads();
    if (seg == 0) {
#pragma unroll
        for (int q = 1; q < 4; ++q) {
            float om = rm[q][lane], os = rs[q][lane];
            if (om > m) { s = s * __expf(m - om) + os; m = om; }
            else if (os > 0.f) { s += os * __expf(om - m); }
        }
        lse[c * 1024 + t] = m + logf(s);
    }
}

// ---------- kernel 5: gather needed logits + assemble output ----------
__global__ void finalize(const float* __restrict__ hidden, const int* __restrict__ target,
                         const float* __restrict__ W_head, const float* __restrict__ b_head,
                         const float* __restrict__ W_clu, const float* __restrict__ b_clu,
                         const float* __restrict__ W1, const float* __restrict__ b1,
                         const float* __restrict__ W2, const float* __restrict__ b2,
                         const float* __restrict__ W3, const float* __restrict__ b3,
                         const unsigned short* __restrict__ proj1,
                         const unsigned short* __restrict__ proj2,
                         const unsigned short* __restrict__ proj3,
                         const float* __restrict__ lse,   // [4][1024]
                         float* __restrict__ out) {
    const int t = blockIdx.x;
    const int lane = threadIdx.x;
    const int tgt = target[t];
    const int cid = (tgt >= 20000) + (tgt >= 40000) + (tgt >= 200000);
    const int j = (cid == 0) ? tgt : (20003 - cid);
    const float* wr = (j < 20000) ? (W_head + (size_t)j * 1024)
                                  : (W_clu + (size_t)(j - 20000) * 1024);
    float acc = 0.f;
#pragma unroll
    for (int i = 0; i < 4; ++i) {
        int k4 = lane + i * 64;
        float4 h = *(const float4*)(hidden + (size_t)t * 1024 + k4 * 4);
        float4 w = *(const float4*)(wr + k4 * 4);
        acc += h.x * w.x + h.y * w.y + h.z * w.z + h.w * w.w;
    }
#pragma unroll
    for (int msk = 1; msk < 64; msk <<= 1) acc += __shfl_xor(acc, msk, 64);
    float bj = (j < 20000) ? b_head[j] : b_clu[j - 20000];
    float res = (acc + bj) - lse[t];
    if (cid > 0) {
        const int starts[4] = {0, 20000, 40000, 200000};
        const int dims[4]   = {0, 256, 64, 16};
        const float* Wt = (cid == 1) ? W1 : (cid == 2) ? W2 : W3;
        const float* bt = (cid == 1) ? b1 : (cid == 2) ? b2 : b3;
        const unsigned short* pr = (cid == 1) ? proj1 + (size_t)t * 256
                                 : (cid == 2) ? proj2 + (size_t)t * 64
                                              : proj3 + (size_t)t * 64;
        int ti = tgt - starts[cid];
        int d  = dims[cid];
        const float* wt = Wt + (size_t)ti * d;
        float a2 = 0.f;
        for (int k = lane; k < d; k += 64) a2 += bf2f(pr[k]) * wt[k];
#pragma unroll
        for (int msk = 1; msk < 64; msk <<= 1) a2 += __shfl_xor(a2, msk, 64);
        res += (a2 + bt[ti]) - lse[cid * 1024 + t];
    }
    if (lane == 0) out[t] = -res;
}

// ---------- launch ----------
extern "C" void kernel_launch(void* const* d_in, const int* in_sizes, int n_in,
                              void* d_out, int out_size, void* d_ws, size_t ws_size,
                              hipStream_t stream) {
    const float* hidden = (const float*)d_in[0];
    const int*   target = (const int*)d_in[1];
    const float* W_head = (const float*)d_in[2];
    const float* b_head = (const float*)d_in[3];
    const float* W_clu  = (const float*)d_in[4];
    const float* b_clu  = (const float*)d_in[5];
    const float* P1 = (const float*)d_in[6];
    const float* W1 = (const float*)d_in[7];
    const float* b1 = (const float*)d_in[8];
    const float* P2 = (const float*)d_in[9];
    const float* W2 = (const float*)d_in[10];
    const float* b2 = (const float*)d_in[11];
    const float* P3 = (const float*)d_in[12];
    const float* W3 = (const float*)d_in[13];
    const float* b3 = (const float*)d_in[14];
    float* out = (float*)d_out;

    char* ws = (char*)d_ws;
    size_t off = 0;
    auto alloc = [&](size_t bytes) -> char* {
        char* p = ws + off;
        off += (bytes + 255) & ~(size_t)255;
        return p;
    };
    const int NT_H = 157;   // ceil(20003/128)
    const int NT_1 = 157;   // ceil(20000/128)
    const int NT_2 = 1250;  // 160000/128
    const int NT_3 = 530;   // ceil(67735/128)

    unsigned short* hbf   = (unsigned short*)alloc((size_t)1024 * 1024 * 2);
    unsigned short* proj1 = (unsigned short*)alloc((size_t)1024 * 256 * 2);
    unsigned short* proj2 = (unsigned short*)alloc((size_t)1024 * 64 * 2);
    unsigned short* proj3 = (unsigned short*)alloc((size_t)1024 * 64 * 2);
    unsigned short* Pb    = (unsigned short*)alloc((size_t)384 * 1024 * 2);
    float* pMh = (float*)alloc((size_t)1024 * NT_H * 4);
    float* pSh = (float*)alloc((size_t)1024 * NT_H * 4);
    float* pM1 = (float*)alloc((size_t)1024 * NT_1 * 4);
    float* pS1 = (float*)alloc((size_t)1024 * NT_1 * 4);
    float* pM2 = (float*)alloc((size_t)1024 * NT_2 * 4);
    float* pS2 = (float*)alloc((size_t)1024 * NT_2 * 4);
    float* pM3 = (float*)alloc((size_t)1024 * NT_3 * 4);
    float* pS3 = (float*)alloc((size_t)1024 * NT_3 * 4);
    float* lse = (float*)alloc((size_t)4 * 1024 * 4);
    float* pRm = (float*)alloc((size_t)4 * 16 * 1024 * 4);
    float* pRs = (float*)alloc((size_t)4 * 16 * 1024 * 4);
    // optional bf16 weight mirrors (last, so fallback stays in-bounds)
    unsigned short* Whb = (unsigned short*)alloc((size_t)20000 * 1024 * 2);
    unsigned short* W1b = (unsigned short*)alloc((size_t)20000 * 256 * 2);
    unsigned short* W2b = (unsigned short*)alloc((size_t)160000 * 64 * 2);
    unsigned short* W3b = (unsigned short*)alloc((size_t)67735 * 64 * 2);
    const bool pre = (off <= ws_size);

    convert_hidden<<<1024, 256, 0, stream>>>(hidden, hbf);
    // build Pb = [P1; P2; P3; zeros] in bf16
    convert_w<<<(65536 + 255) / 256, 256, 0, stream>>>(P1, Pb, 65536);
    convert_w<<<(16384 + 255) / 256, 256, 0, stream>>>(P2, Pb + (size_t)256 * 1024, 16384);
    convert_w<<<(4096 + 255) / 256, 256, 0, stream>>>(P3, Pb + (size_t)320 * 1024, 4096);
    hipMemsetAsync(Pb + (size_t)336 * 1024, 0, (size_t)48 * 1024 * 2, stream);
    proj_mfma<<<dim3(8, 3), 256, 0, stream>>>(hbf, Pb, proj1, proj2, proj3);

    if (pre) {
        convert_w<<<(5120000 + 255) / 256, 256, 0, stream>>>(W_head, Whb, 5120000);
        convert_w<<<(1280000 + 255) / 256, 256, 0, stream>>>(W1, W1b, 1280000);
        convert_w<<<(2560000 + 255) / 256, 256, 0, stream>>>(W2, W2b, 2560000);
        convert_pad16to64<<<(67735 * 8 + 255) / 256, 256, 0, stream>>>(W3, W3b, 67735);
        gemm_lse_t<true><<<dim3(8, NT_H), 256, 0, stream>>>(
            Whb, nullptr, W_clu, 20000, 20003, 1024, 1024, 16,
            b_head, b_clu, hbf, pMh, pSh);
        gemm_lse_t<true><<<dim3(8, NT_1), 256, 0, stream>>>(
            W1b, nullptr, nullptr, 20000, 20000, 256, 256, 4,
            b1, nullptr, proj1, pM1, pS1);
        gemm_lse_t<true><<<dim3(8, NT_2), 256, 0, stream>>>(
            W2b, nullptr, nullptr, 160000, 160000, 64, 64, 1,
            b2, nullptr, proj2, pM2, pS2);
        gemm_lse_t<true><<<dim3(8, NT_3), 256, 0, stream>>>(
            W3b, nullptr, nullptr, 67735, 67735, 64, 64, 1,
            b3, nullptr, proj3, pM3, pS3);
    } else {
        gemm_lse_t<false><<<dim3(8, NT_H), 256, 0, stream>>>(
            nullptr, W_head, W_clu, 20000, 20003, 1024, 1024, 16,
            b_head, b_clu, hbf, pMh, pSh);
        gemm_lse_t<false><<<dim3(8, NT_1), 256, 0, stream>>>(
            nullptr, W1, nullptr, 20000, 20000, 256, 256, 4,
            b1, nullptr, proj1, pM1, pS1);
        gemm_lse_t<false><<<dim3(8, NT_2), 256, 0, stream>>>(
            nullptr, W2, nullptr, 160000, 160000, 64, 64, 1,
            b2, nullptr, proj2, pM2, pS2);
        gemm_lse_t<false><<<dim3(8, NT_3), 256, 0, stream>>>(
            nullptr, W3, nullptr, 67735, 67735, 64, 16, 1,
            b3, nullptr, proj3, pM3, pS3);
    }

    reduce_part<<<dim3(16, 4, 16), 256, 0, stream>>>(pMh, pSh, NT_H,
                                                     pM1, pS1, NT_1,
                                                     pM2, pS2, NT_2,
                                                     pM3, pS3, NT_3, pRm, pRs);
    reduce_final<<<dim3(16, 4), 256, 0, stream>>>(pRm, pRs, lse);

    finalize<<<1024, 64, 0, stream>>>(hidden, target,
                                      W_head, b_head, W_clu, b_clu,
                                      W1, b1, W2, b2, W3, b3,
                                      proj1, proj2, proj3, lse, out);
}

// Round 7
// 238.141 us; speedup vs baseline: 2.2488x; 1.0875x over previous
//
#include <hip/hip_runtime.h>
#include <cstdint>
#include <cstddef>

// ---------- types ----------
typedef __attribute__((ext_vector_type(8))) short short8;   // 8 x bf16 (4 VGPR)
typedef __attribute__((ext_vector_type(4))) float f32x4;

#define LOG2E 1.4426950408889634f
#define LN2   0.6931471805599453f

__device__ __forceinline__ unsigned short f2bf(float x) {
    unsigned u = __float_as_uint(x);
    u += 0x7FFFu + ((u >> 16) & 1u);        // RNE
    return (unsigned short)(u >> 16);
}
__device__ __forceinline__ float bf2f(unsigned short h) {
    return __uint_as_float(((unsigned)h) << 16);
}

// async global->LDS, 16B per lane; LDS dest = uniform base + lane*16
__device__ __forceinline__ void gload_lds16(const void* g, void* l) {
    __builtin_amdgcn_global_load_lds(
        (const __attribute__((address_space(1))) unsigned int*)g,
        (__attribute__((address_space(3))) unsigned int*)l, 16, 0, 0);
}

// ---------- kernel 1a: f32 -> bf16 hidden (exact grid) ----------
__global__ void convert_hidden(const float* __restrict__ in, unsigned short* __restrict__ out) {
    int i = blockIdx.x * 256 + threadIdx.x;           // 262144 float4 total
    float4 v = *(const float4*)(in + (size_t)i * 4);
    unsigned long long p = (unsigned long long)f2bf(v.x)
                         | ((unsigned long long)f2bf(v.y) << 16)
                         | ((unsigned long long)f2bf(v.z) << 32)
                         | ((unsigned long long)f2bf(v.w) << 48);
    *(unsigned long long*)(out + (size_t)i * 4) = p;
}

// ---------- kernel 1b: generic f32 -> bf16 (n4 float4 chunks) ----------
__global__ void convert_w(const float* __restrict__ in, unsigned short* __restrict__ out, int n4) {
    int i = blockIdx.x * 256 + threadIdx.x;
    if (i >= n4) return;
    float4 v = *(const float4*)(in + (size_t)i * 4);
    unsigned long long p = (unsigned long long)f2bf(v.x)
                         | ((unsigned long long)f2bf(v.y) << 16)
                         | ((unsigned long long)f2bf(v.z) << 32)
                         | ((unsigned long long)f2bf(v.w) << 48);
    *(unsigned long long*)(out + (size_t)i * 4) = p;
}

// ---------- kernel 2: MFMA projection: proj[t][d] = sum_k hbf[t][k] * Pb[d][k] ----------
__global__ __launch_bounds__(256)
void proj_mfma(const unsigned short* __restrict__ Hb,   // [1024][1024]
               const unsigned short* __restrict__ Pb,   // [384][1024]
               unsigned short* __restrict__ proj1,      // [1024][256]
               unsigned short* __restrict__ proj2,      // [1024][64]
               unsigned short* __restrict__ proj3) {    // [1024][64]
    __shared__ __align__(16) char As[16384];
    __shared__ __align__(16) char Bs[16384];
    const int tid  = threadIdx.x;
    const int lane = tid & 63;
    const int wid  = tid >> 6;
    const int wm = wid >> 1, wn = wid & 1;
    const int tt = blockIdx.x, dt = blockIdx.y;
    const int t0 = tt * 128, d0 = dt * 128;

    f32x4 acc[4][4];
    const f32x4 zero = {0.f, 0.f, 0.f, 0.f};
#pragma unroll
    for (int i = 0; i < 4; ++i)
#pragma unroll
        for (int j = 0; j < 4; ++j) acc[i][j] = zero;

    for (int kt = 0; kt < 16; ++kt) {
#pragma unroll
        for (int j = 0; j < 4; ++j) {
            int lds_off = wid * 4096 + j * 1024;
            int o = lds_off + lane * 16;
            int r = o >> 7;
            int b = (o & 127) ^ ((r & 7) << 4);
            gload_lds16(Hb + (size_t)(t0 + r) * 1024 + kt * 64 + (b >> 1), As + lds_off);
        }
#pragma unroll
        for (int j = 0; j < 4; ++j) {
            int lds_off = wid * 4096 + j * 1024;
            int o = lds_off + lane * 16;
            int r = o >> 7;
            int b = (o & 127) ^ ((r & 7) << 4);
            gload_lds16(Pb + (size_t)(d0 + r) * 1024 + kt * 64 + (b >> 1), Bs + lds_off);
        }
        __syncthreads();
#pragma unroll
        for (int kk = 0; kk < 2; ++kk) {
            const int kbyte = (kk * 32 + ((lane >> 4) << 3)) * 2;
            short8 a[4], b[4];
#pragma unroll
            for (int mi = 0; mi < 4; ++mi) {
                int row = wm * 64 + mi * 16 + (lane & 15);
                int off = (row * 128 + kbyte) ^ ((row & 7) << 4);
                a[mi] = *(const short8*)(As + off);
            }
#pragma unroll
            for (int ni = 0; ni < 4; ++ni) {
                int row = wn * 64 + ni * 16 + (lane & 15);
                int off = (row * 128 + kbyte) ^ ((row & 7) << 4);
                b[ni] = *(const short8*)(Bs + off);
            }
#pragma unroll
            for (int mi = 0; mi < 4; ++mi)
#pragma unroll
                for (int ni = 0; ni < 4; ++ni)
                    acc[mi][ni] = __builtin_amdgcn_mfma_f32_16x16x32_bf16(a[mi], b[ni], acc[mi][ni], 0, 0, 0);
        }
        __syncthreads();
    }

#pragma unroll
    for (int ni = 0; ni < 4; ++ni) {
        int dg = d0 + wn * 64 + ni * 16 + (lane & 15);
        unsigned short* bp;
        int stride;
        if (dg < 256)      { bp = proj1 + dg;         stride = 256; }
        else if (dg < 320) { bp = proj2 + (dg - 256); stride = 64;  }
        else               { bp = proj3 + (dg - 320); stride = 64;  }
#pragma unroll
        for (int mi = 0; mi < 4; ++mi)
#pragma unroll
            for (int r = 0; r < 4; ++r) {
                int tok = t0 + wm * 64 + mi * 16 + ((lane >> 4) << 2) + r;
                bp[(size_t)tok * stride] = f2bf(acc[mi][ni][r]);
            }
    }
}

// ---------- kernel 2b: deterministic cluster compaction (1 block, 1024 threads) ----------
__global__ __launch_bounds__(1024)
void compact_tokens(const int* __restrict__ target, int* __restrict__ cnt,
                    int* __restrict__ slot, int* __restrict__ lists) {  // lists[3][1024]
    const int t = threadIdx.x;
    const int tgt = target[t];
    const int cid = (tgt >= 20000) + (tgt >= 40000) + (tgt >= 200000);
    const int wave = t >> 6, lane = t & 63;
    unsigned long long lt = (lane == 0) ? 0ull : (~0ull >> (64 - lane));
    __shared__ int wtot[3][16];
    __shared__ int wbase[3][16];
    unsigned long long bal[3];
#pragma unroll
    for (int c = 1; c <= 3; ++c) {
        unsigned long long b = __ballot(cid == c);
        if (lane == 0) wtot[c - 1][wave] = (int)__popcll(b);
        bal[c - 1] = b;
    }
    __syncthreads();
    if (t < 3) {
        int s = 0;
        for (int w = 0; w < 16; ++w) { wbase[t][w] = s; s += wtot[t][w]; }
        cnt[t + 1] = s;
        if (t == 0) cnt[0] = 1024;
    }
    __syncthreads();
    int sl = t;
    if (cid > 0) {
        sl = wbase[cid - 1][wave] + (int)__popcll(bal[cid - 1] & lt);
        lists[(cid - 1) * 1024 + sl] = t;
    }
    slot[t] = sl;
}

// ---------- kernel 2c: gather compacted proj rows (zero-pad beyond cnt) ----------
__global__ __launch_bounds__(64)
void gather_proj(const unsigned short* __restrict__ proj1,
                 const unsigned short* __restrict__ proj2,
                 const unsigned short* __restrict__ proj3,
                 const int* __restrict__ cnt, const int* __restrict__ lists,
                 unsigned short* __restrict__ Hc1, unsigned short* __restrict__ Hc2,
                 unsigned short* __restrict__ Hc3) {
    const int c = blockIdx.y;           // 0,1,2 -> clusters 1,2,3
    const int i = blockIdx.x;           // compact row
    const int lane = threadIdx.x;
    const int n = cnt[c + 1];
    if (c == 0) {
        uint2* dst = (uint2*)(Hc1 + (size_t)i * 256) + lane;       // 64 x 8B = 512B
        uint2 v = {0u, 0u};
        if (i < n) v = *((const uint2*)(proj1 + (size_t)lists[i] * 256) + lane);
        *dst = v;
    } else if (lane < 16) {
        const unsigned short* P = (c == 1) ? proj2 : proj3;
        unsigned short* D = (c == 1) ? Hc2 : Hc3;
        uint2* dst = (uint2*)(D + (size_t)i * 64) + lane;          // 16 x 8B = 128B
        uint2 v = {0u, 0u};
        if (i < n) v = *((const uint2*)(P + (size_t)lists[c * 1024 + i] * 64) + lane);
        *dst = v;
    }
}

// ---------- kernel 3: swapped-operand GEMM + fused LSE partials (log2 domain) ----------
template<bool BF16B>
__global__ __launch_bounds__(256)
void gemm_lse_t(const unsigned short* __restrict__ Wb,  // bf16 [Nsplit][K]  (BF16B)
                const float* __restrict__ Wfa,          // f32 [Nsplit][Kv]  (!BF16B)
                const float* __restrict__ Wfb,          // f32 [N-Nsplit][K] extra rows (may be null)
                int Nsplit, int N, int K, int Kv, int KTILES,
                const float* __restrict__ bias1, const float* __restrict__ bias2,
                const unsigned short* __restrict__ H,   // bf16 [1024][K]
                const int* __restrict__ cnt_p, int cidx,
                float* __restrict__ pM, float* __restrict__ pS) {
    if (cnt_p && (int)blockIdx.x * 128 >= cnt_p[cidx]) return;
    __shared__ __align__(16) char Ws[16384];
    __shared__ __align__(16) char Hs[16384];
    __shared__ float bias_s[128];
    __shared__ float red[2][128][2];
    const int tid  = threadIdx.x;
    const int lane = tid & 63;
    const int wid  = tid >> 6;
    const int wm = wid >> 1, wn = wid & 1;
    const int tt = blockIdx.x, nt = blockIdx.y;
    const int t0 = tt * 128, n0 = nt * 128;
    const bool clean = BF16B && (n0 + 128 <= Nsplit);

    if (tid < 128) {
        int v = n0 + tid;
        float b;
        if (v < Nsplit)      b = bias1[v] * LOG2E;
        else if (v < N)      b = bias2[v - Nsplit] * LOG2E;
        else                 b = -INFINITY;
        bias_s[tid] = b;
    }

    f32x4 acc[4][4];
    const f32x4 zero = {0.f, 0.f, 0.f, 0.f};
#pragma unroll
    for (int i = 0; i < 4; ++i)
#pragma unroll
        for (int j = 0; j < 4; ++j) acc[i][j] = zero;

    for (int kt = 0; kt < KTILES; ++kt) {
        if (clean) {
#pragma unroll
            for (int j = 0; j < 4; ++j) {
                int lds_off = wid * 4096 + j * 1024;
                int o = lds_off + lane * 16;
                int r = o >> 7;
                int b = (o & 127) ^ ((r & 7) << 4);
                gload_lds16(Wb + (size_t)(n0 + r) * K + kt * 64 + (b >> 1), Ws + lds_off);
            }
        } else {
#pragma unroll
            for (int it = 0; it < 4; ++it) {
                int c = tid + it * 256;
                int row = c >> 3, kc = (c & 7) << 3;
                int v = n0 + row;
                int kg = kt * 64 + kc;
                unsigned short hh[8] = {0,0,0,0,0,0,0,0};
                if (v < Nsplit) {
                    if (BF16B) {
                        *(int4*)hh = *(const int4*)(Wb + (size_t)v * K + kg);
                    } else if (kg + 8 <= Kv) {
                        const float* p = Wfa + (size_t)v * Kv;
                        float4 u0 = *(const float4*)(p + kg);
                        float4 u1 = *(const float4*)(p + kg + 4);
                        hh[0]=f2bf(u0.x); hh[1]=f2bf(u0.y); hh[2]=f2bf(u0.z); hh[3]=f2bf(u0.w);
                        hh[4]=f2bf(u1.x); hh[5]=f2bf(u1.y); hh[6]=f2bf(u1.z); hh[7]=f2bf(u1.w);
                    }
                } else if (v < N && Wfb != nullptr) {
                    const float* p = Wfb + (size_t)(v - Nsplit) * K;
                    float4 u0 = *(const float4*)(p + kg);
                    float4 u1 = *(const float4*)(p + kg + 4);
                    hh[0]=f2bf(u0.x); hh[1]=f2bf(u0.y); hh[2]=f2bf(u0.z); hh[3]=f2bf(u0.w);
                    hh[4]=f2bf(u1.x); hh[5]=f2bf(u1.y); hh[6]=f2bf(u1.z); hh[7]=f2bf(u1.w);
                }
                int off = (row * 128 + kc * 2) ^ ((row & 7) << 4);
                *(int4*)(Ws + off) = *(const int4*)hh;
            }
        }
#pragma unroll
        for (int j = 0; j < 4; ++j) {
            int lds_off = wid * 4096 + j * 1024;
            int o = lds_off + lane * 16;
            int r = o >> 7;
            int b = (o & 127) ^ ((r & 7) << 4);
            gload_lds16(H + (size_t)(t0 + r) * K + kt * 64 + (b >> 1), Hs + lds_off);
        }
        __syncthreads();
#pragma unroll
        for (int kk = 0; kk < 2; ++kk) {
            const int kbyte = (kk * 32 + ((lane >> 4) << 3)) * 2;
            short8 a[4], b[4];
#pragma unroll
            for (int mi = 0; mi < 4; ++mi) {
                int row = wm * 64 + mi * 16 + (lane & 15);
                int off = (row * 128 + kbyte) ^ ((row & 7) << 4);
                a[mi] = *(const short8*)(Ws + off);
            }
#pragma unroll
            for (int ni = 0; ni < 4; ++ni) {
                int row = wn * 64 + ni * 16 + (lane & 15);
                int off = (row * 128 + kbyte) ^ ((row & 7) << 4);
                b[ni] = *(const short8*)(Hs + off);
            }
#pragma unroll
            for (int mi = 0; mi < 4; ++mi)
#pragma unroll
                for (int ni = 0; ni < 4; ++ni)
                    acc[mi][ni] = __builtin_amdgcn_mfma_f32_16x16x32_bf16(a[mi], b[ni], acc[mi][ni], 0, 0, 0);
        }
        __syncthreads();
    }

    // ---- epilogue: lane-local vocab reduce in log2 domain ----
    float bvv[4][4];
#pragma unroll
    for (int mi = 0; mi < 4; ++mi)
#pragma unroll
        for (int r = 0; r < 4; ++r)
            bvv[mi][r] = bias_s[wm * 64 + mi * 16 + ((lane >> 4) << 2) + r];

#pragma unroll
    for (int ni = 0; ni < 4; ++ni) {
        float xs[16];
        float mx = -INFINITY;
#pragma unroll
        for (int mi = 0; mi < 4; ++mi)
#pragma unroll
            for (int r = 0; r < 4; ++r) {
                float x = fmaf(acc[mi][ni][r], LOG2E, bvv[mi][r]);
                xs[mi * 4 + r] = x;
                mx = fmaxf(mx, x);
            }
        mx = fmaxf(mx, __shfl_xor(mx, 16, 64));
        mx = fmaxf(mx, __shfl_xor(mx, 32, 64));
        float mxe = (mx == -INFINITY) ? 0.f : mx;
        float sm = 0.f;
#pragma unroll
        for (int i = 0; i < 16; ++i) sm += exp2f(xs[i] - mxe);
        sm += __shfl_xor(sm, 16, 64);
        sm += __shfl_xor(sm, 32, 64);
        if ((lane >> 4) == 0) {
            int tloc = wn * 64 + ni * 16 + lane;
            red[wm][tloc][0] = mx;
            red[wm][tloc][1] = sm;
        }
    }
    __syncthreads();
    if (tid < 128) {
        float m0v = red[0][tid][0], s0v = red[0][tid][1];
        float m1v = red[1][tid][0], s1v = red[1][tid][1];
        float M = fmaxf(m0v, m1v);
        float S = 0.f;
        if (s0v > 0.f) S += s0v * exp2f(m0v - M);
        if (s1v > 0.f) S += s1v * exp2f(m1v - M);
        size_t idx = (size_t)nt * 1024 + t0 + tid;
        pM[idx] = M;
        pS[idx] = S;
    }
}

// ---------- kernel 3b: W-resident tail GEMM (K padded to 64, fused f32 conversion) ----------
template<int KV>
__global__ __launch_bounds__(256)
void tail_lse_res(const float* __restrict__ Wf, int N,
                  const float* __restrict__ bias,
                  const unsigned short* __restrict__ Hc,   // [1024][64] compacted bf16
                  const int* __restrict__ cnt, int cidx,
                  float* __restrict__ pM, float* __restrict__ pS) {
    __shared__ __align__(16) char Ws[16384];
    __shared__ __align__(16) char Hs[2][16384];
    __shared__ float bias_s[128];
    __shared__ float red[2][2][128][2];
    const int tid = threadIdx.x, lane = tid & 63, wid = tid >> 6;
    const int wm = wid >> 1, wn = wid & 1;
    const int n0 = blockIdx.x * 128;

    // ---- stage W once: f32 -> bf16, swizzled, zero-pad k>=KV ----
#pragma unroll
    for (int it = 0; it < 4; ++it) {
        int c = tid + it * 256;
        int row = c >> 3, kc = (c & 7) << 3;
        int v = n0 + row;
        unsigned short hh[8] = {0,0,0,0,0,0,0,0};
        if (v < N && kc < KV) {
            const float* p = Wf + (size_t)v * KV + kc;
            float4 u0 = *(const float4*)p;
            float4 u1 = *(const float4*)(p + 4);
            hh[0]=f2bf(u0.x); hh[1]=f2bf(u0.y); hh[2]=f2bf(u0.z); hh[3]=f2bf(u0.w);
            hh[4]=f2bf(u1.x); hh[5]=f2bf(u1.y); hh[6]=f2bf(u1.z); hh[7]=f2bf(u1.w);
        }
        int off = (row * 128 + kc * 2) ^ ((row & 7) << 4);
        *(int4*)(Ws + off) = *(const int4*)hh;
    }
    if (tid < 128) {
        int v = n0 + tid;
        bias_s[tid] = (v < N) ? bias[v] * LOG2E : -INFINITY;
    }
    const int ntt = (cnt[cidx] + 127) >> 7;
    if (ntt > 0) {
#pragma unroll
        for (int j = 0; j < 4; ++j) {
            int lds_off = wid * 4096 + j * 1024;
            int o = lds_off + lane * 16;
            int r = o >> 7;
            int b = (o & 127) ^ ((r & 7) << 4);
            gload_lds16(Hc + (size_t)r * 64 + (b >> 1), Hs[0] + lds_off);
        }
    }
    __syncthreads();
    // ---- lift W fragments to registers (held across all token tiles) ----
    short8 a[2][4];
#pragma unroll
    for (int kk = 0; kk < 2; ++kk)
#pragma unroll
        for (int mi = 0; mi < 4; ++mi) {
            int row = wm * 64 + mi * 16 + (lane & 15);
            int kbyte = (kk * 32 + ((lane >> 4) << 3)) * 2;
            a[kk][mi] = *(const short8*)(Ws + ((row * 128 + kbyte) ^ ((row & 7) << 4)));
        }
    float bvv[4][4];
#pragma unroll
    for (int mi = 0; mi < 4; ++mi)
#pragma unroll
        for (int r = 0; r < 4; ++r)
            bvv[mi][r] = bias_s[wm * 64 + mi * 16 + ((lane >> 4) << 2) + r];

    for (int tt = 0; tt < ntt; ++tt) {
        const int cur = tt & 1;
        if (tt + 1 < ntt) {     // prefetch next H tile (latency hidden under MFMA+epilogue)
#pragma unroll
            for (int j = 0; j < 4; ++j) {
                int lds_off = wid * 4096 + j * 1024;
                int o = lds_off + lane * 16;
                int r = o >> 7;
                int b = (o & 127) ^ ((r & 7) << 4);
                gload_lds16(Hc + (size_t)((tt + 1) * 128 + r) * 64 + (b >> 1), Hs[cur ^ 1] + lds_off);
            }
        }
        f32x4 acc[4][4];
        const f32x4 zero = {0.f, 0.f, 0.f, 0.f};
#pragma unroll
        for (int i = 0; i < 4; ++i)
#pragma unroll
            for (int j = 0; j < 4; ++j) acc[i][j] = zero;
#pragma unroll
        for (int kk = 0; kk < 2; ++kk) {
            const int kbyte = (kk * 32 + ((lane >> 4) << 3)) * 2;
            short8 b[4];
#pragma unroll
            for (int ni = 0; ni < 4; ++ni) {
                int row = wn * 64 + ni * 16 + (lane & 15);
                b[ni] = *(const short8*)(Hs[cur] + ((row * 128 + kbyte) ^ ((row & 7) << 4)));
            }
#pragma unroll
            for (int mi = 0; mi < 4; ++mi)
#pragma unroll
                for (int ni = 0; ni < 4; ++ni)
                    acc[mi][ni] = __builtin_amdgcn_mfma_f32_16x16x32_bf16(a[kk][mi], b[ni], acc[mi][ni], 0, 0, 0);
        }
        // ---- epilogue (log2 domain) ----
#pragma unroll
        for (int ni = 0; ni < 4; ++ni) {
            float xs[16];
            float mx = -INFINITY;
#pragma unroll
            for (int mi = 0; mi < 4; ++mi)
#pragma unroll
                for (int r = 0; r < 4; ++r) {
                    float x = fmaf(acc[mi][ni][r], LOG2E, bvv[mi][r]);
                    xs[mi * 4 + r] = x;
                    mx = fmaxf(mx, x);
                }
            mx = fmaxf(mx, __shfl_xor(mx, 16, 64));
            mx = fmaxf(mx, __shfl_xor(mx, 32, 64));
            float mxe = (mx == -INFINITY) ? 0.f : mx;
            float sm = 0.f;
#pragma unroll
            for (int i = 0; i < 16; ++i) sm += exp2f(xs[i] - mxe);
            sm += __shfl_xor(sm, 16, 64);
            sm += __shfl_xor(sm, 32, 64);
            if ((lane >> 4) == 0) {
                int tloc = wn * 64 + ni * 16 + lane;
                red[cur][wm][tloc][0] = mx;
                red[cur][wm][tloc][1] = sm;
            }
        }
        __syncthreads();    // orders red + drains next-tile prefetch
        if (tid < 128) {
            float m0v = red[cur][0][tid][0], s0v = red[cur][0][tid][1];
            float m1v = red[cur][1][tid][0], s1v = red[cur][1][tid][1];
            float M = fmaxf(m0v, m1v);
            float S = 0.f;
            if (s0v > 0.f) S += s0v * exp2f(m0v - M);
            if (s1v > 0.f) S += s1v * exp2f(m1v - M);
            size_t idx = (size_t)blockIdx.x * 1024 + tt * 128 + tid;
            pM[idx] = M;
            pS[idx] = S;
        }
    }
}

// ---------- kernel 4a: stage-1 LSE reduce (log2 domain) ----------
__global__ __launch_bounds__(256)
void reduce_part(const float* __restrict__ pMh, const float* __restrict__ pSh, int nth,
                 const float* __restrict__ pM1, const float* __restrict__ pS1, int nt1,
                 const float* __restrict__ pM2, const float* __restrict__ pS2, int nt2,
                 const float* __restrict__ pM3, const float* __restrict__ pS3, int nt3,
                 float* __restrict__ pRm, float* __restrict__ pRs) {
    const int c = blockIdx.y, z = blockIdx.z;
    const float* PM = (c == 0) ? pMh : (c == 1) ? pM1 : (c == 2) ? pM2 : pM3;
    const float* PS = (c == 0) ? pSh : (c == 1) ? pS1 : (c == 2) ? pS2 : pS3;
    const int nt = (c == 0) ? nth : (c == 1) ? nt1 : (c == 2) ? nt2 : nt3;
    const int lane = threadIdx.x & 63;
    const int seg  = threadIdx.x >> 6;
    const int t = blockIdx.x * 64 + lane;
    float m = -INFINITY, s = 0.f;
    for (int i = z * 4 + seg; i < nt; i += 64) {
        float mi = PM[(size_t)i * 1024 + t];
        float si = PS[(size_t)i * 1024 + t];
        if (mi > m) { s = s * exp2f(m - mi) + si; m = mi; }
        else if (si > 0.f) { s += si * exp2f(mi - m); }
    }
    __shared__ float rm[4][64], rs[4][64];
    rm[seg][lane] = m; rs[seg][lane] = s;
    __syncthreads();
    if (seg == 0) {
#pragma unroll
        for (int q = 1; q < 4; ++q) {
            float om = rm[q][lane], os = rs[q][lane];
            if (om > m) { s = s * exp2f(m - om) + os; m = om; }
            else if (os > 0.f) { s += os * exp2f(om - m); }
        }
        size_t idx = ((size_t)c * 16 + z) * 1024 + t;
        pRm[idx] = m;
        pRs[idx] = s;
    }
}

// ---------- kernel 4b: stage-2 combine -> lse (natural log) ----------
__global__ __launch_bounds__(256)
void reduce_final(const float* __restrict__ pRm, const float* __restrict__ pRs,
                  float* __restrict__ lse) {
    const int c = blockIdx.y;
    const int lane = threadIdx.x & 63;
    const int seg  = threadIdx.x >> 6;
    const int t = blockIdx.x * 64 + lane;
    float m = -INFINITY, s = 0.f;
#pragma unroll
    for (int z = 0; z < 4; ++z) {
        size_t idx = ((size_t)c * 16 + seg * 4 + z) * 1024 + t;
        float om = pRm[idx], os = pRs[idx];
        if (om > m) { s = s * exp2f(m - om) + os; m = om; }
        else if (os > 0.f) { s += os * exp2f(om - m); }
    }
    __shared__ float rm[4][64], rs[4][64];
    rm[seg][lane] = m; rs[seg][lane] = s;
    __syncthreads();
    if (seg == 0) {
#pragma unroll
        for (int q = 1; q < 4; ++q) {
            float om = rm[q][lane], os = rs[q][lane];
            if (om > m) { s = s * exp2f(m - om) + os; m = om; }
            else if (os > 0.f) { s += os * exp2f(om - m); }
        }
        lse[c * 1024 + t] = LN2 * (m + log2f(s));
    }
}

// ---------- kernel 5: gather needed logits + assemble output ----------
__global__ void finalize(const float* __restrict__ hidden, const int* __restrict__ target,
                         const float* __restrict__ W_head, const float* __restrict__ b_head,
                         const float* __restrict__ W_clu, const float* __restrict__ b_clu,
                         const float* __restrict__ W1, const float* __restrict__ b1,
                         const float* __restrict__ W2, const float* __restrict__ b2,
                         const float* __restrict__ W3, const float* __restrict__ b3,
                         const unsigned short* __restrict__ proj1,
                         const unsigned short* __restrict__ proj2,
                         const unsigned short* __restrict__ proj3,
                         const int* __restrict__ slot,
                         const float* __restrict__ lse,   // [4][1024]
                         float* __restrict__ out) {
    const int t = blockIdx.x;
    const int lane = threadIdx.x;
    const int tgt = target[t];
    const int cid = (tgt >= 20000) + (tgt >= 40000) + (tgt >= 200000);
    const int j = (cid == 0) ? tgt : (20003 - cid);
    const float* wr = (j < 20000) ? (W_head + (size_t)j * 1024)
                                  : (W_clu + (size_t)(j - 20000) * 1024);
    float acc = 0.f;
#pragma unroll
    for (int i = 0; i < 4; ++i) {
        int k4 = lane + i * 64;
        float4 h = *(const float4*)(hidden + (size_t)t * 1024 + k4 * 4);
        float4 w = *(const float4*)(wr + k4 * 4);
        acc += h.x * w.x + h.y * w.y + h.z * w.z + h.w * w.w;
    }
#pragma unroll
    for (int msk = 1; msk < 64; msk <<= 1) acc += __shfl_xor(acc, msk, 64);
    float bj = (j < 20000) ? b_head[j] : b_clu[j - 20000];
    float res = (acc + bj) - lse[t];
    if (cid > 0) {
        const int starts[4] = {0, 20000, 40000, 200000};
        const int dims[4]   = {0, 256, 64, 16};
        const float* Wt = (cid == 1) ? W1 : (cid == 2) ? W2 : W3;
        const float* bt = (cid == 1) ? b1 : (cid == 2) ? b2 : b3;
        const unsigned short* pr = (cid == 1) ? proj1 + (size_t)t * 256
                                 : (cid == 2) ? proj2 + (size_t)t * 64
                                              : proj3 + (size_t)t * 64;
        int ti = tgt - starts[cid];
        int d  = dims[cid];
        const float* wt = Wt + (size_t)ti * d;
        float a2 = 0.f;
        for (int k = lane; k < d; k += 64) a2 += bf2f(pr[k]) * wt[k];
#pragma unroll
        for (int msk = 1; msk < 64; msk <<= 1) a2 += __shfl_xor(a2, msk, 64);
        res += (a2 + bt[ti]) - lse[cid * 1024 + slot[t]];
    }
    if (lane == 0) out[t] = -res;
}

// ---------- launch ----------
extern "C" void kernel_launch(void* const* d_in, const int* in_sizes, int n_in,
                              void* d_out, int out_size, void* d_ws, size_t ws_size,
                              hipStream_t stream) {
    const float* hidden = (const float*)d_in[0];
    const int*   target = (const int*)d_in[1];
    const float* W_head = (const float*)d_in[2];
    const float* b_head = (const float*)d_in[3];
    const float* W_clu  = (const float*)d_in[4];
    const float* b_clu  = (const float*)d_in[5];
    const float* P1 = (const float*)d_in[6];
    const float* W1 = (const float*)d_in[7];
    const float* b1 = (const float*)d_in[8];
    const float* P2 = (const float*)d_in[9];
    const float* W2 = (const float*)d_in[10];
    const float* b2 = (const float*)d_in[11];
    const float* P3 = (const float*)d_in[12];
    const float* W3 = (const float*)d_in[13];
    const float* b3 = (const float*)d_in[14];
    float* out = (float*)d_out;

    char* ws = (char*)d_ws;
    size_t off = 0;
    auto alloc = [&](size_t bytes) -> char* {
        char* p = ws + off;
        off += (bytes + 255) & ~(size_t)255;
        return p;
    };
    const int NT_H = 157;   // ceil(20003/128)
    const int NT_1 = 157;   // ceil(20000/128)
    const int NT_2 = 1250;  // 160000/128
    const int NT_3 = 530;   // ceil(67735/128)

    unsigned short* hbf   = (unsigned short*)alloc((size_t)1024 * 1024 * 2);
    unsigned short* proj1 = (unsigned short*)alloc((size_t)1024 * 256 * 2);
    unsigned short* proj2 = (unsigned short*)alloc((size_t)1024 * 64 * 2);
    unsigned short* proj3 = (unsigned short*)alloc((size_t)1024 * 64 * 2);
    unsigned short* Pb    = (unsigned short*)alloc((size_t)384 * 1024 * 2);
    int* cnt   = (int*)alloc(4 * 4);
    int* slot  = (int*)alloc(1024 * 4);
    int* lists = (int*)alloc(3 * 1024 * 4);
    unsigned short* Hc1 = (unsigned short*)alloc((size_t)1024 * 256 * 2);
    unsigned short* Hc2 = (unsigned short*)alloc((size_t)1024 * 64 * 2);
    unsigned short* Hc3 = (unsigned short*)alloc((size_t)1024 * 64 * 2);
    float* pMh = (float*)alloc((size_t)1024 * NT_H * 4);
    float* pSh = (float*)alloc((size_t)1024 * NT_H * 4);
    float* pM1 = (float*)alloc((size_t)1024 * NT_1 * 4);
    float* pS1 = (float*)alloc((size_t)1024 * NT_1 * 4);
    float* pM2 = (float*)alloc((size_t)1024 * NT_2 * 4);
    float* pS2 = (float*)alloc((size_t)1024 * NT_2 * 4);
    float* pM3 = (float*)alloc((size_t)1024 * NT_3 * 4);
    float* pS3 = (float*)alloc((size_t)1024 * NT_3 * 4);
    float* lse = (float*)alloc((size_t)4 * 1024 * 4);
    float* pRm = (float*)alloc((size_t)4 * 16 * 1024 * 4);
    float* pRs = (float*)alloc((size_t)4 * 16 * 1024 * 4);
    unsigned short* Whb = (unsigned short*)alloc((size_t)20000 * 1024 * 2);
    const bool pre = (off <= ws_size);

    convert_hidden<<<1024, 256, 0, stream>>>(hidden, hbf);
    // Pb = [P1; P2; P3; zeros] bf16
    convert_w<<<(65536 + 255) / 256, 256, 0, stream>>>(P1, Pb, 65536);
    convert_w<<<(16384 + 255) / 256, 256, 0, stream>>>(P2, Pb + (size_t)256 * 1024, 16384);
    convert_w<<<(4096 + 255) / 256, 256, 0, stream>>>(P3, Pb + (size_t)320 * 1024, 4096);
    (void)hipMemsetAsync(Pb + (size_t)336 * 1024, 0, (size_t)48 * 1024 * 2, stream);
    proj_mfma<<<dim3(8, 3), 256, 0, stream>>>(hbf, Pb, proj1, proj2, proj3);
    compact_tokens<<<1, 1024, 0, stream>>>(target, cnt, slot, lists);
    gather_proj<<<dim3(1024, 3), 64, 0, stream>>>(proj1, proj2, proj3, cnt, lists, Hc1, Hc2, Hc3);

    if (pre) {
        convert_w<<<(5120000 + 255) / 256, 256, 0, stream>>>(W_head, Whb, 5120000);
        gemm_lse_t<true><<<dim3(8, NT_H), 256, 0, stream>>>(
            Whb, nullptr, W_clu, 20000, 20003, 1024, 1024, 16,
            b_head, b_clu, hbf, nullptr, 0, pMh, pSh);
    } else {
        gemm_lse_t<false><<<dim3(8, NT_H), 256, 0, stream>>>(
            nullptr, W_head, W_clu, 20000, 20003, 1024, 1024, 16,
            b_head, b_clu, hbf, nullptr, 0, pMh, pSh);
    }
    // tail1: f32 W1 staged per active token tile (usually 1 after compaction)
    gemm_lse_t<false><<<dim3(8, NT_1), 256, 0, stream>>>(
        nullptr, W1, nullptr, 20000, 20000, 256, 256, 4,
        b1, nullptr, Hc1, cnt, 1, pM1, pS1);
    // tails 2/3: W-resident, fused f32 conversion, compacted tokens
    tail_lse_res<64><<<NT_2, 256, 0, stream>>>(W2, 160000, b2, Hc2, cnt, 2, pM2, pS2);
    tail_lse_res<16><<<NT_3, 256, 0, stream>>>(W3, 67735, b3, Hc3, cnt, 3, pM3, pS3);

    reduce_part<<<dim3(16, 4, 16), 256, 0, stream>>>(pMh, pSh, NT_H,
                                                     pM1, pS1, NT_1,
                                                     pM2, pS2, NT_2,
                                                     pM3, pS3, NT_3, pRm, pRs);
    reduce_final<<<dim3(16, 4), 256, 0, stream>>>(pRm, pRs, lse);

    finalize<<<1024, 64, 0, stream>>>(hidden, target,
                                      W_head, b_head, W_clu, b_clu,
                                      W1, b1, W2, b2, W3, b3,
                                      proj1, proj2, proj3, slot, lse, out);
}

// Round 8
// 229.674 us; speedup vs baseline: 2.3317x; 1.0369x over previous
//
#include <hip/hip_runtime.h>
#include <cstdint>
#include <cstddef>

// ---------- types ----------
typedef __attribute__((ext_vector_type(8))) short short8;   // 8 x bf16 (4 VGPR)
typedef __attribute__((ext_vector_type(4))) float f32x4;

#define LOG2E 1.4426950408889634f
#define LN2   0.6931471805599453f

__device__ __forceinline__ unsigned short f2bf(float x) {
    unsigned u = __float_as_uint(x);
    u += 0x7FFFu + ((u >> 16) & 1u);        // RNE
    return (unsigned short)(u >> 16);
}
__device__ __forceinline__ float bf2f(unsigned short h) {
    return __uint_as_float(((unsigned)h) << 16);
}

// async global->LDS, 16B per lane; LDS dest = uniform base + lane*16
__device__ __forceinline__ void gload_lds16(const void* g, void* l) {
    __builtin_amdgcn_global_load_lds(
        (const __attribute__((address_space(1))) unsigned int*)g,
        (__attribute__((address_space(3))) unsigned int*)l, 16, 0, 0);
}

// ---------- kernel 1: fused f32->bf16 conversion of everything ----------
// segments (in chunk units of 4 floats): [W_head nWh][W1 nW1][hidden 262144]
// [P1 65536][P2 16384][P3 4096][Pb zero tail 12288]
__global__ void mega_convert(const float* __restrict__ hidden,
                             const float* __restrict__ P1, const float* __restrict__ P2,
                             const float* __restrict__ P3,
                             const float* __restrict__ W_head, const float* __restrict__ W1,
                             unsigned short* __restrict__ hbf, unsigned short* __restrict__ Pb,
                             unsigned short* __restrict__ Whb, unsigned short* __restrict__ W1b,
                             int nWh, int nW1) {
    long i = (long)blockIdx.x * 256 + threadIdx.x;
    const float* src;
    unsigned short* dst;
    if (i < nWh)                      { src = W_head; dst = Whb; }
    else if ((i -= nWh) < nW1)        { src = W1;     dst = W1b; }
    else if ((i -= nW1) < 262144)     { src = hidden; dst = hbf; }
    else if ((i -= 262144) < 65536)   { src = P1;     dst = Pb; }
    else if ((i -= 65536) < 16384)    { src = P2;     dst = Pb + (size_t)256 * 1024; }
    else if ((i -= 16384) < 4096)     { src = P3;     dst = Pb + (size_t)320 * 1024; }
    else if ((i -= 4096) < 12288) {
        *(unsigned long long*)(Pb + (size_t)336 * 1024 + i * 4) = 0ull;
        return;
    } else return;
    float4 v = *(const float4*)(src + (size_t)i * 4);
    unsigned long long p = (unsigned long long)f2bf(v.x)
                         | ((unsigned long long)f2bf(v.y) << 16)
                         | ((unsigned long long)f2bf(v.z) << 32)
                         | ((unsigned long long)f2bf(v.w) << 48);
    *(unsigned long long*)(dst + (size_t)i * 4) = p;
}

// ---------- kernel 2: deterministic cluster compaction (1 block, 1024 threads) ----------
// slotc[t] = slot | (cid << 16)
__global__ __launch_bounds__(1024)
void compact_tokens(const int* __restrict__ target, int* __restrict__ cnt,
                    int* __restrict__ slotc) {
    const int t = threadIdx.x;
    const int tgt = target[t];
    const int cid = (tgt >= 20000) + (tgt >= 40000) + (tgt >= 200000);
    const int wave = t >> 6, lane = t & 63;
    unsigned long long lt = (lane == 0) ? 0ull : (~0ull >> (64 - lane));
    __shared__ int wtot[3][16];
    __shared__ int wbase[3][16];
    unsigned long long bal[3];
#pragma unroll
    for (int c = 1; c <= 3; ++c) {
        unsigned long long b = __ballot(cid == c);
        if (lane == 0) wtot[c - 1][wave] = (int)__popcll(b);
        bal[c - 1] = b;
    }
    __syncthreads();
    if (t < 3) {
        int s = 0;
        for (int w = 0; w < 16; ++w) { wbase[t][w] = s; s += wtot[t][w]; }
        cnt[t + 1] = s;
        if (t == 0) cnt[0] = 1024;
    }
    __syncthreads();
    int sl = t;
    if (cid > 0) sl = wbase[cid - 1][wave] + (int)__popcll(bal[cid - 1] & lt);
    slotc[t] = sl | (cid << 16);
}

// ---------- kernel 3: MFMA projection, writes DIRECTLY into compacted Hc buffers ----------
__global__ __launch_bounds__(256)
void proj_mfma(const unsigned short* __restrict__ Hb,   // [1024][1024]
               const unsigned short* __restrict__ Pb,   // [384][1024]
               const int* __restrict__ slotc,
               unsigned short* __restrict__ Hc1,        // [1024][256] compacted
               unsigned short* __restrict__ Hc2,        // [1024][64]
               unsigned short* __restrict__ Hc3) {      // [1024][64]
    __shared__ __align__(16) char As[16384];
    __shared__ __align__(16) char Bs[16384];
    __shared__ int sl_s[128];
    const int tid  = threadIdx.x;
    const int lane = tid & 63;
    const int wid  = tid >> 6;
    const int wm = wid >> 1, wn = wid & 1;
    const int tt = blockIdx.x, dt = blockIdx.y;
    const int t0 = tt * 128, d0 = dt * 128;

    f32x4 acc[4][4];
    const f32x4 zero = {0.f, 0.f, 0.f, 0.f};
#pragma unroll
    for (int i = 0; i < 4; ++i)
#pragma unroll
        for (int j = 0; j < 4; ++j) acc[i][j] = zero;

    for (int kt = 0; kt < 16; ++kt) {
#pragma unroll
        for (int j = 0; j < 4; ++j) {
            int lds_off = wid * 4096 + j * 1024;
            int o = lds_off + lane * 16;
            int r = o >> 7;
            int b = (o & 127) ^ ((r & 7) << 4);
            gload_lds16(Hb + (size_t)(t0 + r) * 1024 + kt * 64 + (b >> 1), As + lds_off);
        }
#pragma unroll
        for (int j = 0; j < 4; ++j) {
            int lds_off = wid * 4096 + j * 1024;
            int o = lds_off + lane * 16;
            int r = o >> 7;
            int b = (o & 127) ^ ((r & 7) << 4);
            gload_lds16(Pb + (size_t)(d0 + r) * 1024 + kt * 64 + (b >> 1), Bs + lds_off);
        }
        __syncthreads();
#pragma unroll
        for (int kk = 0; kk < 2; ++kk) {
            const int kbyte = (kk * 32 + ((lane >> 4) << 3)) * 2;
            short8 a[4], b[4];
#pragma unroll
            for (int mi = 0; mi < 4; ++mi) {
                int row = wm * 64 + mi * 16 + (lane & 15);
                int off = (row * 128 + kbyte) ^ ((row & 7) << 4);
                a[mi] = *(const short8*)(As + off);
            }
#pragma unroll
            for (int ni = 0; ni < 4; ++ni) {
                int row = wn * 64 + ni * 16 + (lane & 15);
                int off = (row * 128 + kbyte) ^ ((row & 7) << 4);
                b[ni] = *(const short8*)(Bs + off);
            }
#pragma unroll
            for (int mi = 0; mi < 4; ++mi)
#pragma unroll
                for (int ni = 0; ni < 4; ++ni)
                    acc[mi][ni] = __builtin_amdgcn_mfma_f32_16x16x32_bf16(a[mi], b[ni], acc[mi][ni], 0, 0, 0);
        }
        __syncthreads();
    }

    if (tid < 128) sl_s[tid] = slotc[t0 + tid];
    __syncthreads();

    // epilogue: C row = token, C col = d; scatter to compacted buffer of d's cluster
#pragma unroll
    for (int ni = 0; ni < 4; ++ni) {
        int dg = d0 + wn * 64 + ni * 16 + (lane & 15);
        unsigned short* base;
        int c_d, dd, stride;
        if (dg < 256)      { c_d = 1; dd = dg;       base = Hc1; stride = 256; }
        else if (dg < 320) { c_d = 2; dd = dg - 256; base = Hc2; stride = 64;  }
        else               { c_d = 3; dd = dg - 320; base = Hc3; stride = 64;  }
#pragma unroll
        for (int mi = 0; mi < 4; ++mi)
#pragma unroll
            for (int r = 0; r < 4; ++r) {
                int tl = wm * 64 + mi * 16 + ((lane >> 4) << 2) + r;
                int sc = sl_s[tl];
                if ((sc >> 16) == c_d)
                    base[(size_t)(sc & 0xFFFF) * stride + dd] = f2bf(acc[mi][ni][r]);
            }
    }
}

// ---------- kernel 4: head GEMM, 128 vocab x 256 tokens, 512 threads, XCD-grouped ----------
// blocks with the same vocab tile share b%8 -> same XCD -> W tile fetched once per L2.
template<bool BF16B>
__global__ __launch_bounds__(512)
void head_lse(const unsigned short* __restrict__ Wb,    // bf16 [Nsplit][K]
              const float* __restrict__ Wfa,            // f32 [Nsplit][K] (fallback)
              const float* __restrict__ Wfb,            // f32 extra rows (W_clu)
              int Nsplit, int N, int K, int KTILES, int NTQ,
              const float* __restrict__ bias1, const float* __restrict__ bias2,
              const unsigned short* __restrict__ H,     // bf16 [1024][K]
              float* __restrict__ pM, float* __restrict__ pS) {
    const int b = blockIdx.x;
    const int nt = (b >> 5) * 8 + (b & 7);
    const int tt = (b >> 3) & 3;
    if (nt >= NTQ) return;
    __shared__ __align__(16) char Ws[16384];
    __shared__ __align__(16) char Hs[32768];
    __shared__ float bias_s[128];
    __shared__ float red[2][256][2];
    const int tid = threadIdx.x, lane = tid & 63, wid = tid >> 6;
    const int wm = wid >> 2, wn = wid & 3;
    const int t0 = tt * 256, n0 = nt * 128;
    const bool clean = BF16B && (n0 + 128 <= Nsplit);

    if (tid < 128) {
        int v = n0 + tid;
        bias_s[tid] = (v < Nsplit) ? bias1[v] * LOG2E
                    : (v < N)      ? bias2[v - Nsplit] * LOG2E
                                   : -INFINITY;
    }

    f32x4 acc[4][4];
    const f32x4 zero = {0.f, 0.f, 0.f, 0.f};
#pragma unroll
    for (int i = 0; i < 4; ++i)
#pragma unroll
        for (int j = 0; j < 4; ++j) acc[i][j] = zero;

    for (int kt = 0; kt < KTILES; ++kt) {
        if (clean) {
#pragma unroll
            for (int j = 0; j < 2; ++j) {
                int lds_off = j * 8192 + wid * 1024;
                int o = lds_off + lane * 16;
                int r = o >> 7;
                int bb = (o & 127) ^ ((r & 7) << 4);
                gload_lds16(Wb + (size_t)(n0 + r) * K + kt * 64 + (bb >> 1), Ws + lds_off);
            }
        } else {
#pragma unroll
            for (int it = 0; it < 2; ++it) {
                int c = tid + it * 512;
                int row = c >> 3, kc = (c & 7) << 3;
                int v = n0 + row;
                int kg = kt * 64 + kc;
                unsigned short hh[8] = {0,0,0,0,0,0,0,0};
                if (v < Nsplit) {
                    if (BF16B) {
                        *(int4*)hh = *(const int4*)(Wb + (size_t)v * K + kg);
                    } else {
                        const float* p = Wfa + (size_t)v * K + kg;
                        float4 u0 = *(const float4*)p;
                        float4 u1 = *(const float4*)(p + 4);
                        hh[0]=f2bf(u0.x); hh[1]=f2bf(u0.y); hh[2]=f2bf(u0.z); hh[3]=f2bf(u0.w);
                        hh[4]=f2bf(u1.x); hh[5]=f2bf(u1.y); hh[6]=f2bf(u1.z); hh[7]=f2bf(u1.w);
                    }
                } else if (v < N && Wfb != nullptr) {
                    const float* p = Wfb + (size_t)(v - Nsplit) * K + kg;
                    float4 u0 = *(const float4*)p;
                    float4 u1 = *(const float4*)(p + 4);
                    hh[0]=f2bf(u0.x); hh[1]=f2bf(u0.y); hh[2]=f2bf(u0.z); hh[3]=f2bf(u0.w);
                    hh[4]=f2bf(u1.x); hh[5]=f2bf(u1.y); hh[6]=f2bf(u1.z); hh[7]=f2bf(u1.w);
                }
                int off = (row * 128 + kc * 2) ^ ((row & 7) << 4);
                *(int4*)(Ws + off) = *(const int4*)hh;
            }
        }
#pragma unroll
        for (int j = 0; j < 4; ++j) {
            int lds_off = j * 8192 + wid * 1024;
            int o = lds_off + lane * 16;
            int r = o >> 7;
            int bb = (o & 127) ^ ((r & 7) << 4);
            gload_lds16(H + (size_t)(t0 + r) * K + kt * 64 + (bb >> 1), Hs + lds_off);
        }
        __syncthreads();
#pragma unroll
        for (int kk = 0; kk < 2; ++kk) {
            const int kbyte = (kk * 32 + ((lane >> 4) << 3)) * 2;
            short8 a[4], bq[4];
#pragma unroll
            for (int mi = 0; mi < 4; ++mi) {
                int row = wm * 64 + mi * 16 + (lane & 15);
                int off = (row * 128 + kbyte) ^ ((row & 7) << 4);
                a[mi] = *(const short8*)(Ws + off);
            }
#pragma unroll
            for (int ni = 0; ni < 4; ++ni) {
                int row = wn * 64 + ni * 16 + (lane & 15);
                int off = (row * 128 + kbyte) ^ ((row & 7) << 4);
                bq[ni] = *(const short8*)(Hs + off);
            }
#pragma unroll
            for (int mi = 0; mi < 4; ++mi)
#pragma unroll
                for (int ni = 0; ni < 4; ++ni)
                    acc[mi][ni] = __builtin_amdgcn_mfma_f32_16x16x32_bf16(a[mi], bq[ni], acc[mi][ni], 0, 0, 0);
        }
        __syncthreads();
    }

    // epilogue: lane-local vocab reduce (log2 domain)
    float bvv[4][4];
#pragma unroll
    for (int mi = 0; mi < 4; ++mi)
#pragma unroll
        for (int r = 0; r < 4; ++r)
            bvv[mi][r] = bias_s[wm * 64 + mi * 16 + ((lane >> 4) << 2) + r];

#pragma unroll
    for (int ni = 0; ni < 4; ++ni) {
        float xs[16];
        float mx = -INFINITY;
#pragma unroll
        for (int mi = 0; mi < 4; ++mi)
#pragma unroll
            for (int r = 0; r < 4; ++r) {
                float x = fmaf(acc[mi][ni][r], LOG2E, bvv[mi][r]);
                xs[mi * 4 + r] = x;
                mx = fmaxf(mx, x);
            }
        mx = fmaxf(mx, __shfl_xor(mx, 16, 64));
        mx = fmaxf(mx, __shfl_xor(mx, 32, 64));
        float mxe = (mx == -INFINITY) ? 0.f : mx;
        float sm = 0.f;
#pragma unroll
        for (int i = 0; i < 16; ++i) sm += exp2f(xs[i] - mxe);
        sm += __shfl_xor(sm, 16, 64);
        sm += __shfl_xor(sm, 32, 64);
        if ((lane >> 4) == 0) {
            int tloc = wn * 64 + ni * 16 + lane;
            red[wm][tloc][0] = mx;
            red[wm][tloc][1] = sm;
        }
    }
    __syncthreads();
    if (tid < 256) {
        float m0v = red[0][tid][0], s0v = red[0][tid][1];
        float m1v = red[1][tid][0], s1v = red[1][tid][1];
        float M = fmaxf(m0v, m1v);
        float S = 0.f;
        if (s0v > 0.f) S += s0v * exp2f(m0v - M);
        if (s1v > 0.f) S += s1v * exp2f(m1v - M);
        size_t idx = (size_t)nt * 1024 + t0 + tid;
        pM[idx] = M;
        pS[idx] = S;
    }
}

// ---------- kernel 5: 128x128 GEMM + LSE (tail1; cnt-guarded) ----------
template<bool BF16B>
__global__ __launch_bounds__(256)
void gemm_lse_t(const unsigned short* __restrict__ Wb,
                const float* __restrict__ Wfa, const float* __restrict__ Wfb,
                int Nsplit, int N, int K, int Kv, int KTILES,
                const float* __restrict__ bias1, const float* __restrict__ bias2,
                const unsigned short* __restrict__ H,
                const int* __restrict__ cnt_p, int cidx,
                float* __restrict__ pM, float* __restrict__ pS) {
    if (cnt_p && (int)blockIdx.x * 128 >= cnt_p[cidx]) return;
    __shared__ __align__(16) char Ws[16384];
    __shared__ __align__(16) char Hs[16384];
    __shared__ float bias_s[128];
    __shared__ float red[2][128][2];
    const int tid  = threadIdx.x;
    const int lane = tid & 63;
    const int wid  = tid >> 6;
    const int wm = wid >> 1, wn = wid & 1;
    const int tt = blockIdx.x, nt = blockIdx.y;
    const int t0 = tt * 128, n0 = nt * 128;
    const bool clean = BF16B && (n0 + 128 <= Nsplit);

    if (tid < 128) {
        int v = n0 + tid;
        bias_s[tid] = (v < Nsplit) ? bias1[v] * LOG2E
                    : (v < N)      ? bias2[v - Nsplit] * LOG2E
                                   : -INFINITY;
    }

    f32x4 acc[4][4];
    const f32x4 zero = {0.f, 0.f, 0.f, 0.f};
#pragma unroll
    for (int i = 0; i < 4; ++i)
#pragma unroll
        for (int j = 0; j < 4; ++j) acc[i][j] = zero;

    for (int kt = 0; kt < KTILES; ++kt) {
        if (clean) {
#pragma unroll
            for (int j = 0; j < 4; ++j) {
                int lds_off = wid * 4096 + j * 1024;
                int o = lds_off + lane * 16;
                int r = o >> 7;
                int b = (o & 127) ^ ((r & 7) << 4);
                gload_lds16(Wb + (size_t)(n0 + r) * K + kt * 64 + (b >> 1), Ws + lds_off);
            }
        } else {
#pragma unroll
            for (int it = 0; it < 4; ++it) {
                int c = tid + it * 256;
                int row = c >> 3, kc = (c & 7) << 3;
                int v = n0 + row;
                int kg = kt * 64 + kc;
                unsigned short hh[8] = {0,0,0,0,0,0,0,0};
                if (v < Nsplit) {
                    if (BF16B) {
                        *(int4*)hh = *(const int4*)(Wb + (size_t)v * K + kg);
                    } else if (kg + 8 <= Kv) {
                        const float* p = Wfa + (size_t)v * Kv;
                        float4 u0 = *(const float4*)(p + kg);
                        float4 u1 = *(const float4*)(p + kg + 4);
                        hh[0]=f2bf(u0.x); hh[1]=f2bf(u0.y); hh[2]=f2bf(u0.z); hh[3]=f2bf(u0.w);
                        hh[4]=f2bf(u1.x); hh[5]=f2bf(u1.y); hh[6]=f2bf(u1.z); hh[7]=f2bf(u1.w);
                    }
                } else if (v < N && Wfb != nullptr) {
                    const float* p = Wfb + (size_t)(v - Nsplit) * K;
                    float4 u0 = *(const float4*)(p + kg);
                    float4 u1 = *(const float4*)(p + kg + 4);
                    hh[0]=f2bf(u0.x); hh[1]=f2bf(u0.y); hh[2]=f2bf(u0.z); hh[3]=f2bf(u0.w);
                    hh[4]=f2bf(u1.x); hh[5]=f2bf(u1.y); hh[6]=f2bf(u1.z); hh[7]=f2bf(u1.w);
                }
                int off = (row * 128 + kc * 2) ^ ((row & 7) << 4);
                *(int4*)(Ws + off) = *(const int4*)hh;
            }
        }
#pragma unroll
        for (int j = 0; j < 4; ++j) {
            int lds_off = wid * 4096 + j * 1024;
            int o = lds_off + lane * 16;
            int r = o >> 7;
            int b = (o & 127) ^ ((r & 7) << 4);
            gload_lds16(H + (size_t)(t0 + r) * K + kt * 64 + (b >> 1), Hs + lds_off);
        }
        __syncthreads();
#pragma unroll
        for (int kk = 0; kk < 2; ++kk) {
            const int kbyte = (kk * 32 + ((lane >> 4) << 3)) * 2;
            short8 a[4], b[4];
#pragma unroll
            for (int mi = 0; mi < 4; ++mi) {
                int row = wm * 64 + mi * 16 + (lane & 15);
                int off = (row * 128 + kbyte) ^ ((row & 7) << 4);
                a[mi] = *(const short8*)(Ws + off);
            }
#pragma unroll
            for (int ni = 0; ni < 4; ++ni) {
                int row = wn * 64 + ni * 16 + (lane & 15);
                int off = (row * 128 + kbyte) ^ ((row & 7) << 4);
                b[ni] = *(const short8*)(Hs + off);
            }
#pragma unroll
            for (int mi = 0; mi < 4; ++mi)
#pragma unroll
                for (int ni = 0; ni < 4; ++ni)
                    acc[mi][ni] = __builtin_amdgcn_mfma_f32_16x16x32_bf16(a[mi], b[ni], acc[mi][ni], 0, 0, 0);
        }
        __syncthreads();
    }

    float bvv[4][4];
#pragma unroll
    for (int mi = 0; mi < 4; ++mi)
#pragma unroll
        for (int r = 0; r < 4; ++r)
            bvv[mi][r] = bias_s[wm * 64 + mi * 16 + ((lane >> 4) << 2) + r];

#pragma unroll
    for (int ni = 0; ni < 4; ++ni) {
        float xs[16];
        float mx = -INFINITY;
#pragma unroll
        for (int mi = 0; mi < 4; ++mi)
#pragma unroll
            for (int r = 0; r < 4; ++r) {
                float x = fmaf(acc[mi][ni][r], LOG2E, bvv[mi][r]);
                xs[mi * 4 + r] = x;
                mx = fmaxf(mx, x);
            }
        mx = fmaxf(mx, __shfl_xor(mx, 16, 64));
        mx = fmaxf(mx, __shfl_xor(mx, 32, 64));
        float mxe = (mx == -INFINITY) ? 0.f : mx;
        float sm = 0.f;
#pragma unroll
        for (int i = 0; i < 16; ++i) sm += exp2f(xs[i] - mxe);
        sm += __shfl_xor(sm, 16, 64);
        sm += __shfl_xor(sm, 32, 64);
        if ((lane >> 4) == 0) {
            int tloc = wn * 64 + ni * 16 + lane;
            red[wm][tloc][0] = mx;
            red[wm][tloc][1] = sm;
        }
    }
    __syncthreads();
    if (tid < 128) {
        float m0v = red[0][tid][0], s0v = red[0][tid][1];
        float m1v = red[1][tid][0], s1v = red[1][tid][1];
        float M = fmaxf(m0v, m1v);
        float S = 0.f;
        if (s0v > 0.f) S += s0v * exp2f(m0v - M);
        if (s1v > 0.f) S += s1v * exp2f(m1v - M);
        size_t idx = (size_t)nt * 1024 + t0 + tid;
        pM[idx] = M;
        pS[idx] = S;
    }
}

// ---------- kernel 6: W-resident tail GEMM (K<=64, fused f32 conversion) ----------
template<int KV>
__global__ __launch_bounds__(256)
void tail_lse_res(const float* __restrict__ Wf, int N,
                  const float* __restrict__ bias,
                  const unsigned short* __restrict__ Hc,
                  const int* __restrict__ cnt, int cidx,
                  float* __restrict__ pM, float* __restrict__ pS) {
    __shared__ __align__(16) char Ws[16384];
    __shared__ __align__(16) char Hs[2][16384];
    __shared__ float bias_s[128];
    __shared__ float red[2][2][128][2];
    const int tid = threadIdx.x, lane = tid & 63, wid = tid >> 6;
    const int wm = wid >> 1, wn = wid & 1;
    const int n0 = blockIdx.x * 128;

#pragma unroll
    for (int it = 0; it < 4; ++it) {
        int c = tid + it * 256;
        int row = c >> 3, kc = (c & 7) << 3;
        int v = n0 + row;
        unsigned short hh[8] = {0,0,0,0,0,0,0,0};
        if (v < N && kc < KV) {
            const float* p = Wf + (size_t)v * KV + kc;
            float4 u0 = *(const float4*)p;
            float4 u1 = *(const float4*)(p + 4);
            hh[0]=f2bf(u0.x); hh[1]=f2bf(u0.y); hh[2]=f2bf(u0.z); hh[3]=f2bf(u0.w);
            hh[4]=f2bf(u1.x); hh[5]=f2bf(u1.y); hh[6]=f2bf(u1.z); hh[7]=f2bf(u1.w);
        }
        int off = (row * 128 + kc * 2) ^ ((row & 7) << 4);
        *(int4*)(Ws + off) = *(const int4*)hh;
    }
    if (tid < 128) {
        int v = n0 + tid;
        bias_s[tid] = (v < N) ? bias[v] * LOG2E : -INFINITY;
    }
    const int ntt = (cnt[cidx] + 127) >> 7;
    if (ntt > 0) {
#pragma unroll
        for (int j = 0; j < 4; ++j) {
            int lds_off = wid * 4096 + j * 1024;
            int o = lds_off + lane * 16;
            int r = o >> 7;
            int b = (o & 127) ^ ((r & 7) << 4);
            gload_lds16(Hc + (size_t)r * 64 + (b >> 1), Hs[0] + lds_off);
        }
    }
    __syncthreads();
    short8 a[2][4];
#pragma unroll
    for (int kk = 0; kk < 2; ++kk)
#pragma unroll
        for (int mi = 0; mi < 4; ++mi) {
            int row = wm * 64 + mi * 16 + (lane & 15);
            int kbyte = (kk * 32 + ((lane >> 4) << 3)) * 2;
            a[kk][mi] = *(const short8*)(Ws + ((row * 128 + kbyte) ^ ((row & 7) << 4)));
        }
    float bvv[4][4];
#pragma unroll
    for (int mi = 0; mi < 4; ++mi)
#pragma unroll
        for (int r = 0; r < 4; ++r)
            bvv[mi][r] = bias_s[wm * 64 + mi * 16 + ((lane >> 4) << 2) + r];

    for (int tt = 0; tt < ntt; ++tt) {
        const int cur = tt & 1;
        if (tt + 1 < ntt) {
#pragma unroll
            for (int j = 0; j < 4; ++j) {
                int lds_off = wid * 4096 + j * 1024;
                int o = lds_off + lane * 16;
                int r = o >> 7;
                int b = (o & 127) ^ ((r & 7) << 4);
                gload_lds16(Hc + (size_t)((tt + 1) * 128 + r) * 64 + (b >> 1), Hs[cur ^ 1] + lds_off);
            }
        }
        f32x4 acc[4][4];
        const f32x4 zero = {0.f, 0.f, 0.f, 0.f};
#pragma unroll
        for (int i = 0; i < 4; ++i)
#pragma unroll
            for (int j = 0; j < 4; ++j) acc[i][j] = zero;
#pragma unroll
        for (int kk = 0; kk < 2; ++kk) {
            const int kbyte = (kk * 32 + ((lane >> 4) << 3)) * 2;
            short8 b[4];
#pragma unroll
            for (int ni = 0; ni < 4; ++ni) {
                int row = wn * 64 + ni * 16 + (lane & 15);
                b[ni] = *(const short8*)(Hs[cur] + ((row * 128 + kbyte) ^ ((row & 7) << 4)));
            }
#pragma unroll
            for (int mi = 0; mi < 4; ++mi)
#pragma unroll
                for (int ni = 0; ni < 4; ++ni)
                    acc[mi][ni] = __builtin_amdgcn_mfma_f32_16x16x32_bf16(a[kk][mi], b[ni], acc[mi][ni], 0, 0, 0);
        }
#pragma unroll
        for (int ni = 0; ni < 4; ++ni) {
            float xs[16];
            float mx = -INFINITY;
#pragma unroll
            for (int mi = 0; mi < 4; ++mi)
#pragma unroll
                for (int r = 0; r < 4; ++r) {
                    float x = fmaf(acc[mi][ni][r], LOG2E, bvv[mi][r]);
                    xs[mi * 4 + r] = x;
                    mx = fmaxf(mx, x);
                }
            mx = fmaxf(mx, __shfl_xor(mx, 16, 64));
            mx = fmaxf(mx, __shfl_xor(mx, 32, 64));
            float mxe = (mx == -INFINITY) ? 0.f : mx;
            float sm = 0.f;
#pragma unroll
            for (int i = 0; i < 16; ++i) sm += exp2f(xs[i] - mxe);
            sm += __shfl_xor(sm, 16, 64);
            sm += __shfl_xor(sm, 32, 64);
            if ((lane >> 4) == 0) {
                int tloc = wn * 64 + ni * 16 + lane;
                red[cur][wm][tloc][0] = mx;
                red[cur][wm][tloc][1] = sm;
            }
        }
        __syncthreads();
        if (tid < 128) {
            float m0v = red[cur][0][tid][0], s0v = red[cur][0][tid][1];
            float m1v = red[cur][1][tid][0], s1v = red[cur][1][tid][1];
            float M = fmaxf(m0v, m1v);
            float S = 0.f;
            if (s0v > 0.f) S += s0v * exp2f(m0v - M);
            if (s1v > 0.f) S += s1v * exp2f(m1v - M);
            size_t idx = (size_t)blockIdx.x * 1024 + tt * 128 + tid;
            pM[idx] = M;
            pS[idx] = S;
        }
    }
}

// ---------- kernel 7a: stage-1 LSE reduce ----------
__global__ __launch_bounds__(256)
void reduce_part(const float* __restrict__ pMh, const float* __restrict__ pSh, int nth,
                 const float* __restrict__ pM1, const float* __restrict__ pS1, int nt1,
                 const float* __restrict__ pM2, const float* __restrict__ pS2, int nt2,
                 const float* __restrict__ pM3, const float* __restrict__ pS3, int nt3,
                 float* __restrict__ pRm, float* __restrict__ pRs) {
    const int c = blockIdx.y, z = blockIdx.z;
    const float* PM = (c == 0) ? pMh : (c == 1) ? pM1 : (c == 2) ? pM2 : pM3;
    const float* PS = (c == 0) ? pSh : (c == 1) ? pS1 : (c == 2) ? pS2 : pS3;
    const int nt = (c == 0) ? nth : (c == 1) ? nt1 : (c == 2) ? nt2 : nt3;
    const int lane = threadIdx.x & 63;
    const int seg  = threadIdx.x >> 6;
    const int t = blockIdx.x * 64 + lane;
    float m = -INFINITY, s = 0.f;
    for (int i = z * 4 + seg; i < nt; i += 64) {
        float mi = PM[(size_t)i * 1024 + t];
        float si = PS[(size_t)i * 1024 + t];
        if (mi > m) { s = s * exp2f(m - mi) + si; m = mi; }
        else if (si > 0.f) { s += si * exp2f(mi - m); }
    }
    __shared__ float rm[4][64], rs[4][64];
    rm[seg][lane] = m; rs[seg][lane] = s;
    __syncthreads();
    if (seg == 0) {
#pragma unroll
        for (int q = 1; q < 4; ++q) {
            float om = rm[q][lane], os = rs[q][lane];
            if (om > m) { s = s * exp2f(m - om) + os; m = om; }
            else if (os > 0.f) { s += os * exp2f(om - m); }
        }
        size_t idx = ((size_t)c * 16 + z) * 1024 + t;
        pRm[idx] = m;
        pRs[idx] = s;
    }
}

// ---------- kernel 7b: stage-2 combine -> lse ----------
__global__ __launch_bounds__(256)
void reduce_final(const float* __restrict__ pRm, const float* __restrict__ pRs,
                  float* __restrict__ lse) {
    const int c = blockIdx.y;
    const int lane = threadIdx.x & 63;
    const int seg  = threadIdx.x >> 6;
    const int t = blockIdx.x * 64 + lane;
    float m = -INFINITY, s = 0.f;
#pragma unroll
    for (int z = 0; z < 4; ++z) {
        size_t idx = ((size_t)c * 16 + seg * 4 + z) * 1024 + t;
        float om = pRm[idx], os = pRs[idx];
        if (om > m) { s = s * exp2f(m - om) + os; m = om; }
        else if (os > 0.f) { s += os * exp2f(om - m); }
    }
    __shared__ float rm[4][64], rs[4][64];
    rm[seg][lane] = m; rs[seg][lane] = s;
    __syncthreads();
    if (seg == 0) {
#pragma unroll
        for (int q = 1; q < 4; ++q) {
            float om = rm[q][lane], os = rs[q][lane];
            if (om > m) { s = s * exp2f(m - om) + os; m = om; }
            else if (os > 0.f) { s += os * exp2f(om - m); }
        }
        lse[c * 1024 + t] = LN2 * (m + log2f(s));
    }
}

// ---------- kernel 8: gather needed logits + assemble output ----------
__global__ void finalize(const float* __restrict__ hidden, const int* __restrict__ target,
                         const float* __restrict__ W_head, const float* __restrict__ b_head,
                         const float* __restrict__ W_clu, const float* __restrict__ b_clu,
                         const float* __restrict__ W1, const float* __restrict__ b1,
                         const float* __restrict__ W2, const float* __restrict__ b2,
                         const float* __restrict__ W3, const float* __restrict__ b3,
                         const unsigned short* __restrict__ Hc1,
                         const unsigned short* __restrict__ Hc2,
                         const unsigned short* __restrict__ Hc3,
                         const int* __restrict__ slotc,
                         const float* __restrict__ lse,   // [4][1024]
                         float* __restrict__ out) {
    const int t = blockIdx.x;
    const int lane = threadIdx.x;
    const int tgt = target[t];
    const int cid = (tgt >= 20000) + (tgt >= 40000) + (tgt >= 200000);
    const int j = (cid == 0) ? tgt : (20003 - cid);
    const float* wr = (j < 20000) ? (W_head + (size_t)j * 1024)
                                  : (W_clu + (size_t)(j - 20000) * 1024);
    float acc = 0.f;
#pragma unroll
    for (int i = 0; i < 4; ++i) {
        int k4 = lane + i * 64;
        float4 h = *(const float4*)(hidden + (size_t)t * 1024 + k4 * 4);
        float4 w = *(const float4*)(wr + k4 * 4);
        acc += h.x * w.x + h.y * w.y + h.z * w.z + h.w * w.w;
    }
#pragma unroll
    for (int msk = 1; msk < 64; msk <<= 1) acc += __shfl_xor(acc, msk, 64);
    float bj = (j < 20000) ? b_head[j] : b_clu[j - 20000];
    float res = (acc + bj) - lse[t];
    if (cid > 0) {
        const int starts[4] = {0, 20000, 40000, 200000};
        const int dims[4]   = {0, 256, 64, 16};
        const int slot = slotc[t] & 0xFFFF;
        const float* Wt = (cid == 1) ? W1 : (cid == 2) ? W2 : W3;
        const float* bt = (cid == 1) ? b1 : (cid == 2) ? b2 : b3;
        const unsigned short* pr = (cid == 1) ? Hc1 + (size_t)slot * 256
                                 : (cid == 2) ? Hc2 + (size_t)slot * 64
                                              : Hc3 + (size_t)slot * 64;
        int ti = tgt - starts[cid];
        int d  = dims[cid];
        const float* wt = Wt + (size_t)ti * d;
        float a2 = 0.f;
        for (int k = lane; k < d; k += 64) a2 += bf2f(pr[k]) * wt[k];
#pragma unroll
        for (int msk = 1; msk < 64; msk <<= 1) a2 += __shfl_xor(a2, msk, 64);
        res += (a2 + bt[ti]) - lse[cid * 1024 + slot];
    }
    if (lane == 0) out[t] = -res;
}

// ---------- launch ----------
extern "C" void kernel_launch(void* const* d_in, const int* in_sizes, int n_in,
                              void* d_out, int out_size, void* d_ws, size_t ws_size,
                              hipStream_t stream) {
    const float* hidden = (const float*)d_in[0];
    const int*   target = (const int*)d_in[1];
    const float* W_head = (const float*)d_in[2];
    const float* b_head = (const float*)d_in[3];
    const float* W_clu  = (const float*)d_in[4];
    const float* b_clu  = (const float*)d_in[5];
    const float* P1 = (const float*)d_in[6];
    const float* W1 = (const float*)d_in[7];
    const float* b1 = (const float*)d_in[8];
    const float* P2 = (const float*)d_in[9];
    const float* W2 = (const float*)d_in[10];
    const float* b2 = (const float*)d_in[11];
    const float* P3 = (const float*)d_in[12];
    const float* W3 = (const float*)d_in[13];
    const float* b3 = (const float*)d_in[14];
    float* out = (float*)d_out;

    char* ws = (char*)d_ws;
    size_t off = 0;
    auto alloc = [&](size_t bytes) -> char* {
        char* p = ws + off;
        off += (bytes + 255) & ~(size_t)255;
        return p;
    };
    const int NT_H = 157;   // ceil(20003/128)
    const int NT_1 = 157;   // ceil(20000/128)
    const int NT_2 = 1250;  // 160000/128
    const int NT_3 = 530;   // ceil(67735/128)

    unsigned short* hbf   = (unsigned short*)alloc((size_t)1024 * 1024 * 2);
    unsigned short* Pb    = (unsigned short*)alloc((size_t)384 * 1024 * 2);
    int* cnt   = (int*)alloc(4 * 4);
    int* slotc = (int*)alloc(1024 * 4);
    unsigned short* Hc1 = (unsigned short*)alloc((size_t)1024 * 256 * 2);
    unsigned short* Hc2 = (unsigned short*)alloc((size_t)1024 * 64 * 2);
    unsigned short* Hc3 = (unsigned short*)alloc((size_t)1024 * 64 * 2);
    float* pMh = (float*)alloc((size_t)1024 * NT_H * 4);
    float* pSh = (float*)alloc((size_t)1024 * NT_H * 4);
    float* pM1 = (float*)alloc((size_t)1024 * NT_1 * 4);
    float* pS1 = (float*)alloc((size_t)1024 * NT_1 * 4);
    float* pM2 = (float*)alloc((size_t)1024 * NT_2 * 4);
    float* pS2 = (float*)alloc((size_t)1024 * NT_2 * 4);
    float* pM3 = (float*)alloc((size_t)1024 * NT_3 * 4);
    float* pS3 = (float*)alloc((size_t)1024 * NT_3 * 4);
    float* lse = (float*)alloc((size_t)4 * 1024 * 4);
    float* pRm = (float*)alloc((size_t)4 * 16 * 1024 * 4);
    float* pRs = (float*)alloc((size_t)4 * 16 * 1024 * 4);
    unsigned short* Whb = (unsigned short*)alloc((size_t)20000 * 1024 * 2);
    unsigned short* W1b = (unsigned short*)alloc((size_t)20000 * 256 * 2);
    const bool pre = (off <= ws_size);

    const int nWh = pre ? 5120000 : 0;
    const int nW1 = pre ? 1280000 : 0;
    const long nChunks = (long)nWh + nW1 + 360448;
    mega_convert<<<(unsigned)((nChunks + 255) / 256), 256, 0, stream>>>(
        hidden, P1, P2, P3, W_head, W1, hbf, Pb, Whb, W1b, nWh, nW1);
    compact_tokens<<<1, 1024, 0, stream>>>(target, cnt, slotc);
    proj_mfma<<<dim3(8, 3), 256, 0, stream>>>(hbf, Pb, slotc, Hc1, Hc2, Hc3);

    // head: 640 blocks (20 groups x [8 vocab-tiles x 4 token-tiles]); nt>=157 guarded
    if (pre) {
        head_lse<true><<<640, 512, 0, stream>>>(
            Whb, nullptr, W_clu, 20000, 20003, 1024, 16, NT_H,
            b_head, b_clu, hbf, pMh, pSh);
        gemm_lse_t<true><<<dim3(8, NT_1), 256, 0, stream>>>(
            W1b, nullptr, nullptr, 20000, 20000, 256, 256, 4,
            b1, nullptr, Hc1, cnt, 1, pM1, pS1);
    } else {
        head_lse<false><<<640, 512, 0, stream>>>(
            nullptr, W_head, W_clu, 20000, 20003, 1024, 16, NT_H,
            b_head, b_clu, hbf, pMh, pSh);
        gemm_lse_t<false><<<dim3(8, NT_1), 256, 0, stream>>>(
            nullptr, W1, nullptr, 20000, 20000, 256, 256, 4,
            b1, nullptr, Hc1, cnt, 1, pM1, pS1);
    }
    tail_lse_res<64><<<NT_2, 256, 0, stream>>>(W2, 160000, b2, Hc2, cnt, 2, pM2, pS2);
    tail_lse_res<16><<<NT_3, 256, 0, stream>>>(W3, 67735, b3, Hc3, cnt, 3, pM3, pS3);

    reduce_part<<<dim3(16, 4, 16), 256, 0, stream>>>(pMh, pSh, NT_H,
                                                     pM1, pS1, NT_1,
                                                     pM2, pS2, NT_2,
                                                     pM3, pS3, NT_3, pRm, pRs);
    reduce_final<<<dim3(16, 4), 256, 0, stream>>>(pRm, pRs, lse);

    finalize<<<1024, 64, 0, stream>>>(hidden, target,
                                      W_head, b_head, W_clu, b_clu,
                                      W1, b1, W2, b2, W3, b3,
                                      Hc1, Hc2, Hc3, slotc, lse, out);
}

// Round 9
// 206.043 us; speedup vs baseline: 2.5991x; 1.1147x over previous
//
#include <hip/hip_runtime.h>
#include <cstdint>
#include <cstddef>

// ---------- types ----------
typedef __attribute__((ext_vector_type(8))) short short8;   // 8 x bf16 (4 VGPR)
typedef __attribute__((ext_vector_type(4))) float f32x4;

#define LOG2E 1.4426950408889634f
#define LN2   0.6931471805599453f

__device__ __forceinline__ unsigned short f2bf(float x) {
    unsigned u = __float_as_uint(x);
    u += 0x7FFFu + ((u >> 16) & 1u);        // RNE
    return (unsigned short)(u >> 16);
}
__device__ __forceinline__ float bf2f(unsigned short h) {
    return __uint_as_float(((unsigned)h) << 16);
}

// async global->LDS, 16B per lane; LDS dest = uniform base + lane*16
__device__ __forceinline__ void gload_lds16(const void* g, void* l) {
    __builtin_amdgcn_global_load_lds(
        (const __attribute__((address_space(1))) unsigned int*)g,
        (__attribute__((address_space(3))) unsigned int*)l, 16, 0, 0);
}

// ---------- kernel 1: fused f32->bf16 conversion of everything ----------
__global__ void mega_convert(const float* __restrict__ hidden,
                             const float* __restrict__ P1, const float* __restrict__ P2,
                             const float* __restrict__ P3,
                             const float* __restrict__ W_head, const float* __restrict__ W1,
                             unsigned short* __restrict__ hbf, unsigned short* __restrict__ Pb,
                             unsigned short* __restrict__ Whb, unsigned short* __restrict__ W1b,
                             int nWh, int nW1) {
    long i = (long)blockIdx.x * 256 + threadIdx.x;
    const float* src;
    unsigned short* dst;
    if (i < nWh)                      { src = W_head; dst = Whb; }
    else if ((i -= nWh) < nW1)        { src = W1;     dst = W1b; }
    else if ((i -= nW1) < 262144)     { src = hidden; dst = hbf; }
    else if ((i -= 262144) < 65536)   { src = P1;     dst = Pb; }
    else if ((i -= 65536) < 16384)    { src = P2;     dst = Pb + (size_t)256 * 1024; }
    else if ((i -= 16384) < 4096)     { src = P3;     dst = Pb + (size_t)320 * 1024; }
    else if ((i -= 4096) < 12288) {
        *(unsigned long long*)(Pb + (size_t)336 * 1024 + i * 4) = 0ull;
        return;
    } else return;
    float4 v = *(const float4*)(src + (size_t)i * 4);
    unsigned long long p = (unsigned long long)f2bf(v.x)
                         | ((unsigned long long)f2bf(v.y) << 16)
                         | ((unsigned long long)f2bf(v.z) << 32)
                         | ((unsigned long long)f2bf(v.w) << 48);
    *(unsigned long long*)(dst + (size_t)i * 4) = p;
}

// ---------- kernel 2: deterministic cluster compaction (1 block, 1024 threads) ----------
__global__ __launch_bounds__(1024)
void compact_tokens(const int* __restrict__ target, int* __restrict__ cnt,
                    int* __restrict__ slotc) {
    const int t = threadIdx.x;
    const int tgt = target[t];
    const int cid = (tgt >= 20000) + (tgt >= 40000) + (tgt >= 200000);
    const int wave = t >> 6, lane = t & 63;
    unsigned long long lt = (lane == 0) ? 0ull : (~0ull >> (64 - lane));
    __shared__ int wtot[3][16];
    __shared__ int wbase[3][16];
    unsigned long long bal[3];
#pragma unroll
    for (int c = 1; c <= 3; ++c) {
        unsigned long long b = __ballot(cid == c);
        if (lane == 0) wtot[c - 1][wave] = (int)__popcll(b);
        bal[c - 1] = b;
    }
    __syncthreads();
    if (t < 3) {
        int s = 0;
        for (int w = 0; w < 16; ++w) { wbase[t][w] = s; s += wtot[t][w]; }
        cnt[t + 1] = s;
        if (t == 0) cnt[0] = 1024;
    }
    __syncthreads();
    int sl = t;
    if (cid > 0) sl = wbase[cid - 1][wave] + (int)__popcll(bal[cid - 1] & lt);
    slotc[t] = sl | (cid << 16);
}

// ---------- kernel 3: MFMA projection, writes DIRECTLY into compacted Hc buffers ----------
__global__ __launch_bounds__(256)
void proj_mfma(const unsigned short* __restrict__ Hb,   // [1024][1024]
               const unsigned short* __restrict__ Pb,   // [384][1024]
               const int* __restrict__ slotc,
               unsigned short* __restrict__ Hc1,        // [1024][256] compacted
               unsigned short* __restrict__ Hc2,        // [1024][64]
               unsigned short* __restrict__ Hc3) {      // [1024][64]
    __shared__ __align__(16) char As[16384];
    __shared__ __align__(16) char Bs[16384];
    __shared__ int sl_s[128];
    const int tid  = threadIdx.x;
    const int lane = tid & 63;
    const int wid  = tid >> 6;
    const int wm = wid >> 1, wn = wid & 1;
    const int tt = blockIdx.x, dt = blockIdx.y;
    const int t0 = tt * 128, d0 = dt * 128;

    f32x4 acc[4][4];
    const f32x4 zero = {0.f, 0.f, 0.f, 0.f};
#pragma unroll
    for (int i = 0; i < 4; ++i)
#pragma unroll
        for (int j = 0; j < 4; ++j) acc[i][j] = zero;

    for (int kt = 0; kt < 16; ++kt) {
#pragma unroll
        for (int j = 0; j < 4; ++j) {
            int lds_off = wid * 4096 + j * 1024;
            int o = lds_off + lane * 16;
            int r = o >> 7;
            int b = (o & 127) ^ ((r & 7) << 4);
            gload_lds16(Hb + (size_t)(t0 + r) * 1024 + kt * 64 + (b >> 1), As + lds_off);
        }
#pragma unroll
        for (int j = 0; j < 4; ++j) {
            int lds_off = wid * 4096 + j * 1024;
            int o = lds_off + lane * 16;
            int r = o >> 7;
            int b = (o & 127) ^ ((r & 7) << 4);
            gload_lds16(Pb + (size_t)(d0 + r) * 1024 + kt * 64 + (b >> 1), Bs + lds_off);
        }
        __syncthreads();
#pragma unroll
        for (int kk = 0; kk < 2; ++kk) {
            const int kbyte = (kk * 32 + ((lane >> 4) << 3)) * 2;
            short8 a[4], b[4];
#pragma unroll
            for (int mi = 0; mi < 4; ++mi) {
                int row = wm * 64 + mi * 16 + (lane & 15);
                int off = (row * 128 + kbyte) ^ ((row & 7) << 4);
                a[mi] = *(const short8*)(As + off);
            }
#pragma unroll
            for (int ni = 0; ni < 4; ++ni) {
                int row = wn * 64 + ni * 16 + (lane & 15);
                int off = (row * 128 + kbyte) ^ ((row & 7) << 4);
                b[ni] = *(const short8*)(Bs + off);
            }
#pragma unroll
            for (int mi = 0; mi < 4; ++mi)
#pragma unroll
                for (int ni = 0; ni < 4; ++ni)
                    acc[mi][ni] = __builtin_amdgcn_mfma_f32_16x16x32_bf16(a[mi], b[ni], acc[mi][ni], 0, 0, 0);
        }
        __syncthreads();
    }

    if (tid < 128) sl_s[tid] = slotc[t0 + tid];
    __syncthreads();

#pragma unroll
    for (int ni = 0; ni < 4; ++ni) {
        int dg = d0 + wn * 64 + ni * 16 + (lane & 15);
        unsigned short* base;
        int c_d, dd, stride;
        if (dg < 256)      { c_d = 1; dd = dg;       base = Hc1; stride = 256; }
        else if (dg < 320) { c_d = 2; dd = dg - 256; base = Hc2; stride = 64;  }
        else               { c_d = 3; dd = dg - 320; base = Hc3; stride = 64;  }
#pragma unroll
        for (int mi = 0; mi < 4; ++mi)
#pragma unroll
            for (int r = 0; r < 4; ++r) {
                int tl = wm * 64 + mi * 16 + ((lane >> 4) << 2) + r;
                int sc = sl_s[tl];
                if ((sc >> 16) == c_d)
                    base[(size_t)(sc & 0xFFFF) * stride + dd] = f2bf(acc[mi][ni][r]);
            }
    }
}

// ---------- kernel 4: head GEMM 128x128, 256 threads, XCD-grouped decode ----------
// x = b&7 (XCD), i = b>>3; nt = x*20 + (i>>3), tt = i&7  -> blocks sharing a W tile
// are consecutive on the SAME XCD (tt cycles fast) => W tile hits that L2 once.
template<bool BF16B>
__global__ __launch_bounds__(256)
void head_lse(const unsigned short* __restrict__ Wb,
              const float* __restrict__ Wfa, const float* __restrict__ Wfb,
              int Nsplit, int N, int K, int KTILES, int NTQ,
              const float* __restrict__ bias1, const float* __restrict__ bias2,
              const unsigned short* __restrict__ H,
              float* __restrict__ pM, float* __restrict__ pS) {
    const int b = blockIdx.x;
    const int x = b & 7, i = b >> 3;
    const int nt = x * 20 + (i >> 3);
    const int tt = i & 7;
    if (nt >= NTQ) return;
    __shared__ __align__(16) char Ws[16384];
    __shared__ __align__(16) char Hs[16384];
    __shared__ float bias_s[128];
    __shared__ float red[2][128][2];
    const int tid  = threadIdx.x;
    const int lane = tid & 63;
    const int wid  = tid >> 6;
    const int wm = wid >> 1, wn = wid & 1;
    const int t0 = tt * 128, n0 = nt * 128;
    const bool clean = BF16B && (n0 + 128 <= Nsplit);

    if (tid < 128) {
        int v = n0 + tid;
        bias_s[tid] = (v < Nsplit) ? bias1[v] * LOG2E
                    : (v < N)      ? bias2[v - Nsplit] * LOG2E
                                   : -INFINITY;
    }

    f32x4 acc[4][4];
    const f32x4 zero = {0.f, 0.f, 0.f, 0.f};
#pragma unroll
    for (int i2 = 0; i2 < 4; ++i2)
#pragma unroll
        for (int j = 0; j < 4; ++j) acc[i2][j] = zero;

    for (int kt = 0; kt < KTILES; ++kt) {
        if (clean) {
#pragma unroll
            for (int j = 0; j < 4; ++j) {
                int lds_off = wid * 4096 + j * 1024;
                int o = lds_off + lane * 16;
                int r = o >> 7;
                int bb = (o & 127) ^ ((r & 7) << 4);
                gload_lds16(Wb + (size_t)(n0 + r) * K + kt * 64 + (bb >> 1), Ws + lds_off);
            }
        } else {
#pragma unroll
            for (int it = 0; it < 4; ++it) {
                int c = tid + it * 256;
                int row = c >> 3, kc = (c & 7) << 3;
                int v = n0 + row;
                int kg = kt * 64 + kc;
                unsigned short hh[8] = {0,0,0,0,0,0,0,0};
                if (v < Nsplit) {
                    if (BF16B) {
                        *(int4*)hh = *(const int4*)(Wb + (size_t)v * K + kg);
                    } else {
                        const float* p = Wfa + (size_t)v * K + kg;
                        float4 u0 = *(const float4*)p;
                        float4 u1 = *(const float4*)(p + 4);
                        hh[0]=f2bf(u0.x); hh[1]=f2bf(u0.y); hh[2]=f2bf(u0.z); hh[3]=f2bf(u0.w);
                        hh[4]=f2bf(u1.x); hh[5]=f2bf(u1.y); hh[6]=f2bf(u1.z); hh[7]=f2bf(u1.w);
                    }
                } else if (v < N && Wfb != nullptr) {
                    const float* p = Wfb + (size_t)(v - Nsplit) * K + kg;
                    float4 u0 = *(const float4*)p;
                    float4 u1 = *(const float4*)(p + 4);
                    hh[0]=f2bf(u0.x); hh[1]=f2bf(u0.y); hh[2]=f2bf(u0.z); hh[3]=f2bf(u0.w);
                    hh[4]=f2bf(u1.x); hh[5]=f2bf(u1.y); hh[6]=f2bf(u1.z); hh[7]=f2bf(u1.w);
                }
                int off = (row * 128 + kc * 2) ^ ((row & 7) << 4);
                *(int4*)(Ws + off) = *(const int4*)hh;
            }
        }
#pragma unroll
        for (int j = 0; j < 4; ++j) {
            int lds_off = wid * 4096 + j * 1024;
            int o = lds_off + lane * 16;
            int r = o >> 7;
            int bb = (o & 127) ^ ((r & 7) << 4);
            gload_lds16(H + (size_t)(t0 + r) * K + kt * 64 + (bb >> 1), Hs + lds_off);
        }
        __syncthreads();
#pragma unroll
        for (int kk = 0; kk < 2; ++kk) {
            const int kbyte = (kk * 32 + ((lane >> 4) << 3)) * 2;
            short8 a[4], bq[4];
#pragma unroll
            for (int mi = 0; mi < 4; ++mi) {
                int row = wm * 64 + mi * 16 + (lane & 15);
                int off = (row * 128 + kbyte) ^ ((row & 7) << 4);
                a[mi] = *(const short8*)(Ws + off);
            }
#pragma unroll
            for (int ni = 0; ni < 4; ++ni) {
                int row = wn * 64 + ni * 16 + (lane & 15);
                int off = (row * 128 + kbyte) ^ ((row & 7) << 4);
                bq[ni] = *(const short8*)(Hs + off);
            }
#pragma unroll
            for (int mi = 0; mi < 4; ++mi)
#pragma unroll
                for (int ni = 0; ni < 4; ++ni)
                    acc[mi][ni] = __builtin_amdgcn_mfma_f32_16x16x32_bf16(a[mi], bq[ni], acc[mi][ni], 0, 0, 0);
        }
        __syncthreads();
    }

    float bvv[4][4];
#pragma unroll
    for (int mi = 0; mi < 4; ++mi)
#pragma unroll
        for (int r = 0; r < 4; ++r)
            bvv[mi][r] = bias_s[wm * 64 + mi * 16 + ((lane >> 4) << 2) + r];

#pragma unroll
    for (int ni = 0; ni < 4; ++ni) {
        float xs[16];
        float mx = -INFINITY;
#pragma unroll
        for (int mi = 0; mi < 4; ++mi)
#pragma unroll
            for (int r = 0; r < 4; ++r) {
                float xv = fmaf(acc[mi][ni][r], LOG2E, bvv[mi][r]);
                xs[mi * 4 + r] = xv;
                mx = fmaxf(mx, xv);
            }
        mx = fmaxf(mx, __shfl_xor(mx, 16, 64));
        mx = fmaxf(mx, __shfl_xor(mx, 32, 64));
        float mxe = (mx == -INFINITY) ? 0.f : mx;
        float sm = 0.f;
#pragma unroll
        for (int q = 0; q < 16; ++q) sm += exp2f(xs[q] - mxe);
        sm += __shfl_xor(sm, 16, 64);
        sm += __shfl_xor(sm, 32, 64);
        if ((lane >> 4) == 0) {
            int tloc = wn * 64 + ni * 16 + lane;
            red[wm][tloc][0] = mx;
            red[wm][tloc][1] = sm;
        }
    }
    __syncthreads();
    if (tid < 128) {
        float m0v = red[0][tid][0], s0v = red[0][tid][1];
        float m1v = red[1][tid][0], s1v = red[1][tid][1];
        float M = fmaxf(m0v, m1v);
        float S = 0.f;
        if (s0v > 0.f) S += s0v * exp2f(m0v - M);
        if (s1v > 0.f) S += s1v * exp2f(m1v - M);
        size_t idx = (size_t)nt * 1024 + t0 + tid;
        pM[idx] = M;
        pS[idx] = S;
    }
}

// ---------- kernel 5: 128x128 GEMM + LSE (tail1; cnt-guarded) ----------
template<bool BF16B>
__global__ __launch_bounds__(256)
void gemm_lse_t(const unsigned short* __restrict__ Wb,
                const float* __restrict__ Wfa, const float* __restrict__ Wfb,
                int Nsplit, int N, int K, int Kv, int KTILES,
                const float* __restrict__ bias1, const float* __restrict__ bias2,
                const unsigned short* __restrict__ H,
                const int* __restrict__ cnt_p, int cidx,
                float* __restrict__ pM, float* __restrict__ pS) {
    if (cnt_p && (int)blockIdx.x * 128 >= cnt_p[cidx]) return;
    __shared__ __align__(16) char Ws[16384];
    __shared__ __align__(16) char Hs[16384];
    __shared__ float bias_s[128];
    __shared__ float red[2][128][2];
    const int tid  = threadIdx.x;
    const int lane = tid & 63;
    const int wid  = tid >> 6;
    const int wm = wid >> 1, wn = wid & 1;
    const int tt = blockIdx.x, nt = blockIdx.y;
    const int t0 = tt * 128, n0 = nt * 128;
    const bool clean = BF16B && (n0 + 128 <= Nsplit);

    if (tid < 128) {
        int v = n0 + tid;
        bias_s[tid] = (v < Nsplit) ? bias1[v] * LOG2E
                    : (v < N)      ? bias2[v - Nsplit] * LOG2E
                                   : -INFINITY;
    }

    f32x4 acc[4][4];
    const f32x4 zero = {0.f, 0.f, 0.f, 0.f};
#pragma unroll
    for (int i = 0; i < 4; ++i)
#pragma unroll
        for (int j = 0; j < 4; ++j) acc[i][j] = zero;

    for (int kt = 0; kt < KTILES; ++kt) {
        if (clean) {
#pragma unroll
            for (int j = 0; j < 4; ++j) {
                int lds_off = wid * 4096 + j * 1024;
                int o = lds_off + lane * 16;
                int r = o >> 7;
                int b = (o & 127) ^ ((r & 7) << 4);
                gload_lds16(Wb + (size_t)(n0 + r) * K + kt * 64 + (b >> 1), Ws + lds_off);
            }
        } else {
#pragma unroll
            for (int it = 0; it < 4; ++it) {
                int c = tid + it * 256;
                int row = c >> 3, kc = (c & 7) << 3;
                int v = n0 + row;
                int kg = kt * 64 + kc;
                unsigned short hh[8] = {0,0,0,0,0,0,0,0};
                if (v < Nsplit) {
                    if (BF16B) {
                        *(int4*)hh = *(const int4*)(Wb + (size_t)v * K + kg);
                    } else if (kg + 8 <= Kv) {
                        const float* p = Wfa + (size_t)v * Kv;
                        float4 u0 = *(const float4*)(p + kg);
                        float4 u1 = *(const float4*)(p + kg + 4);
                        hh[0]=f2bf(u0.x); hh[1]=f2bf(u0.y); hh[2]=f2bf(u0.z); hh[3]=f2bf(u0.w);
                        hh[4]=f2bf(u1.x); hh[5]=f2bf(u1.y); hh[6]=f2bf(u1.z); hh[7]=f2bf(u1.w);
                    }
                } else if (v < N && Wfb != nullptr) {
                    const float* p = Wfb + (size_t)(v - Nsplit) * K;
                    float4 u0 = *(const float4*)(p + kg);
                    float4 u1 = *(const float4*)(p + kg + 4);
                    hh[0]=f2bf(u0.x); hh[1]=f2bf(u0.y); hh[2]=f2bf(u0.z); hh[3]=f2bf(u0.w);
                    hh[4]=f2bf(u1.x); hh[5]=f2bf(u1.y); hh[6]=f2bf(u1.z); hh[7]=f2bf(u1.w);
                }
                int off = (row * 128 + kc * 2) ^ ((row & 7) << 4);
                *(int4*)(Ws + off) = *(const int4*)hh;
            }
        }
#pragma unroll
        for (int j = 0; j < 4; ++j) {
            int lds_off = wid * 4096 + j * 1024;
            int o = lds_off + lane * 16;
            int r = o >> 7;
            int b = (o & 127) ^ ((r & 7) << 4);
            gload_lds16(H + (size_t)(t0 + r) * K + kt * 64 + (b >> 1), Hs + lds_off);
        }
        __syncthreads();
#pragma unroll
        for (int kk = 0; kk < 2; ++kk) {
            const int kbyte = (kk * 32 + ((lane >> 4) << 3)) * 2;
            short8 a[4], b[4];
#pragma unroll
            for (int mi = 0; mi < 4; ++mi) {
                int row = wm * 64 + mi * 16 + (lane & 15);
                int off = (row * 128 + kbyte) ^ ((row & 7) << 4);
                a[mi] = *(const short8*)(Ws + off);
            }
#pragma unroll
            for (int ni = 0; ni < 4; ++ni) {
                int row = wn * 64 + ni * 16 + (lane & 15);
                int off = (row * 128 + kbyte) ^ ((row & 7) << 4);
                b[ni] = *(const short8*)(Hs + off);
            }
#pragma unroll
            for (int mi = 0; mi < 4; ++mi)
#pragma unroll
                for (int ni = 0; ni < 4; ++ni)
                    acc[mi][ni] = __builtin_amdgcn_mfma_f32_16x16x32_bf16(a[mi], b[ni], acc[mi][ni], 0, 0, 0);
        }
        __syncthreads();
    }

    float bvv[4][4];
#pragma unroll
    for (int mi = 0; mi < 4; ++mi)
#pragma unroll
        for (int r = 0; r < 4; ++r)
            bvv[mi][r] = bias_s[wm * 64 + mi * 16 + ((lane >> 4) << 2) + r];

#pragma unroll
    for (int ni = 0; ni < 4; ++ni) {
        float xs[16];
        float mx = -INFINITY;
#pragma unroll
        for (int mi = 0; mi < 4; ++mi)
#pragma unroll
            for (int r = 0; r < 4; ++r) {
                float x = fmaf(acc[mi][ni][r], LOG2E, bvv[mi][r]);
                xs[mi * 4 + r] = x;
                mx = fmaxf(mx, x);
            }
        mx = fmaxf(mx, __shfl_xor(mx, 16, 64));
        mx = fmaxf(mx, __shfl_xor(mx, 32, 64));
        float mxe = (mx == -INFINITY) ? 0.f : mx;
        float sm = 0.f;
#pragma unroll
        for (int i = 0; i < 16; ++i) sm += exp2f(xs[i] - mxe);
        sm += __shfl_xor(sm, 16, 64);
        sm += __shfl_xor(sm, 32, 64);
        if ((lane >> 4) == 0) {
            int tloc = wn * 64 + ni * 16 + lane;
            red[wm][tloc][0] = mx;
            red[wm][tloc][1] = sm;
        }
    }
    __syncthreads();
    if (tid < 128) {
        float m0v = red[0][tid][0], s0v = red[0][tid][1];
        float m1v = red[1][tid][0], s1v = red[1][tid][1];
        float M = fmaxf(m0v, m1v);
        float S = 0.f;
        if (s0v > 0.f) S += s0v * exp2f(m0v - M);
        if (s1v > 0.f) S += s1v * exp2f(m1v - M);
        size_t idx = (size_t)nt * 1024 + t0 + tid;
        pM[idx] = M;
        pS[idx] = S;
    }
}

// ---------- kernel 6: W-resident tail GEMM (K<=64, fused f32 conversion) ----------
template<int KV>
__global__ __launch_bounds__(256)
void tail_lse_res(const float* __restrict__ Wf, int N,
                  const float* __restrict__ bias,
                  const unsigned short* __restrict__ Hc,
                  const int* __restrict__ cnt, int cidx,
                  float* __restrict__ pM, float* __restrict__ pS) {
    __shared__ __align__(16) char Ws[16384];
    __shared__ __align__(16) char Hs[2][16384];
    __shared__ float bias_s[128];
    __shared__ float red[2][2][128][2];
    const int tid = threadIdx.x, lane = tid & 63, wid = tid >> 6;
    const int wm = wid >> 1, wn = wid & 1;
    const int n0 = blockIdx.x * 128;

#pragma unroll
    for (int it = 0; it < 4; ++it) {
        int c = tid + it * 256;
        int row = c >> 3, kc = (c & 7) << 3;
        int v = n0 + row;
        unsigned short hh[8] = {0,0,0,0,0,0,0,0};
        if (v < N && kc < KV) {
            const float* p = Wf + (size_t)v * KV + kc;
            float4 u0 = *(const float4*)p;
            float4 u1 = *(const float4*)(p + 4);
            hh[0]=f2bf(u0.x); hh[1]=f2bf(u0.y); hh[2]=f2bf(u0.z); hh[3]=f2bf(u0.w);
            hh[4]=f2bf(u1.x); hh[5]=f2bf(u1.y); hh[6]=f2bf(u1.z); hh[7]=f2bf(u1.w);
        }
        int off = (row * 128 + kc * 2) ^ ((row & 7) << 4);
        *(int4*)(Ws + off) = *(const int4*)hh;
    }
    if (tid < 128) {
        int v = n0 + tid;
        bias_s[tid] = (v < N) ? bias[v] * LOG2E : -INFINITY;
    }
    const int ntt = (cnt[cidx] + 127) >> 7;
    if (ntt > 0) {
#pragma unroll
        for (int j = 0; j < 4; ++j) {
            int lds_off = wid * 4096 + j * 1024;
            int o = lds_off + lane * 16;
            int r = o >> 7;
            int b = (o & 127) ^ ((r & 7) << 4);
            gload_lds16(Hc + (size_t)r * 64 + (b >> 1), Hs[0] + lds_off);
        }
    }
    __syncthreads();
    short8 a[2][4];
#pragma unroll
    for (int kk = 0; kk < 2; ++kk)
#pragma unroll
        for (int mi = 0; mi < 4; ++mi) {
            int row = wm * 64 + mi * 16 + (lane & 15);
            int kbyte = (kk * 32 + ((lane >> 4) << 3)) * 2;
            a[kk][mi] = *(const short8*)(Ws + ((row * 128 + kbyte) ^ ((row & 7) << 4)));
        }
    float bvv[4][4];
#pragma unroll
    for (int mi = 0; mi < 4; ++mi)
#pragma unroll
        for (int r = 0; r < 4; ++r)
            bvv[mi][r] = bias_s[wm * 64 + mi * 16 + ((lane >> 4) << 2) + r];

    for (int tt = 0; tt < ntt; ++tt) {
        const int cur = tt & 1;
        if (tt + 1 < ntt) {
#pragma unroll
            for (int j = 0; j < 4; ++j) {
                int lds_off = wid * 4096 + j * 1024;
                int o = lds_off + lane * 16;
                int r = o >> 7;
                int b = (o & 127) ^ ((r & 7) << 4);
                gload_lds16(Hc + (size_t)((tt + 1) * 128 + r) * 64 + (b >> 1), Hs[cur ^ 1] + lds_off);
            }
        }
        f32x4 acc[4][4];
        const f32x4 zero = {0.f, 0.f, 0.f, 0.f};
#pragma unroll
        for (int i = 0; i < 4; ++i)
#pragma unroll
            for (int j = 0; j < 4; ++j) acc[i][j] = zero;
#pragma unroll
        for (int kk = 0; kk < 2; ++kk) {
            const int kbyte = (kk * 32 + ((lane >> 4) << 3)) * 2;
            short8 b[4];
#pragma unroll
            for (int ni = 0; ni < 4; ++ni) {
                int row = wn * 64 + ni * 16 + (lane & 15);
                b[ni] = *(const short8*)(Hs[cur] + ((row * 128 + kbyte) ^ ((row & 7) << 4)));
            }
#pragma unroll
            for (int mi = 0; mi < 4; ++mi)
#pragma unroll
                for (int ni = 0; ni < 4; ++ni)
                    acc[mi][ni] = __builtin_amdgcn_mfma_f32_16x16x32_bf16(a[kk][mi], b[ni], acc[mi][ni], 0, 0, 0);
        }
#pragma unroll
        for (int ni = 0; ni < 4; ++ni) {
            float xs[16];
            float mx = -INFINITY;
#pragma unroll
            for (int mi = 0; mi < 4; ++mi)
#pragma unroll
                for (int r = 0; r < 4; ++r) {
                    float x = fmaf(acc[mi][ni][r], LOG2E, bvv[mi][r]);
                    xs[mi * 4 + r] = x;
                    mx = fmaxf(mx, x);
                }
            mx = fmaxf(mx, __shfl_xor(mx, 16, 64));
            mx = fmaxf(mx, __shfl_xor(mx, 32, 64));
            float mxe = (mx == -INFINITY) ? 0.f : mx;
            float sm = 0.f;
#pragma unroll
            for (int i = 0; i < 16; ++i) sm += exp2f(xs[i] - mxe);
            sm += __shfl_xor(sm, 16, 64);
            sm += __shfl_xor(sm, 32, 64);
            if ((lane >> 4) == 0) {
                int tloc = wn * 64 + ni * 16 + lane;
                red[cur][wm][tloc][0] = mx;
                red[cur][wm][tloc][1] = sm;
            }
        }
        __syncthreads();
        if (tid < 128) {
            float m0v = red[cur][0][tid][0], s0v = red[cur][0][tid][1];
            float m1v = red[cur][1][tid][0], s1v = red[cur][1][tid][1];
            float M = fmaxf(m0v, m1v);
            float S = 0.f;
            if (s0v > 0.f) S += s0v * exp2f(m0v - M);
            if (s1v > 0.f) S += s1v * exp2f(m1v - M);
            size_t idx = (size_t)blockIdx.x * 1024 + tt * 128 + tid;
            pM[idx] = M;
            pS[idx] = S;
        }
    }
}

// ---------- kernel 7a: stage-1 LSE reduce ----------
__global__ __launch_bounds__(256)
void reduce_part(const float* __restrict__ pMh, const float* __restrict__ pSh, int nth,
                 const float* __restrict__ pM1, const float* __restrict__ pS1, int nt1,
                 const float* __restrict__ pM2, const float* __restrict__ pS2, int nt2,
                 const float* __restrict__ pM3, const float* __restrict__ pS3, int nt3,
                 float* __restrict__ pRm, float* __restrict__ pRs) {
    const int c = blockIdx.y, z = blockIdx.z;
    const float* PM = (c == 0) ? pMh : (c == 1) ? pM1 : (c == 2) ? pM2 : pM3;
    const float* PS = (c == 0) ? pSh : (c == 1) ? pS1 : (c == 2) ? pS2 : pS3;
    const int nt = (c == 0) ? nth : (c == 1) ? nt1 : (c == 2) ? nt2 : nt3;
    const int lane = threadIdx.x & 63;
    const int seg  = threadIdx.x >> 6;
    const int t = blockIdx.x * 64 + lane;
    float m = -INFINITY, s = 0.f;
    for (int i = z * 4 + seg; i < nt; i += 64) {
        float mi = PM[(size_t)i * 1024 + t];
        float si = PS[(size_t)i * 1024 + t];
        if (mi > m) { s = s * exp2f(m - mi) + si; m = mi; }
        else if (si > 0.f) { s += si * exp2f(mi - m); }
    }
    __shared__ float rm[4][64], rs[4][64];
    rm[seg][lane] = m; rs[seg][lane] = s;
    __syncthreads();
    if (seg == 0) {
#pragma unroll
        for (int q = 1; q < 4; ++q) {
            float om = rm[q][lane], os = rs[q][lane];
            if (om > m) { s = s * exp2f(m - om) + os; m = om; }
            else if (os > 0.f) { s += os * exp2f(om - m); }
        }
        size_t idx = ((size_t)c * 16 + z) * 1024 + t;
        pRm[idx] = m;
        pRs[idx] = s;
    }
}

// ---------- kernel 7b: stage-2 combine -> lse ----------
__global__ __launch_bounds__(256)
void reduce_final(const float* __restrict__ pRm, const float* __restrict__ pRs,
                  float* __restrict__ lse) {
    const int c = blockIdx.y;
    const int lane = threadIdx.x & 63;
    const int seg  = threadIdx.x >> 6;
    const int t = blockIdx.x * 64 + lane;
    float m = -INFINITY, s = 0.f;
#pragma unroll
    for (int z = 0; z < 4; ++z) {
        size_t idx = ((size_t)c * 16 + seg * 4 + z) * 1024 + t;
        float om = pRm[idx], os = pRs[idx];
        if (om > m) { s = s * exp2f(m - om) + os; m = om; }
        else if (os > 0.f) { s += os * exp2f(om - m); }
    }
    __shared__ float rm[4][64], rs[4][64];
    rm[seg][lane] = m; rs[seg][lane] = s;
    __syncthreads();
    if (seg == 0) {
#pragma unroll
        for (int q = 1; q < 4; ++q) {
            float om = rm[q][lane], os = rs[q][lane];
            if (om > m) { s = s * exp2f(m - om) + os; m = om; }
            else if (os > 0.f) { s += os * exp2f(om - m); }
        }
        lse[c * 1024 + t] = LN2 * (m + log2f(s));
    }
}

// ---------- kernel 8: gather needed logits + assemble output ----------
__global__ void finalize(const float* __restrict__ hidden, const int* __restrict__ target,
                         const float* __restrict__ W_head, const float* __restrict__ b_head,
                         const float* __restrict__ W_clu, const float* __restrict__ b_clu,
                         const float* __restrict__ W1, const float* __restrict__ b1,
                         const float* __restrict__ W2, const float* __restrict__ b2,
                         const float* __restrict__ W3, const float* __restrict__ b3,
                         const unsigned short* __restrict__ Hc1,
                         const unsigned short* __restrict__ Hc2,
                         const unsigned short* __restrict__ Hc3,
                         const int* __restrict__ slotc,
                         const float* __restrict__ lse,   // [4][1024]
                         float* __restrict__ out) {
    const int t = blockIdx.x;
    const int lane = threadIdx.x;
    const int tgt = target[t];
    const int cid = (tgt >= 20000) + (tgt >= 40000) + (tgt >= 200000);
    const int j = (cid == 0) ? tgt : (20003 - cid);
    const float* wr = (j < 20000) ? (W_head + (size_t)j * 1024)
                                  : (W_clu + (size_t)(j - 20000) * 1024);
    float acc = 0.f;
#pragma unroll
    for (int i = 0; i < 4; ++i) {
        int k4 = lane + i * 64;
        float4 h = *(const float4*)(hidden + (size_t)t * 1024 + k4 * 4);
        float4 w = *(const float4*)(wr + k4 * 4);
        acc += h.x * w.x + h.y * w.y + h.z * w.z + h.w * w.w;
    }
#pragma unroll
    for (int msk = 1; msk < 64; msk <<= 1) acc += __shfl_xor(acc, msk, 64);
    float bj = (j < 20000) ? b_head[j] : b_clu[j - 20000];
    float res = (acc + bj) - lse[t];
    if (cid > 0) {
        const int starts[4] = {0, 20000, 40000, 200000};
        const int dims[4]   = {0, 256, 64, 16};
        const int slot = slotc[t] & 0xFFFF;
        const float* Wt = (cid == 1) ? W1 : (cid == 2) ? W2 : W3;
        const float* bt = (cid == 1) ? b1 : (cid == 2) ? b2 : b3;
        const unsigned short* pr = (cid == 1) ? Hc1 + (size_t)slot * 256
                                 : (cid == 2) ? Hc2 + (size_t)slot * 64
                                              : Hc3 + (size_t)slot * 64;
        int ti = tgt - starts[cid];
        int d  = dims[cid];
        const float* wt = Wt + (size_t)ti * d;
        float a2 = 0.f;
        for (int k = lane; k < d; k += 64) a2 += bf2f(pr[k]) * wt[k];
#pragma unroll
        for (int msk = 1; msk < 64; msk <<= 1) a2 += __shfl_xor(a2, msk, 64);
        res += (a2 + bt[ti]) - lse[cid * 1024 + slot];
    }
    if (lane == 0) out[t] = -res;
}

// ---------- launch ----------
extern "C" void kernel_launch(void* const* d_in, const int* in_sizes, int n_in,
                              void* d_out, int out_size, void* d_ws, size_t ws_size,
                              hipStream_t stream) {
    const float* hidden = (const float*)d_in[0];
    const int*   target = (const int*)d_in[1];
    const float* W_head = (const float*)d_in[2];
    const float* b_head = (const float*)d_in[3];
    const float* W_clu  = (const float*)d_in[4];
    const float* b_clu  = (const float*)d_in[5];
    const float* P1 = (const float*)d_in[6];
    const float* W1 = (const float*)d_in[7];
    const float* b1 = (const float*)d_in[8];
    const float* P2 = (const float*)d_in[9];
    const float* W2 = (const float*)d_in[10];
    const float* b2 = (const float*)d_in[11];
    const float* P3 = (const float*)d_in[12];
    const float* W3 = (const float*)d_in[13];
    const float* b3 = (const float*)d_in[14];
    float* out = (float*)d_out;

    char* ws = (char*)d_ws;
    size_t off = 0;
    auto alloc = [&](size_t bytes) -> char* {
        char* p = ws + off;
        off += (bytes + 255) & ~(size_t)255;
        return p;
    };
    const int NT_H = 157;   // ceil(20003/128)
    const int NT_1 = 157;   // ceil(20000/128)
    const int NT_2 = 1250;  // 160000/128
    const int NT_3 = 530;   // ceil(67735/128)

    unsigned short* hbf   = (unsigned short*)alloc((size_t)1024 * 1024 * 2);
    unsigned short* Pb    = (unsigned short*)alloc((size_t)384 * 1024 * 2);
    int* cnt   = (int*)alloc(4 * 4);
    int* slotc = (int*)alloc(1024 * 4);
    unsigned short* Hc1 = (unsigned short*)alloc((size_t)1024 * 256 * 2);
    unsigned short* Hc2 = (unsigned short*)alloc((size_t)1024 * 64 * 2);
    unsigned short* Hc3 = (unsigned short*)alloc((size_t)1024 * 64 * 2);
    float* pMh = (float*)alloc((size_t)1024 * NT_H * 4);
    float* pSh = (float*)alloc((size_t)1024 * NT_H * 4);
    float* pM1 = (float*)alloc((size_t)1024 * NT_1 * 4);
    float* pS1 = (float*)alloc((size_t)1024 * NT_1 * 4);
    float* pM2 = (float*)alloc((size_t)1024 * NT_2 * 4);
    float* pS2 = (float*)alloc((size_t)1024 * NT_2 * 4);
    float* pM3 = (float*)alloc((size_t)1024 * NT_3 * 4);
    float* pS3 = (float*)alloc((size_t)1024 * NT_3 * 4);
    float* lse = (float*)alloc((size_t)4 * 1024 * 4);
    float* pRm = (float*)alloc((size_t)4 * 16 * 1024 * 4);
    float* pRs = (float*)alloc((size_t)4 * 16 * 1024 * 4);
    unsigned short* Whb = (unsigned short*)alloc((size_t)20000 * 1024 * 2);
    unsigned short* W1b = (unsigned short*)alloc((size_t)20000 * 256 * 2);
    const bool pre = (off <= ws_size);

    const int nWh = pre ? 5120000 : 0;
    const int nW1 = pre ? 1280000 : 0;
    const long nChunks = (long)nWh + nW1 + 360448;
    mega_convert<<<(unsigned)((nChunks + 255) / 256), 256, 0, stream>>>(
        hidden, P1, P2, P3, W_head, W1, hbf, Pb, Whb, W1b, nWh, nW1);
    compact_tokens<<<1, 1024, 0, stream>>>(target, cnt, slotc);
    proj_mfma<<<dim3(8, 3), 256, 0, stream>>>(hbf, Pb, slotc, Hc1, Hc2, Hc3);

    // head: 1280 blocks = 8 XCD groups x 20 nt x 8 tt; nt>=157 guarded
    if (pre) {
        head_lse<true><<<1280, 256, 0, stream>>>(
            Whb, nullptr, W_clu, 20000, 20003, 1024, 16, NT_H,
            b_head, b_clu, hbf, pMh, pSh);
        gemm_lse_t<true><<<dim3(8, NT_1), 256, 0, stream>>>(
            W1b, nullptr, nullptr, 20000, 20000, 256, 256, 4,
            b1, nullptr, Hc1, cnt, 1, pM1, pS1);
    } else {
        head_lse<false><<<1280, 256, 0, stream>>>(
            nullptr, W_head, W_clu, 20000, 20003, 1024, 16, NT_H,
            b_head, b_clu, hbf, pMh, pSh);
        gemm_lse_t<false><<<dim3(8, NT_1), 256, 0, stream>>>(
            nullptr, W1, nullptr, 20000, 20000, 256, 256, 4,
            b1, nullptr, Hc1, cnt, 1, pM1, pS1);
    }
    tail_lse_res<64><<<NT_2, 256, 0, stream>>>(W2, 160000, b2, Hc2, cnt, 2, pM2, pS2);
    tail_lse_res<16><<<NT_3, 256, 0, stream>>>(W3, 67735, b3, Hc3, cnt, 3, pM3, pS3);

    reduce_part<<<dim3(16, 4, 16), 256, 0, stream>>>(pMh, pSh, NT_H,
                                                     pM1, pS1, NT_1,
                                                     pM2, pS2, NT_2,
                                                     pM3, pS3, NT_3, pRm, pRs);
    reduce_final<<<dim3(16, 4), 256, 0, stream>>>(pRm, pRs, lse);

    finalize<<<1024, 64, 0, stream>>>(hidden, target,
                                      W_head, b_head, W_clu, b_clu,
                                      W1, b1, W2, b2, W3, b3,
                                      Hc1, Hc2, Hc3, slotc, lse, out);
}